// Round 3
// baseline (3396.603 us; speedup 1.0000x reference)
//
#include <hip/hip_runtime.h>
#include <stddef.h>

// Problem constants (E=2 experts, NB=2 blocks, B=8 batch, N=512 nodes)
#define EE 2
#define NBK 2
#define BATCH 8
#define NN 512
#define CC 32
#define TT 26     // RF
#define SEQ 12

// ---------------------------------------------------------------------------
// A-normalization: di[v] = rsqrt(sum_w (adj[v,w] + I))
__global__ __launch_bounds__(256) void k_rowsum(const float* __restrict__ adj,
                                                float* __restrict__ di) {
    int v = blockIdx.x;
    int tid = threadIdx.x;
    float s = 0.f;
    for (int w = tid; w < 512; w += 256)
        s += adj[v * 512 + w] + (w == v ? 1.f : 0.f);
    for (int off = 32; off; off >>= 1) s += __shfl_down(s, off);
    __shared__ float red[4];
    if ((tid & 63) == 0) red[tid >> 6] = s;
    __syncthreads();
    if (tid == 0) {
        float t = red[0] + red[1] + red[2] + red[3];
        di[v] = rsqrtf(t);
    }
}

// An[v,w] = di[v]*(adj+I)[v,w]*di[w]; AnT = An^T (both row-major)
__global__ __launch_bounds__(256) void k_norm(const float* __restrict__ adj,
                                              const float* __restrict__ di,
                                              float* __restrict__ An,
                                              float* __restrict__ AnT) {
    int idx = blockIdx.x * 256 + threadIdx.x;  // 0..262143
    int v = idx >> 9, w = idx & 511;
    float a = adj[idx] + (v == w ? 1.f : 0.f);
    float val = di[v] * a * di[w];
    An[idx] = val;
    AnT[w * 512 + v] = val;
}

// ---------------------------------------------------------------------------
// start: x[eb, t, c, n] = b_start[c] + W_start[c,0]*in0 + W_start[c,1]*in1
// t<14 -> zero-pad region (bias only)
__global__ __launch_bounds__(256) void k_start(const float* __restrict__ bkc,
                                               float* __restrict__ x,
                                               const float* __restrict__ Wst,
                                               const float* __restrict__ bst,
                                               int kb) {
    int n = blockIdx.x * 256 + threadIdx.x;
    int t = blockIdx.y;
    int eb = blockIdx.z;
    int e = eb >> 3;
    int ek = e * NBK + kb;
    const float* Wp = Wst + (size_t)ek * 32 * 2;
    const float* bp = bst + (size_t)ek * 32;
    float in0 = 0.f, in1 = 0.f;
    if (t >= 14) {
        const float* p = bkc + ((size_t)(eb * 12 + (t - 14)) * 512 + n) * 2;
        in0 = p[0];
        in1 = p[1];
    }
    float* xo = x + ((size_t)(eb * 26 + t) * 32) * 512 + n;
#pragma unroll
    for (int c = 0; c < 32; ++c) {
        xo[(size_t)c * 512] = bp[c] + Wp[c * 2] * in0 + Wp[c * 2 + 1] * in1;
    }
}

// ---------------------------------------------------------------------------
// inception + gating: h[col][n], col = (eb*L + j)*32 + c
// window for output j: x columns t0..t0+6, t0 = 26-cur_len+j
__global__ __launch_bounds__(256) void k_incept(
    const float* __restrict__ x, float* __restrict__ h,
    const float* __restrict__ Wf2, const float* __restrict__ Wf3,
    const float* __restrict__ Wf5, const float* __restrict__ Wf7,
    const float* __restrict__ bf,
    const float* __restrict__ Wg2, const float* __restrict__ Wg3,
    const float* __restrict__ Wg5, const float* __restrict__ Wg7,
    const float* __restrict__ bg,
    int kb, int cur_len, int L) {
    int n = blockIdx.x * 256 + threadIdx.x;
    int j = blockIdx.y;
    int eb = blockIdx.z;
    int e = eb >> 3;
    int ek = e * NBK + kb;
    int t0 = 26 - cur_len + j;
    const float* xb = x + ((size_t)eb * 26 * 32) * 512 + n;

    float af[32], ag[32];
#pragma unroll
    for (int o = 0; o < 32; ++o) {
        af[o] = bf[ek * 32 + o];
        ag[o] = bg[ek * 32 + o];
    }
    const float* wf2 = Wf2 + (size_t)ek * 512;   // [oo][c][2]
    const float* wf3 = Wf3 + (size_t)ek * 768;   // [oo][c][3]
    const float* wf5 = Wf5 + (size_t)ek * 1280;  // [oo][c][5]
    const float* wf7 = Wf7 + (size_t)ek * 1792;  // [oo][c][7]
    const float* wg2 = Wg2 + (size_t)ek * 512;
    const float* wg3 = Wg3 + (size_t)ek * 768;
    const float* wg5 = Wg5 + (size_t)ek * 1280;
    const float* wg7 = Wg7 + (size_t)ek * 1792;

    for (int c = 0; c < 32; ++c) {
        float w0 = xb[(size_t)((t0 + 0) * 32 + c) * 512];
        float w1 = xb[(size_t)((t0 + 1) * 32 + c) * 512];
        float w2 = xb[(size_t)((t0 + 2) * 32 + c) * 512];
        float w3 = xb[(size_t)((t0 + 3) * 32 + c) * 512];
        float w4 = xb[(size_t)((t0 + 4) * 32 + c) * 512];
        float w5 = xb[(size_t)((t0 + 5) * 32 + c) * 512];
        float w6 = xb[(size_t)((t0 + 6) * 32 + c) * 512];
#pragma unroll
        for (int oo = 0; oo < 8; ++oo) {
            af[oo]      += wf2[oo * 64 + c * 2 + 0] * w5 + wf2[oo * 64 + c * 2 + 1] * w6;
            af[8 + oo]  += wf3[oo * 96 + c * 3 + 0] * w4 + wf3[oo * 96 + c * 3 + 1] * w5 +
                           wf3[oo * 96 + c * 3 + 2] * w6;
            af[16 + oo] += wf5[oo * 160 + c * 5 + 0] * w2 + wf5[oo * 160 + c * 5 + 1] * w3 +
                           wf5[oo * 160 + c * 5 + 2] * w4 + wf5[oo * 160 + c * 5 + 3] * w5 +
                           wf5[oo * 160 + c * 5 + 4] * w6;
            af[24 + oo] += wf7[oo * 224 + c * 7 + 0] * w0 + wf7[oo * 224 + c * 7 + 1] * w1 +
                           wf7[oo * 224 + c * 7 + 2] * w2 + wf7[oo * 224 + c * 7 + 3] * w3 +
                           wf7[oo * 224 + c * 7 + 4] * w4 + wf7[oo * 224 + c * 7 + 5] * w5 +
                           wf7[oo * 224 + c * 7 + 6] * w6;
            ag[oo]      += wg2[oo * 64 + c * 2 + 0] * w5 + wg2[oo * 64 + c * 2 + 1] * w6;
            ag[8 + oo]  += wg3[oo * 96 + c * 3 + 0] * w4 + wg3[oo * 96 + c * 3 + 1] * w5 +
                           wg3[oo * 96 + c * 3 + 2] * w6;
            ag[16 + oo] += wg5[oo * 160 + c * 5 + 0] * w2 + wg5[oo * 160 + c * 5 + 1] * w3 +
                           wg5[oo * 160 + c * 5 + 2] * w4 + wg5[oo * 160 + c * 5 + 3] * w5 +
                           wg5[oo * 160 + c * 5 + 4] * w6;
            ag[24 + oo] += wg7[oo * 224 + c * 7 + 0] * w0 + wg7[oo * 224 + c * 7 + 1] * w1 +
                           wg7[oo * 224 + c * 7 + 2] * w2 + wg7[oo * 224 + c * 7 + 3] * w3 +
                           wg7[oo * 224 + c * 7 + 4] * w4 + wg7[oo * 224 + c * 7 + 5] * w5 +
                           wg7[oo * 224 + c * 7 + 6] * w6;
        }
    }
    size_t colbase = ((size_t)eb * L + j) * 32;
#pragma unroll
    for (int c = 0; c < 32; ++c) {
        float fv = tanhf(af[c]);
        float gv = 1.f / (1.f + expf(-ag[c]));
        h[(colbase + c) * 512 + n] = fv * gv;
    }
}

// ---------------------------------------------------------------------------
// NT GEMM: C[m][v] = sum_w A[m][w] * Bm[v][w];  K=N=512, M multiple of 128.
// Two independent problems batched via blockIdx.z.
__global__ __launch_bounds__(256) void k_gemm(
    const float* __restrict__ A0, const float* __restrict__ B0, float* __restrict__ C0,
    const float* __restrict__ A1, const float* __restrict__ B1, float* __restrict__ C1,
    int M) {
    const float* A = blockIdx.z ? A1 : A0;
    const float* Bm = blockIdx.z ? B1 : B0;
    float* C = blockIdx.z ? C1 : C0;
    __shared__ float As[16][128];
    __shared__ float Bs[16][128];
    int tid = threadIdx.x;
    int m0 = blockIdx.x * 128, n0 = blockIdx.y * 128;
    int lr = tid >> 1, lk = (tid & 1) * 8;
    int tm = (tid & 15) * 4, tn = (tid >> 4) * 4;
    float acc[8][8] = {{0.f}};
    for (int k0 = 0; k0 < 512; k0 += 16) {
        float4 a0 = *(const float4*)(A + (size_t)(m0 + lr) * 512 + k0 + lk);
        float4 a1 = *(const float4*)(A + (size_t)(m0 + lr) * 512 + k0 + lk + 4);
        float4 b0 = *(const float4*)(Bm + (size_t)(n0 + lr) * 512 + k0 + lk);
        float4 b1 = *(const float4*)(Bm + (size_t)(n0 + lr) * 512 + k0 + lk + 4);
        As[lk + 0][lr] = a0.x; As[lk + 1][lr] = a0.y; As[lk + 2][lr] = a0.z; As[lk + 3][lr] = a0.w;
        As[lk + 4][lr] = a1.x; As[lk + 5][lr] = a1.y; As[lk + 6][lr] = a1.z; As[lk + 7][lr] = a1.w;
        Bs[lk + 0][lr] = b0.x; Bs[lk + 1][lr] = b0.y; Bs[lk + 2][lr] = b0.z; Bs[lk + 3][lr] = b0.w;
        Bs[lk + 4][lr] = b1.x; Bs[lk + 5][lr] = b1.y; Bs[lk + 6][lr] = b1.z; Bs[lk + 7][lr] = b1.w;
        __syncthreads();
#pragma unroll
        for (int kk = 0; kk < 16; ++kk) {
            float4 av0 = *(const float4*)&As[kk][tm];
            float4 av1 = *(const float4*)&As[kk][tm + 64];
            float4 bv0 = *(const float4*)&Bs[kk][tn];
            float4 bv1 = *(const float4*)&Bs[kk][tn + 64];
            float a[8] = {av0.x, av0.y, av0.z, av0.w, av1.x, av1.y, av1.z, av1.w};
            float b[8] = {bv0.x, bv0.y, bv0.z, bv0.w, bv1.x, bv1.y, bv1.z, bv1.w};
#pragma unroll
            for (int i = 0; i < 8; ++i)
#pragma unroll
                for (int jj = 0; jj < 8; ++jj) acc[i][jj] += a[i] * b[jj];
        }
        __syncthreads();
    }
#pragma unroll
    for (int i = 0; i < 8; ++i) {
        int rm = m0 + ((i < 4) ? tm + i : 64 + tm + (i - 4));
        float4 o0 = {acc[i][0], acc[i][1], acc[i][2], acc[i][3]};
        float4 o1 = {acc[i][4], acc[i][5], acc[i][6], acc[i][7]};
        *(float4*)(C + (size_t)rm * 512 + n0 + tn) = o0;
        *(float4*)(C + (size_t)rm * 512 + n0 + 64 + tn) = o1;
    }
}

// ---------------------------------------------------------------------------
// Precompute effective channel-mix matrices (transposed [cp][c]) and bias sum.
// M0 = W0+W1+W2+V0+V1+V2 (h), M1 = .5W1+W2 (u1), M2 = .25W2 (v1),
// M3 = .5V1+V2 (u1t), M4 = .25V2 (v1t)
__global__ __launch_bounds__(256) void k_prepmix(const float* __restrict__ Wgc1,
                                                 const float* __restrict__ bgc1,
                                                 const float* __restrict__ Wgc2,
                                                 const float* __restrict__ bgc2,
                                                 float* __restrict__ mixT,
                                                 float* __restrict__ bsum, int kb) {
    int e = blockIdx.x;
    int ek = e * NBK + kb;
    const float* W1 = Wgc1 + (size_t)ek * 32 * 96;
    const float* W2 = Wgc2 + (size_t)ek * 32 * 96;
    for (int idx = threadIdx.x; idx < 5 * 32 * 32; idx += 256) {
        int m = idx >> 10, cp = (idx >> 5) & 31, c = idx & 31;
        float w0 = W1[c * 96 + cp], w1 = W1[c * 96 + 32 + cp], w2 = W1[c * 96 + 64 + cp];
        float v0 = W2[c * 96 + cp], v1 = W2[c * 96 + 32 + cp], v2 = W2[c * 96 + 64 + cp];
        float val;
        if (m == 0) val = w0 + w1 + w2 + v0 + v1 + v2;
        else if (m == 1) val = 0.5f * w1 + w2;
        else if (m == 2) val = 0.25f * w2;
        else if (m == 3) val = 0.5f * v1 + v2;
        else val = 0.25f * v2;
        mixT[((size_t)(e * 5 + m) * 32 + cp) * 32 + c] = val;
    }
    if (threadIdx.x < 32)
        bsum[e * 32 + threadIdx.x] =
            bgc1[ek * 32 + threadIdx.x] + bgc2[ek * 32 + threadIdx.x];
}

// ---------------------------------------------------------------------------
// combine: g[c] = bsum[c] + sum_m sum_cp mixT[m][cp][c]*buf_m[cp]; x -= 0.25*g
__global__ __launch_bounds__(256) void k_combine(
    float* __restrict__ x, const float* __restrict__ h, const float* __restrict__ u1,
    const float* __restrict__ v1, const float* __restrict__ u1t,
    const float* __restrict__ v1t, const float* __restrict__ mixT,
    const float* __restrict__ bsum, int L) {
    int n = blockIdx.x * 256 + threadIdx.x;
    int j = blockIdx.y;
    int eb = blockIdx.z;
    int e = eb >> 3;
    size_t colbase = ((size_t)eb * L + j) * 32;
    const float* bufs[5] = {h, u1, v1, u1t, v1t};
    float g[32];
#pragma unroll
    for (int c = 0; c < 32; ++c) g[c] = bsum[e * 32 + c];
#pragma unroll
    for (int m = 0; m < 5; ++m) {
        const float* in = bufs[m] + colbase * 512 + n;
        const float* Mp = mixT + ((size_t)(e * 5 + m) * 32) * 32;
        for (int cp = 0; cp < 32; ++cp) {
            float v = in[(size_t)cp * 512];
#pragma unroll
            for (int c = 0; c < 32; ++c) g[c] += Mp[cp * 32 + c] * v;
        }
    }
    int t = 26 - L + j;
    float* xo = x + ((size_t)(eb * 26 + t) * 32) * 512 + n;
#pragma unroll
    for (int c = 0; c < 32; ++c) xo[(size_t)c * 512] -= 0.25f * g[c];
}

// ---------------------------------------------------------------------------
// layernorm stats over x[..., t=24..25] (32768 contiguous floats per eb)
__global__ __launch_bounds__(256) void k_lnstats(const float* __restrict__ x,
                                                 float* __restrict__ stats) {
    int eb = blockIdx.x;
    const float* p = x + ((size_t)(eb * 26 + 24) * 32) * 512;
    float s = 0.f, s2 = 0.f;
    for (int i = threadIdx.x; i < 32768; i += 256) {
        float v = p[i];
        s += v;
        s2 += v * v;
    }
    for (int off = 32; off; off >>= 1) {
        s += __shfl_down(s, off);
        s2 += __shfl_down(s2, off);
    }
    __shared__ float r1[4], r2[4];
    if ((threadIdx.x & 63) == 0) {
        r1[threadIdx.x >> 6] = s;
        r2[threadIdx.x >> 6] = s2;
    }
    __syncthreads();
    if (threadIdx.x == 0) {
        float S = r1[0] + r1[1] + r1[2] + r1[3];
        float S2 = r2[0] + r2[1] + r2[2] + r2[3];
        float mu = S / 32768.f;
        float var = S2 / 32768.f - mu * mu;
        stats[eb * 2] = mu;
        stats[eb * 2 + 1] = rsqrtf(var + 1e-5f);
    }
}

// ---------------------------------------------------------------------------
// heads: layernorm-apply + bc head (update bkc) + fc head (accumulate acc)
__global__ __launch_bounds__(256) void k_heads(
    const float* __restrict__ x, const float* __restrict__ stats,
    float* __restrict__ bkc, float* __restrict__ acc,
    const float* __restrict__ Wb1, const float* __restrict__ bb1,
    const float* __restrict__ Wb2, const float* __restrict__ bb2,
    const float* __restrict__ Wf1, const float* __restrict__ bf1,
    const float* __restrict__ Wf2h, const float* __restrict__ bf2,
    int kb) {
    int n = blockIdx.x * 256 + threadIdx.x;
    int eb = blockIdx.y;
    int e = eb >> 3;
    int ek = e * NBK + kb;
    float mu = stats[eb * 2], rs = stats[eb * 2 + 1];
    const float* xb = x + ((size_t)(eb * 26 + 24) * 32) * 512 + n;

    for (int w = 0; w < 2; ++w) {
        float xn[32];
#pragma unroll
        for (int c = 0; c < 32; ++c)
            xn[c] = (xb[(size_t)w * 16384 + (size_t)c * 512] - mu) * rs;
        float hid[64];
#pragma unroll
        for (int d = 0; d < 64; ++d) {
            float a = bb1[ek * 64 + d];
#pragma unroll
            for (int c = 0; c < 32; ++c) a += Wb1[((size_t)ek * 64 + d) * 32 + c] * xn[c];
            hid[d] = fmaxf(a, 0.f);
        }
#pragma unroll
        for (int s = 0; s < 12; ++s) {
            float a = bb2[ek * 12 + s];
#pragma unroll
            for (int d = 0; d < 64; ++d) a += Wb2[((size_t)ek * 12 + s) * 64 + d] * hid[d];
            bkc[((size_t)(eb * 12 + s) * 512 + n) * 2 + w] -= a;
        }
        if (w == 1) {
            float hf[64];
#pragma unroll
            for (int d = 0; d < 64; ++d) {
                float a = bf1[ek * 64 + d];
#pragma unroll
                for (int c = 0; c < 32; ++c) a += Wf1[((size_t)ek * 64 + d) * 32 + c] * xn[c];
                hf[d] = fmaxf(a, 0.f);
            }
#pragma unroll
            for (int s = 0; s < 12; ++s) {
                float a = bf2[ek * 12 + s];
#pragma unroll
                for (int d = 0; d < 64; ++d) a += Wf2h[((size_t)ek * 12 + s) * 64 + d] * hf[d];
                acc[(size_t)(eb * 12 + s) * 512 + n] += a;
            }
        }
    }
}

// ---------------------------------------------------------------------------
__global__ __launch_bounds__(256) void k_final(const float* __restrict__ acc,
                                               const float* __restrict__ ew,
                                               float* __restrict__ out) {
    int i = blockIdx.x * 256 + threadIdx.x;  // 49152
    out[i] = ew[0] * acc[i] + ew[1] * acc[49152 + i];
}

// ---------------------------------------------------------------------------
extern "C" void kernel_launch(void* const* d_in, const int* in_sizes, int n_in,
                              void* d_out, int out_size, void* d_ws, size_t ws_size,
                              hipStream_t stream) {
    const float* X    = (const float*)d_in[0];
    const float* adj  = (const float*)d_in[1];
    const float* ew   = (const float*)d_in[2];
    const float* Wst  = (const float*)d_in[3];
    const float* bst  = (const float*)d_in[4];
    const float* Wf2  = (const float*)d_in[5];
    const float* Wf3  = (const float*)d_in[6];
    const float* Wf5  = (const float*)d_in[7];
    const float* Wf7  = (const float*)d_in[8];
    const float* bf   = (const float*)d_in[9];
    const float* Wg2  = (const float*)d_in[10];
    const float* Wg3  = (const float*)d_in[11];
    const float* Wg5  = (const float*)d_in[12];
    const float* Wg7  = (const float*)d_in[13];
    const float* bg   = (const float*)d_in[14];
    const float* Wgc1 = (const float*)d_in[15];
    const float* bgc1 = (const float*)d_in[16];
    const float* Wgc2 = (const float*)d_in[17];
    const float* bgc2 = (const float*)d_in[18];
    const float* Wb1  = (const float*)d_in[19];
    const float* bb1  = (const float*)d_in[20];
    const float* Wb2  = (const float*)d_in[21];
    const float* bb2  = (const float*)d_in[22];
    const float* Wfc1 = (const float*)d_in[23];
    const float* bfc1 = (const float*)d_in[24];
    const float* Wfc2 = (const float*)d_in[25];
    const float* bfc2 = (const float*)d_in[26];

    float* ws = (float*)d_ws;
    size_t off = 0;
    auto alloc = [&](size_t nf) { float* p = ws + off; off += nf; return p; };
    float* di    = alloc(512);
    float* An    = alloc(512 * 512);
    float* AnT   = alloc(512 * 512);
    float* bkc   = alloc((size_t)EE * BATCH * 12 * 512 * 2);
    float* acc   = alloc((size_t)EE * BATCH * 12 * 512);
    float* stats = alloc(32);
    float* mixT  = alloc(2 * 5 * 32 * 32);
    float* bsum  = alloc(64);
    float* x     = alloc((size_t)16 * 26 * 32 * 512);
    size_t hbuf  = (size_t)16 * 20 * 32 * 512;  // Lmax = 20
    float* h   = alloc(hbuf);
    float* u1  = alloc(hbuf);
    float* v1  = alloc(hbuf);
    float* u1t = alloc(hbuf);
    float* v1t = alloc(hbuf);
    if (off * sizeof(float) > ws_size) return;  // workspace too small: bail

    // Graph normalization
    k_rowsum<<<512, 256, 0, stream>>>(adj, di);
    k_norm<<<1024, 256, 0, stream>>>(adj, di, An, AnT);

    // Residual init (both experts start from X) + output accumulator zero
    hipMemcpyAsync(bkc, X, (size_t)98304 * 4, hipMemcpyDeviceToDevice, stream);
    hipMemcpyAsync(bkc + 98304, X, (size_t)98304 * 4, hipMemcpyDeviceToDevice, stream);
    hipMemsetAsync(acc, 0, (size_t)EE * BATCH * 12 * 512 * 4, stream);

    for (int kb = 0; kb < NBK; ++kb) {
        k_prepmix<<<2, 256, 0, stream>>>(Wgc1, bgc1, Wgc2, bgc2, mixT, bsum, kb);
        k_start<<<dim3(2, 26, 16), 256, 0, stream>>>(bkc, x, Wst, bst, kb);
        int cur = 26;
        for (int it = 0; it < 4; ++it) {
            int L = cur - 6;
            k_incept<<<dim3(2, L, 16), 256, 0, stream>>>(
                x, h, Wf2, Wf3, Wf5, Wf7, bf, Wg2, Wg3, Wg5, Wg7, bg, kb, cur, L);
            int M = 512 * L;
            k_gemm<<<dim3(M / 128, 4, 2), 256, 0, stream>>>(h, An, u1, h, AnT, u1t, M);
            k_gemm<<<dim3(M / 128, 4, 2), 256, 0, stream>>>(u1, An, v1, u1t, AnT, v1t, M);
            k_combine<<<dim3(2, L, 16), 256, 0, stream>>>(x, h, u1, v1, u1t, v1t, mixT,
                                                          bsum, L);
            cur -= 6;
        }
        k_lnstats<<<16, 256, 0, stream>>>(x, stats);
        k_heads<<<dim3(2, 16), 256, 0, stream>>>(x, stats, bkc, acc, Wb1, bb1, Wb2, bb2,
                                                 Wfc1, bfc1, Wfc2, bfc2, kb);
    }
    k_final<<<192, 256, 0, stream>>>(acc, ew, (float*)d_out);
}

// Round 4
// 2405.530 us; speedup vs baseline: 1.4120x; 1.4120x over previous
//
#include <hip/hip_runtime.h>
#include <stddef.h>

// Problem constants (E=2 experts, NB=2 blocks, B=8 batch, N=512 nodes)
#define EE 2
#define NBK 2
#define BATCH 8

typedef unsigned short ushort_t;
typedef short bf16x8 __attribute__((ext_vector_type(8)));
typedef float f32x4 __attribute__((ext_vector_type(4)));

__device__ __forceinline__ ushort_t f2bf(float f) {
    unsigned int u = __float_as_uint(f);
    u += 0x7FFF + ((u >> 16) & 1);
    return (ushort_t)(u >> 16);
}
__device__ __forceinline__ float bf2f(ushort_t h) {
    return __uint_as_float(((unsigned int)h) << 16);
}

// ---------------------------------------------------------------------------
// A-normalization: di[v] = rsqrt(sum_w (adj[v,w] + I))
__global__ __launch_bounds__(256) void k_rowsum(const float* __restrict__ adj,
                                                float* __restrict__ di) {
    int v = blockIdx.x;
    int tid = threadIdx.x;
    float s = 0.f;
    for (int w = tid; w < 512; w += 256)
        s += adj[v * 512 + w] + (w == v ? 1.f : 0.f);
    for (int off = 32; off; off >>= 1) s += __shfl_down(s, off);
    __shared__ float red[4];
    if ((tid & 63) == 0) red[tid >> 6] = s;
    __syncthreads();
    if (tid == 0) {
        float t = red[0] + red[1] + red[2] + red[3];
        di[v] = rsqrtf(t);
    }
}

// An[v,w] (bf16) = di[v]*(adj+I)[v,w]*di[w]; AnT = An^T
__global__ __launch_bounds__(256) void k_norm(const float* __restrict__ adj,
                                              const float* __restrict__ di,
                                              ushort_t* __restrict__ An,
                                              ushort_t* __restrict__ AnT) {
    int idx = blockIdx.x * 256 + threadIdx.x;  // 0..262143
    int v = idx >> 9, w = idx & 511;
    float a = adj[idx] + (v == w ? 1.f : 0.f);
    ushort_t val = f2bf(di[v] * a * di[w]);
    An[idx] = val;
    AnT[w * 512 + v] = val;
}

// ---------------------------------------------------------------------------
// start: x[eb, t, c, n] = b_start[c] + W_start[c,0]*in0 + W_start[c,1]*in1
__global__ __launch_bounds__(256) void k_start(const float* __restrict__ bkc,
                                               float* __restrict__ x,
                                               const float* __restrict__ Wst,
                                               const float* __restrict__ bst,
                                               int kb) {
    int n = blockIdx.x * 256 + threadIdx.x;
    int t = blockIdx.y;
    int eb = blockIdx.z;
    int e = eb >> 3;
    int ek = e * NBK + kb;
    const float* Wp = Wst + (size_t)ek * 32 * 2;
    const float* bp = bst + (size_t)ek * 32;
    float in0 = 0.f, in1 = 0.f;
    if (t >= 14) {
        const float* p = bkc + ((size_t)(eb * 12 + (t - 14)) * 512 + n) * 2;
        in0 = p[0];
        in1 = p[1];
    }
    float* xo = x + ((size_t)(eb * 26 + t) * 32) * 512 + n;
#pragma unroll
    for (int c = 0; c < 32; ++c) {
        xo[(size_t)c * 512] = bp[c] + Wp[c * 2] * in0 + Wp[c * 2 + 1] * in1;
    }
}

// ---------------------------------------------------------------------------
// inception + gating: h[col][n] (bf16), col = (eb*L + j)*32 + c
__global__ __launch_bounds__(256) void k_incept(
    const float* __restrict__ x, ushort_t* __restrict__ h,
    const float* __restrict__ Wf2, const float* __restrict__ Wf3,
    const float* __restrict__ Wf5, const float* __restrict__ Wf7,
    const float* __restrict__ bf,
    const float* __restrict__ Wg2, const float* __restrict__ Wg3,
    const float* __restrict__ Wg5, const float* __restrict__ Wg7,
    const float* __restrict__ bg,
    int kb, int cur_len, int L) {
    int n = blockIdx.x * 256 + threadIdx.x;
    int j = blockIdx.y;
    int eb = blockIdx.z;
    int e = eb >> 3;
    int ek = e * NBK + kb;
    int t0 = 26 - cur_len + j;
    const float* xb = x + ((size_t)eb * 26 * 32) * 512 + n;

    float af[32], ag[32];
#pragma unroll
    for (int o = 0; o < 32; ++o) {
        af[o] = bf[ek * 32 + o];
        ag[o] = bg[ek * 32 + o];
    }
    const float* wf2 = Wf2 + (size_t)ek * 512;   // [oo][c][2]
    const float* wf3 = Wf3 + (size_t)ek * 768;   // [oo][c][3]
    const float* wf5 = Wf5 + (size_t)ek * 1280;  // [oo][c][5]
    const float* wf7 = Wf7 + (size_t)ek * 1792;  // [oo][c][7]
    const float* wg2 = Wg2 + (size_t)ek * 512;
    const float* wg3 = Wg3 + (size_t)ek * 768;
    const float* wg5 = Wg5 + (size_t)ek * 1280;
    const float* wg7 = Wg7 + (size_t)ek * 1792;

    for (int c = 0; c < 32; ++c) {
        float w0 = xb[(size_t)((t0 + 0) * 32 + c) * 512];
        float w1 = xb[(size_t)((t0 + 1) * 32 + c) * 512];
        float w2 = xb[(size_t)((t0 + 2) * 32 + c) * 512];
        float w3 = xb[(size_t)((t0 + 3) * 32 + c) * 512];
        float w4 = xb[(size_t)((t0 + 4) * 32 + c) * 512];
        float w5 = xb[(size_t)((t0 + 5) * 32 + c) * 512];
        float w6 = xb[(size_t)((t0 + 6) * 32 + c) * 512];
#pragma unroll
        for (int oo = 0; oo < 8; ++oo) {
            af[oo]      += wf2[oo * 64 + c * 2 + 0] * w5 + wf2[oo * 64 + c * 2 + 1] * w6;
            af[8 + oo]  += wf3[oo * 96 + c * 3 + 0] * w4 + wf3[oo * 96 + c * 3 + 1] * w5 +
                           wf3[oo * 96 + c * 3 + 2] * w6;
            af[16 + oo] += wf5[oo * 160 + c * 5 + 0] * w2 + wf5[oo * 160 + c * 5 + 1] * w3 +
                           wf5[oo * 160 + c * 5 + 2] * w4 + wf5[oo * 160 + c * 5 + 3] * w5 +
                           wf5[oo * 160 + c * 5 + 4] * w6;
            af[24 + oo] += wf7[oo * 224 + c * 7 + 0] * w0 + wf7[oo * 224 + c * 7 + 1] * w1 +
                           wf7[oo * 224 + c * 7 + 2] * w2 + wf7[oo * 224 + c * 7 + 3] * w3 +
                           wf7[oo * 224 + c * 7 + 4] * w4 + wf7[oo * 224 + c * 7 + 5] * w5 +
                           wf7[oo * 224 + c * 7 + 6] * w6;
            ag[oo]      += wg2[oo * 64 + c * 2 + 0] * w5 + wg2[oo * 64 + c * 2 + 1] * w6;
            ag[8 + oo]  += wg3[oo * 96 + c * 3 + 0] * w4 + wg3[oo * 96 + c * 3 + 1] * w5 +
                           wg3[oo * 96 + c * 3 + 2] * w6;
            ag[16 + oo] += wg5[oo * 160 + c * 5 + 0] * w2 + wg5[oo * 160 + c * 5 + 1] * w3 +
                           wg5[oo * 160 + c * 5 + 2] * w4 + wg5[oo * 160 + c * 5 + 3] * w5 +
                           wg5[oo * 160 + c * 5 + 4] * w6;
            ag[24 + oo] += wg7[oo * 224 + c * 7 + 0] * w0 + wg7[oo * 224 + c * 7 + 1] * w1 +
                           wg7[oo * 224 + c * 7 + 2] * w2 + wg7[oo * 224 + c * 7 + 3] * w3 +
                           wg7[oo * 224 + c * 7 + 4] * w4 + wg7[oo * 224 + c * 7 + 5] * w5 +
                           wg7[oo * 224 + c * 7 + 6] * w6;
        }
    }
    size_t colbase = ((size_t)eb * L + j) * 32;
#pragma unroll
    for (int c = 0; c < 32; ++c) {
        float fv = tanhf(af[c]);
        float gv = 1.f / (1.f + expf(-ag[c]));
        h[(colbase + c) * 512 + n] = f2bf(fv * gv);
    }
}

// ---------------------------------------------------------------------------
// bf16 MFMA NT GEMM: C[m][v] = sum_w A[m][w] * B[v][w]; K=N=512, M % 256 == 0.
// A,B,C bf16 (C rounded from f32 acc). Two problems batched via blockIdx.z.
// Fragment mapping (v_mfma_f32_16x16x32_bf16):
//   A: row = lane&15, k = 8*(lane>>4)+j (contig 8 -> one 16B load)
//   B: col = lane&15, k = 8*(lane>>4)+j (An row-major [v][w], w contig -> 16B)
//   D: col = lane&15, row = 4*(lane>>4)+r   [m89-verified]
__global__ __launch_bounds__(256) void k_gemm_bf16(
    const ushort_t* __restrict__ A0, const ushort_t* __restrict__ B0,
    ushort_t* __restrict__ C0,
    const ushort_t* __restrict__ A1, const ushort_t* __restrict__ B1,
    ushort_t* __restrict__ C1) {
    const ushort_t* A = blockIdx.z ? A1 : A0;
    const ushort_t* B = blockIdx.z ? B1 : B0;
    ushort_t* C = blockIdx.z ? C1 : C0;
    int tid = threadIdx.x;
    int w = tid >> 6, lane = tid & 63;
    int l15 = lane & 15, lg = lane >> 4;
    int wbase = blockIdx.x * 256 + w * 64;  // 64 rows per wave
    int n0 = blockIdx.y * 64;               // 64 cols per block
    f32x4 acc[4][4] = {};
    const ushort_t* Ap = A + (size_t)(wbase + l15) * 512 + lg * 8;
    const ushort_t* Bp = B + (size_t)(n0 + l15) * 512 + lg * 8;
#pragma unroll 4
    for (int k0 = 0; k0 < 512; k0 += 32) {
        bf16x8 av[4], bv[4];
#pragma unroll
        for (int mf = 0; mf < 4; ++mf)
            av[mf] = *(const bf16x8*)(Ap + (size_t)mf * 16 * 512 + k0);
#pragma unroll
        for (int nf = 0; nf < 4; ++nf)
            bv[nf] = *(const bf16x8*)(Bp + (size_t)nf * 16 * 512 + k0);
#pragma unroll
        for (int mf = 0; mf < 4; ++mf)
#pragma unroll
            for (int nf = 0; nf < 4; ++nf)
                acc[mf][nf] = __builtin_amdgcn_mfma_f32_16x16x32_bf16(
                    av[mf], bv[nf], acc[mf][nf], 0, 0, 0);
    }
#pragma unroll
    for (int mf = 0; mf < 4; ++mf)
#pragma unroll
        for (int nf = 0; nf < 4; ++nf)
#pragma unroll
            for (int r = 0; r < 4; ++r) {
                int row = wbase + 16 * mf + 4 * lg + r;
                int col = n0 + 16 * nf + l15;
                C[(size_t)row * 512 + col] = f2bf(acc[mf][nf][r]);
            }
}

// ---------------------------------------------------------------------------
// Precompute effective channel-mix matrices (transposed [cp][c]) and bias sum.
__global__ __launch_bounds__(256) void k_prepmix(const float* __restrict__ Wgc1,
                                                 const float* __restrict__ bgc1,
                                                 const float* __restrict__ Wgc2,
                                                 const float* __restrict__ bgc2,
                                                 float* __restrict__ mixT,
                                                 float* __restrict__ bsum, int kb) {
    int e = blockIdx.x;
    int ek = e * NBK + kb;
    const float* W1 = Wgc1 + (size_t)ek * 32 * 96;
    const float* W2 = Wgc2 + (size_t)ek * 32 * 96;
    for (int idx = threadIdx.x; idx < 5 * 32 * 32; idx += 256) {
        int m = idx >> 10, cp = (idx >> 5) & 31, c = idx & 31;
        float w0 = W1[c * 96 + cp], w1 = W1[c * 96 + 32 + cp], w2 = W1[c * 96 + 64 + cp];
        float v0 = W2[c * 96 + cp], v1 = W2[c * 96 + 32 + cp], v2 = W2[c * 96 + 64 + cp];
        float val;
        if (m == 0) val = w0 + w1 + w2 + v0 + v1 + v2;
        else if (m == 1) val = 0.5f * w1 + w2;
        else if (m == 2) val = 0.25f * w2;
        else if (m == 3) val = 0.5f * v1 + v2;
        else val = 0.25f * v2;
        mixT[((size_t)(e * 5 + m) * 32 + cp) * 32 + c] = val;
    }
    if (threadIdx.x < 32)
        bsum[e * 32 + threadIdx.x] =
            bgc1[ek * 32 + threadIdx.x] + bgc2[ek * 32 + threadIdx.x];
}

// ---------------------------------------------------------------------------
// combine: g[c] = bsum[c] + sum_m sum_cp mixT[m][cp][c]*buf_m[cp]; x -= 0.25*g
// buffers bf16
__global__ __launch_bounds__(256) void k_combine(
    float* __restrict__ x, const ushort_t* __restrict__ h,
    const ushort_t* __restrict__ u1, const ushort_t* __restrict__ v1,
    const ushort_t* __restrict__ u1t, const ushort_t* __restrict__ v1t,
    const float* __restrict__ mixT, const float* __restrict__ bsum, int L) {
    int n = blockIdx.x * 256 + threadIdx.x;
    int j = blockIdx.y;
    int eb = blockIdx.z;
    int e = eb >> 3;
    size_t colbase = ((size_t)eb * L + j) * 32;
    const ushort_t* bufs[5] = {h, u1, v1, u1t, v1t};
    float g[32];
#pragma unroll
    for (int c = 0; c < 32; ++c) g[c] = bsum[e * 32 + c];
#pragma unroll
    for (int m = 0; m < 5; ++m) {
        const ushort_t* in = bufs[m] + colbase * 512 + n;
        const float* Mp = mixT + ((size_t)(e * 5 + m) * 32) * 32;
        for (int cp = 0; cp < 32; ++cp) {
            float v = bf2f(in[(size_t)cp * 512]);
#pragma unroll
            for (int c = 0; c < 32; ++c) g[c] += Mp[cp * 32 + c] * v;
        }
    }
    int t = 26 - L + j;
    float* xo = x + ((size_t)(eb * 26 + t) * 32) * 512 + n;
#pragma unroll
    for (int c = 0; c < 32; ++c) xo[(size_t)c * 512] -= 0.25f * g[c];
}

// ---------------------------------------------------------------------------
// layernorm stats over x[..., t=24..25] (32768 contiguous floats per eb)
__global__ __launch_bounds__(256) void k_lnstats(const float* __restrict__ x,
                                                 float* __restrict__ stats) {
    int eb = blockIdx.x;
    const float* p = x + ((size_t)(eb * 26 + 24) * 32) * 512;
    float s = 0.f, s2 = 0.f;
    for (int i = threadIdx.x; i < 32768; i += 256) {
        float v = p[i];
        s += v;
        s2 += v * v;
    }
    for (int off = 32; off; off >>= 1) {
        s += __shfl_down(s, off);
        s2 += __shfl_down(s2, off);
    }
    __shared__ float r1[4], r2[4];
    if ((threadIdx.x & 63) == 0) {
        r1[threadIdx.x >> 6] = s;
        r2[threadIdx.x >> 6] = s2;
    }
    __syncthreads();
    if (threadIdx.x == 0) {
        float S = r1[0] + r1[1] + r1[2] + r1[3];
        float S2 = r2[0] + r2[1] + r2[2] + r2[3];
        float mu = S / 32768.f;
        float var = S2 / 32768.f - mu * mu;
        stats[eb * 2] = mu;
        stats[eb * 2 + 1] = rsqrtf(var + 1e-5f);
    }
}

// ---------------------------------------------------------------------------
// heads: layernorm-apply + bc head (update bkc) + fc head (accumulate acc)
__global__ __launch_bounds__(256) void k_heads(
    const float* __restrict__ x, const float* __restrict__ stats,
    float* __restrict__ bkc, float* __restrict__ acc,
    const float* __restrict__ Wb1, const float* __restrict__ bb1,
    const float* __restrict__ Wb2, const float* __restrict__ bb2,
    const float* __restrict__ Wf1, const float* __restrict__ bf1,
    const float* __restrict__ Wf2h, const float* __restrict__ bf2,
    int kb) {
    int n = blockIdx.x * 256 + threadIdx.x;
    int eb = blockIdx.y;
    int e = eb >> 3;
    int ek = e * NBK + kb;
    float mu = stats[eb * 2], rs = stats[eb * 2 + 1];
    const float* xb = x + ((size_t)(eb * 26 + 24) * 32) * 512 + n;

    for (int w = 0; w < 2; ++w) {
        float xn[32];
#pragma unroll
        for (int c = 0; c < 32; ++c)
            xn[c] = (xb[(size_t)w * 16384 + (size_t)c * 512] - mu) * rs;
        float hid[64];
#pragma unroll
        for (int d = 0; d < 64; ++d) {
            float a = bb1[ek * 64 + d];
#pragma unroll
            for (int c = 0; c < 32; ++c) a += Wb1[((size_t)ek * 64 + d) * 32 + c] * xn[c];
            hid[d] = fmaxf(a, 0.f);
        }
#pragma unroll
        for (int s = 0; s < 12; ++s) {
            float a = bb2[ek * 12 + s];
#pragma unroll
            for (int d = 0; d < 64; ++d) a += Wb2[((size_t)ek * 12 + s) * 64 + d] * hid[d];
            bkc[((size_t)(eb * 12 + s) * 512 + n) * 2 + w] -= a;
        }
        if (w == 1) {
            float hf[64];
#pragma unroll
            for (int d = 0; d < 64; ++d) {
                float a = bf1[ek * 64 + d];
#pragma unroll
                for (int c = 0; c < 32; ++c) a += Wf1[((size_t)ek * 64 + d) * 32 + c] * xn[c];
                hf[d] = fmaxf(a, 0.f);
            }
#pragma unroll
            for (int s = 0; s < 12; ++s) {
                float a = bf2[ek * 12 + s];
#pragma unroll
                for (int d = 0; d < 64; ++d) a += Wf2h[((size_t)ek * 12 + s) * 64 + d] * hf[d];
                acc[(size_t)(eb * 12 + s) * 512 + n] += a;
            }
        }
    }
}

// ---------------------------------------------------------------------------
__global__ __launch_bounds__(256) void k_final(const float* __restrict__ acc,
                                               const float* __restrict__ ew,
                                               float* __restrict__ out) {
    int i = blockIdx.x * 256 + threadIdx.x;  // 49152
    out[i] = ew[0] * acc[i] + ew[1] * acc[49152 + i];
}

// ---------------------------------------------------------------------------
extern "C" void kernel_launch(void* const* d_in, const int* in_sizes, int n_in,
                              void* d_out, int out_size, void* d_ws, size_t ws_size,
                              hipStream_t stream) {
    const float* X    = (const float*)d_in[0];
    const float* adj  = (const float*)d_in[1];
    const float* ew   = (const float*)d_in[2];
    const float* Wst  = (const float*)d_in[3];
    const float* bst  = (const float*)d_in[4];
    const float* Wf2  = (const float*)d_in[5];
    const float* Wf3  = (const float*)d_in[6];
    const float* Wf5  = (const float*)d_in[7];
    const float* Wf7  = (const float*)d_in[8];
    const float* bf   = (const float*)d_in[9];
    const float* Wg2  = (const float*)d_in[10];
    const float* Wg3  = (const float*)d_in[11];
    const float* Wg5  = (const float*)d_in[12];
    const float* Wg7  = (const float*)d_in[13];
    const float* bg   = (const float*)d_in[14];
    const float* Wgc1 = (const float*)d_in[15];
    const float* bgc1 = (const float*)d_in[16];
    const float* Wgc2 = (const float*)d_in[17];
    const float* bgc2 = (const float*)d_in[18];
    const float* Wb1  = (const float*)d_in[19];
    const float* bb1  = (const float*)d_in[20];
    const float* Wb2  = (const float*)d_in[21];
    const float* bb2  = (const float*)d_in[22];
    const float* Wfc1 = (const float*)d_in[23];
    const float* bfc1 = (const float*)d_in[24];
    const float* Wfc2 = (const float*)d_in[25];
    const float* bfc2 = (const float*)d_in[26];

    float* ws = (float*)d_ws;
    size_t off = 0;
    auto alloc = [&](size_t nf) { float* p = ws + off; off += nf; return p; };
    float* di    = alloc(512);
    ushort_t* Anb  = (ushort_t*)alloc(512 * 512 / 2 * 2);  // 262144 ushorts
    ushort_t* AnTb = (ushort_t*)alloc(512 * 512 / 2 * 2);
    float* bkc   = alloc((size_t)EE * BATCH * 12 * 512 * 2);
    float* acc   = alloc((size_t)EE * BATCH * 12 * 512);
    float* stats = alloc(32);
    float* mixT  = alloc(2 * 5 * 32 * 32);
    float* bsum  = alloc(64);
    float* x     = alloc((size_t)16 * 26 * 32 * 512);
    size_t hbuf_f = (size_t)16 * 20 * 32 * 512 / 2;  // bf16 buffers, float units
    ushort_t* h   = (ushort_t*)alloc(hbuf_f);
    ushort_t* u1  = (ushort_t*)alloc(hbuf_f);
    ushort_t* v1  = (ushort_t*)alloc(hbuf_f);
    ushort_t* u1t = (ushort_t*)alloc(hbuf_f);
    ushort_t* v1t = (ushort_t*)alloc(hbuf_f);
    if (off * sizeof(float) > ws_size) return;  // workspace too small: bail

    // Graph normalization
    k_rowsum<<<512, 256, 0, stream>>>(adj, di);
    k_norm<<<1024, 256, 0, stream>>>(adj, di, Anb, AnTb);

    // Residual init (both experts start from X) + output accumulator zero
    hipMemcpyAsync(bkc, X, (size_t)98304 * 4, hipMemcpyDeviceToDevice, stream);
    hipMemcpyAsync(bkc + 98304, X, (size_t)98304 * 4, hipMemcpyDeviceToDevice, stream);
    hipMemsetAsync(acc, 0, (size_t)EE * BATCH * 12 * 512 * 4, stream);

    for (int kb = 0; kb < NBK; ++kb) {
        k_prepmix<<<2, 256, 0, stream>>>(Wgc1, bgc1, Wgc2, bgc2, mixT, bsum, kb);
        k_start<<<dim3(2, 26, 16), 256, 0, stream>>>(bkc, x, Wst, bst, kb);
        int cur = 26;
        for (int it = 0; it < 4; ++it) {
            int L = cur - 6;
            k_incept<<<dim3(2, L, 16), 256, 0, stream>>>(
                x, h, Wf2, Wf3, Wf5, Wf7, bf, Wg2, Wg3, Wg5, Wg7, bg, kb, cur, L);
            // M = 512*L rows; grid.x = M/256 = 2L
            k_gemm_bf16<<<dim3(2 * L, 8, 2), 256, 0, stream>>>(h, Anb, u1, h, AnTb, u1t);
            k_gemm_bf16<<<dim3(2 * L, 8, 2), 256, 0, stream>>>(u1, Anb, v1, u1t, AnTb, v1t);
            k_combine<<<dim3(2, L, 16), 256, 0, stream>>>(x, h, u1, v1, u1t, v1t, mixT,
                                                          bsum, L);
            cur -= 6;
        }
        k_lnstats<<<16, 256, 0, stream>>>(x, stats);
        k_heads<<<dim3(2, 16), 256, 0, stream>>>(x, stats, bkc, acc, Wb1, bb1, Wb2, bb2,
                                                 Wfc1, bfc1, Wfc2, bfc2, kb);
    }
    k_final<<<192, 256, 0, stream>>>(acc, ew, (float*)d_out);
}

// Round 5
// 1489.254 us; speedup vs baseline: 2.2807x; 1.6153x over previous
//
#include <hip/hip_runtime.h>
#include <stddef.h>

// Problem constants (E=2 experts, NB=2 blocks, B=8 batch, N=512 nodes)
#define EE 2
#define NBK 2
#define BATCH 8

typedef unsigned short ushort_t;
typedef short bf16x8 __attribute__((ext_vector_type(8)));
typedef float f32x4 __attribute__((ext_vector_type(4)));

__device__ __forceinline__ ushort_t f2bf(float f) {
    unsigned int u = __float_as_uint(f);
    u += 0x7FFF + ((u >> 16) & 1);
    return (ushort_t)(u >> 16);
}
__device__ __forceinline__ float bf2f(ushort_t h) {
    return __uint_as_float(((unsigned int)h) << 16);
}

// ---------------------------------------------------------------------------
__global__ __launch_bounds__(256) void k_rowsum(const float* __restrict__ adj,
                                                float* __restrict__ di) {
    int v = blockIdx.x;
    int tid = threadIdx.x;
    float s = 0.f;
    for (int w = tid; w < 512; w += 256)
        s += adj[v * 512 + w] + (w == v ? 1.f : 0.f);
    for (int off = 32; off; off >>= 1) s += __shfl_down(s, off);
    __shared__ float red[4];
    if ((tid & 63) == 0) red[tid >> 6] = s;
    __syncthreads();
    if (tid == 0) {
        float t = red[0] + red[1] + red[2] + red[3];
        di[v] = rsqrtf(t);
    }
}

__global__ __launch_bounds__(256) void k_norm(const float* __restrict__ adj,
                                              const float* __restrict__ di,
                                              ushort_t* __restrict__ An,
                                              ushort_t* __restrict__ AnT) {
    int idx = blockIdx.x * 256 + threadIdx.x;  // 0..262143
    int v = idx >> 9, w = idx & 511;
    float a = adj[idx] + (v == w ? 1.f : 0.f);
    ushort_t val = f2bf(di[v] * a * di[w]);
    An[idx] = val;
    AnT[w * 512 + v] = val;
}

// ---------------------------------------------------------------------------
// Pack inception weights into dense bf16 Weff[e][fg][dt][ot][o16][c32]
// (zero-padded taps: kernel size ks occupies dt in [7-ks, 7))
__global__ __launch_bounds__(256) void k_prepw(
    const float* __restrict__ Wf2, const float* __restrict__ Wf3,
    const float* __restrict__ Wf5, const float* __restrict__ Wf7,
    const float* __restrict__ Wg2, const float* __restrict__ Wg3,
    const float* __restrict__ Wg5, const float* __restrict__ Wg7,
    ushort_t* __restrict__ Wb, int kb) {
    int idx = blockIdx.x * 256 + threadIdx.x;  // 28672 total
    if (idx >= 2 * 2 * 7 * 2 * 16 * 32) return;
    int c = idx & 31;
    int t1 = idx >> 5;
    int o16 = t1 & 15;
    int t2 = t1 >> 4;
    int ot = t2 & 1;
    int t3 = t2 >> 1;
    int dt = t3 % 7;
    int t4 = t3 / 7;
    int fg = t4 & 1;
    int e = t4 >> 1;
    int ek = e * NBK + kb;
    int o = ot * 16 + o16;
    int grp = o >> 3, oo = o & 7;
    const int kstab[4] = {2, 3, 5, 7};
    int ks = kstab[grp];
    int lo = 7 - ks;
    float val = 0.f;
    if (dt >= lo) {
        int di = dt - lo;
        const float* W;
        if (grp == 0) W = (fg ? Wg2 : Wf2) + (size_t)ek * 512 + oo * 64 + c * 2 + di;
        else if (grp == 1) W = (fg ? Wg3 : Wf3) + (size_t)ek * 768 + oo * 96 + c * 3 + di;
        else if (grp == 2) W = (fg ? Wg5 : Wf5) + (size_t)ek * 1280 + oo * 160 + c * 5 + di;
        else W = (fg ? Wg7 : Wf7) + (size_t)ek * 1792 + oo * 224 + c * 7 + di;
        val = *W;
    }
    Wb[idx] = f2bf(val);
}

// ---------------------------------------------------------------------------
// start: writes x fp32 [eb][t][c][n] and bf16 mirror xb [eb][t][n][c]
__global__ __launch_bounds__(256) void k_start(const float* __restrict__ bkc,
                                               float* __restrict__ x,
                                               ushort_t* __restrict__ xb,
                                               const float* __restrict__ Wst,
                                               const float* __restrict__ bst,
                                               int kb) {
    int n = blockIdx.x * 256 + threadIdx.x;
    int t = blockIdx.y;
    int eb = blockIdx.z;
    int e = eb >> 3;
    int ek = e * NBK + kb;
    const float* Wp = Wst + (size_t)ek * 32 * 2;
    const float* bp = bst + (size_t)ek * 32;
    float in0 = 0.f, in1 = 0.f;
    if (t >= 14) {
        const float* p = bkc + ((size_t)(eb * 12 + (t - 14)) * 512 + n) * 2;
        in0 = p[0];
        in1 = p[1];
    }
    float* xo = x + ((size_t)(eb * 26 + t) * 32) * 512 + n;
    ushort_t tmp[32];
#pragma unroll
    for (int c = 0; c < 32; ++c) {
        float v = bp[c] + Wp[c * 2] * in0 + Wp[c * 2 + 1] * in1;
        xo[(size_t)c * 512] = v;
        tmp[c] = f2bf(v);
    }
    ushort_t* xbp = xb + ((size_t)(eb * 26 + t) * 512 + n) * 32;
#pragma unroll
    for (int q = 0; q < 4; ++q)
        *(bf16x8*)(xbp + q * 8) = *(bf16x8*)(tmp + q * 8);
}

// ---------------------------------------------------------------------------
// MFMA inception: h[(eb*L+j)*32+o][n] = tanh(f)*sigmoid(g),
// f/g[o][n] = bias + sum_dt sum_c Weff[fg][dt][o][c] * xb[t0+dt][n][c]
// block = 4 waves: wave w -> o-tile (w>>1), n-64-chunk (w&1); grid (4, L, 16)
__global__ __launch_bounds__(256) void k_incept_mfma(
    const ushort_t* __restrict__ xb, ushort_t* __restrict__ h,
    const ushort_t* __restrict__ Wb,
    const float* __restrict__ bf, const float* __restrict__ bg,
    int kb, int cur_len, int L) {
    int j = blockIdx.y, eb = blockIdx.z, e = eb >> 3, ek = e * NBK + kb;
    int tid = threadIdx.x;
    int w = tid >> 6, lane = tid & 63;
    int l15 = lane & 15, lg = lane >> 4;
    int ot = w >> 1;
    int n0base = blockIdx.x * 128 + (w & 1) * 64;
    int t0 = 26 - cur_len + j;

    // A fragments: row(o)=l15, k(c)=8*lg+jj
    const ushort_t* WbE = Wb + (size_t)e * 14336;
    bf16x8 af_[7], ag_[7];
#pragma unroll
    for (int dt = 0; dt < 7; ++dt) {
        af_[dt] = *(const bf16x8*)(WbE + ((size_t)(dt * 2 + ot) * 16 + l15) * 32 + lg * 8);
        ag_[dt] = *(const bf16x8*)(WbE + 7168 + ((size_t)(dt * 2 + ot) * 16 + l15) * 32 + lg * 8);
    }
    float bfv[4], bgv[4];
#pragma unroll
    for (int r = 0; r < 4; ++r) {
        int o = ot * 16 + 4 * lg + r;
        bfv[r] = bf[ek * 32 + o];
        bgv[r] = bg[ek * 32 + o];
    }
    size_t colbase = ((size_t)eb * L + j) * 32;
    const ushort_t* xe = xb + ((size_t)eb * 26) * 512 * 32;
#pragma unroll
    for (int nt = 0; nt < 4; ++nt) {
        int n0 = n0base + nt * 16;
        f32x4 accf = {}, accg = {};
#pragma unroll
        for (int dt = 0; dt < 7; ++dt) {
            bf16x8 bfr = *(const bf16x8*)(xe + ((size_t)(t0 + dt) * 512 + n0 + l15) * 32 + lg * 8);
            accf = __builtin_amdgcn_mfma_f32_16x16x32_bf16(af_[dt], bfr, accf, 0, 0, 0);
            accg = __builtin_amdgcn_mfma_f32_16x16x32_bf16(ag_[dt], bfr, accg, 0, 0, 0);
        }
#pragma unroll
        for (int r = 0; r < 4; ++r) {
            float a = accf[r] + bfv[r];
            float b = accg[r] + bgv[r];
            float hv = tanhf(a) * (1.f / (1.f + expf(-b)));
            int o = ot * 16 + 4 * lg + r;
            h[(colbase + o) * 512 + n0 + l15] = f2bf(hv);
        }
    }
}

// ---------------------------------------------------------------------------
// bf16 MFMA NT GEMM: C[m][v] = sum_w A[m][w] * B[v][w]; K=N=512, M % 256 == 0.
__global__ __launch_bounds__(256) void k_gemm_bf16(
    const ushort_t* __restrict__ A0, const ushort_t* __restrict__ B0,
    ushort_t* __restrict__ C0,
    const ushort_t* __restrict__ A1, const ushort_t* __restrict__ B1,
    ushort_t* __restrict__ C1) {
    const ushort_t* A = blockIdx.z ? A1 : A0;
    const ushort_t* B = blockIdx.z ? B1 : B0;
    ushort_t* C = blockIdx.z ? C1 : C0;
    int tid = threadIdx.x;
    int w = tid >> 6, lane = tid & 63;
    int l15 = lane & 15, lg = lane >> 4;
    int wbase = blockIdx.x * 256 + w * 64;  // 64 rows per wave
    int n0 = blockIdx.y * 64;               // 64 cols per block
    f32x4 acc[4][4] = {};
    const ushort_t* Ap = A + (size_t)(wbase + l15) * 512 + lg * 8;
    const ushort_t* Bp = B + (size_t)(n0 + l15) * 512 + lg * 8;
#pragma unroll 4
    for (int k0 = 0; k0 < 512; k0 += 32) {
        bf16x8 av[4], bv[4];
#pragma unroll
        for (int mf = 0; mf < 4; ++mf)
            av[mf] = *(const bf16x8*)(Ap + (size_t)mf * 16 * 512 + k0);
#pragma unroll
        for (int nf = 0; nf < 4; ++nf)
            bv[nf] = *(const bf16x8*)(Bp + (size_t)nf * 16 * 512 + k0);
#pragma unroll
        for (int mf = 0; mf < 4; ++mf)
#pragma unroll
            for (int nf = 0; nf < 4; ++nf)
                acc[mf][nf] = __builtin_amdgcn_mfma_f32_16x16x32_bf16(
                    av[mf], bv[nf], acc[mf][nf], 0, 0, 0);
    }
#pragma unroll
    for (int mf = 0; mf < 4; ++mf)
#pragma unroll
        for (int nf = 0; nf < 4; ++nf)
#pragma unroll
            for (int r = 0; r < 4; ++r) {
                int row = wbase + 16 * mf + 4 * lg + r;
                int col = n0 + 16 * nf + l15;
                C[(size_t)row * 512 + col] = f2bf(acc[mf][nf][r]);
            }
}

// ---------------------------------------------------------------------------
__global__ __launch_bounds__(256) void k_prepmix(const float* __restrict__ Wgc1,
                                                 const float* __restrict__ bgc1,
                                                 const float* __restrict__ Wgc2,
                                                 const float* __restrict__ bgc2,
                                                 float* __restrict__ mixT,
                                                 float* __restrict__ bsum, int kb) {
    int e = blockIdx.x;
    int ek = e * NBK + kb;
    const float* W1 = Wgc1 + (size_t)ek * 32 * 96;
    const float* W2 = Wgc2 + (size_t)ek * 32 * 96;
    for (int idx = threadIdx.x; idx < 5 * 32 * 32; idx += 256) {
        int m = idx >> 10, cp = (idx >> 5) & 31, c = idx & 31;
        float w0 = W1[c * 96 + cp], w1 = W1[c * 96 + 32 + cp], w2 = W1[c * 96 + 64 + cp];
        float v0 = W2[c * 96 + cp], v1 = W2[c * 96 + 32 + cp], v2 = W2[c * 96 + 64 + cp];
        float val;
        if (m == 0) val = w0 + w1 + w2 + v0 + v1 + v2;
        else if (m == 1) val = 0.5f * w1 + w2;
        else if (m == 2) val = 0.25f * w2;
        else if (m == 3) val = 0.5f * v1 + v2;
        else val = 0.25f * v2;
        mixT[((size_t)(e * 5 + m) * 32 + cp) * 32 + c] = val;
    }
    if (threadIdx.x < 32)
        bsum[e * 32 + threadIdx.x] =
            bgc1[ek * 32 + threadIdx.x] + bgc2[ek * 32 + threadIdx.x];
}

// ---------------------------------------------------------------------------
// combine: g[c] = bsum[c] + sum_m sum_cp mixT[m][cp][c]*buf_m[cp];
// x -= 0.25*g; also refresh bf16 mirror xb
__global__ __launch_bounds__(256) void k_combine(
    float* __restrict__ x, ushort_t* __restrict__ xb,
    const ushort_t* __restrict__ h,
    const ushort_t* __restrict__ u1, const ushort_t* __restrict__ v1,
    const ushort_t* __restrict__ u1t, const ushort_t* __restrict__ v1t,
    const float* __restrict__ mixT, const float* __restrict__ bsum, int L) {
    int n = blockIdx.x * 256 + threadIdx.x;
    int j = blockIdx.y;
    int eb = blockIdx.z;
    int e = eb >> 3;
    size_t colbase = ((size_t)eb * L + j) * 32;
    const ushort_t* bufs[5] = {h, u1, v1, u1t, v1t};
    float g[32];
#pragma unroll
    for (int c = 0; c < 32; ++c) g[c] = bsum[e * 32 + c];
#pragma unroll
    for (int m = 0; m < 5; ++m) {
        const ushort_t* in = bufs[m] + colbase * 512 + n;
        const float* Mp = mixT + ((size_t)(e * 5 + m) * 32) * 32;
        for (int cp = 0; cp < 32; ++cp) {
            float v = bf2f(in[(size_t)cp * 512]);
#pragma unroll
            for (int c = 0; c < 32; ++c) g[c] += Mp[cp * 32 + c] * v;
        }
    }
    int t = 26 - L + j;
    float* xo = x + ((size_t)(eb * 26 + t) * 32) * 512 + n;
    ushort_t tmp[32];
#pragma unroll
    for (int c = 0; c < 32; ++c) {
        float nv = xo[(size_t)c * 512] - 0.25f * g[c];
        xo[(size_t)c * 512] = nv;
        tmp[c] = f2bf(nv);
    }
    ushort_t* xbp = xb + ((size_t)(eb * 26 + t) * 512 + n) * 32;
#pragma unroll
    for (int q = 0; q < 4; ++q)
        *(bf16x8*)(xbp + q * 8) = *(bf16x8*)(tmp + q * 8);
}

// ---------------------------------------------------------------------------
__global__ __launch_bounds__(256) void k_lnstats(const float* __restrict__ x,
                                                 float* __restrict__ stats) {
    int eb = blockIdx.x;
    const float* p = x + ((size_t)(eb * 26 + 24) * 32) * 512;
    float s = 0.f, s2 = 0.f;
    for (int i = threadIdx.x; i < 32768; i += 256) {
        float v = p[i];
        s += v;
        s2 += v * v;
    }
    for (int off = 32; off; off >>= 1) {
        s += __shfl_down(s, off);
        s2 += __shfl_down(s2, off);
    }
    __shared__ float r1[4], r2[4];
    if ((threadIdx.x & 63) == 0) {
        r1[threadIdx.x >> 6] = s;
        r2[threadIdx.x >> 6] = s2;
    }
    __syncthreads();
    if (threadIdx.x == 0) {
        float S = r1[0] + r1[1] + r1[2] + r1[3];
        float S2 = r2[0] + r2[1] + r2[2] + r2[3];
        float mu = S / 32768.f;
        float var = S2 / 32768.f - mu * mu;
        stats[eb * 2] = mu;
        stats[eb * 2 + 1] = rsqrtf(var + 1e-5f);
    }
}

// ---------------------------------------------------------------------------
__global__ __launch_bounds__(256) void k_heads(
    const float* __restrict__ x, const float* __restrict__ stats,
    float* __restrict__ bkc, float* __restrict__ acc,
    const float* __restrict__ Wb1, const float* __restrict__ bb1,
    const float* __restrict__ Wb2, const float* __restrict__ bb2,
    const float* __restrict__ Wf1, const float* __restrict__ bf1,
    const float* __restrict__ Wf2h, const float* __restrict__ bf2,
    int kb) {
    int n = blockIdx.x * 256 + threadIdx.x;
    int eb = blockIdx.y;
    int e = eb >> 3;
    int ek = e * NBK + kb;
    float mu = stats[eb * 2], rs = stats[eb * 2 + 1];
    const float* xb = x + ((size_t)(eb * 26 + 24) * 32) * 512 + n;

    for (int w = 0; w < 2; ++w) {
        float xn[32];
#pragma unroll
        for (int c = 0; c < 32; ++c)
            xn[c] = (xb[(size_t)w * 16384 + (size_t)c * 512] - mu) * rs;
        float hid[64];
#pragma unroll
        for (int d = 0; d < 64; ++d) {
            float a = bb1[ek * 64 + d];
#pragma unroll
            for (int c = 0; c < 32; ++c) a += Wb1[((size_t)ek * 64 + d) * 32 + c] * xn[c];
            hid[d] = fmaxf(a, 0.f);
        }
#pragma unroll
        for (int s = 0; s < 12; ++s) {
            float a = bb2[ek * 12 + s];
#pragma unroll
            for (int d = 0; d < 64; ++d) a += Wb2[((size_t)ek * 12 + s) * 64 + d] * hid[d];
            bkc[((size_t)(eb * 12 + s) * 512 + n) * 2 + w] -= a;
        }
        if (w == 1) {
            float hf[64];
#pragma unroll
            for (int d = 0; d < 64; ++d) {
                float a = bf1[ek * 64 + d];
#pragma unroll
                for (int c = 0; c < 32; ++c) a += Wf1[((size_t)ek * 64 + d) * 32 + c] * xn[c];
                hf[d] = fmaxf(a, 0.f);
            }
#pragma unroll
            for (int s = 0; s < 12; ++s) {
                float a = bf2[ek * 12 + s];
#pragma unroll
                for (int d = 0; d < 64; ++d) a += Wf2h[((size_t)ek * 12 + s) * 64 + d] * hf[d];
                acc[(size_t)(eb * 12 + s) * 512 + n] += a;
            }
        }
    }
}

// ---------------------------------------------------------------------------
__global__ __launch_bounds__(256) void k_final(const float* __restrict__ acc,
                                               const float* __restrict__ ew,
                                               float* __restrict__ out) {
    int i = blockIdx.x * 256 + threadIdx.x;  // 49152
    out[i] = ew[0] * acc[i] + ew[1] * acc[49152 + i];
}

// ---------------------------------------------------------------------------
extern "C" void kernel_launch(void* const* d_in, const int* in_sizes, int n_in,
                              void* d_out, int out_size, void* d_ws, size_t ws_size,
                              hipStream_t stream) {
    const float* X    = (const float*)d_in[0];
    const float* adj  = (const float*)d_in[1];
    const float* ew   = (const float*)d_in[2];
    const float* Wst  = (const float*)d_in[3];
    const float* bst  = (const float*)d_in[4];
    const float* Wf2  = (const float*)d_in[5];
    const float* Wf3  = (const float*)d_in[6];
    const float* Wf5  = (const float*)d_in[7];
    const float* Wf7  = (const float*)d_in[8];
    const float* bf   = (const float*)d_in[9];
    const float* Wg2  = (const float*)d_in[10];
    const float* Wg3  = (const float*)d_in[11];
    const float* Wg5  = (const float*)d_in[12];
    const float* Wg7  = (const float*)d_in[13];
    const float* bg   = (const float*)d_in[14];
    const float* Wgc1 = (const float*)d_in[15];
    const float* bgc1 = (const float*)d_in[16];
    const float* Wgc2 = (const float*)d_in[17];
    const float* bgc2 = (const float*)d_in[18];
    const float* Wb1  = (const float*)d_in[19];
    const float* bb1  = (const float*)d_in[20];
    const float* Wb2  = (const float*)d_in[21];
    const float* bb2  = (const float*)d_in[22];
    const float* Wfc1 = (const float*)d_in[23];
    const float* bfc1 = (const float*)d_in[24];
    const float* Wfc2 = (const float*)d_in[25];
    const float* bfc2 = (const float*)d_in[26];

    float* ws = (float*)d_ws;
    size_t off = 0;
    auto alloc = [&](size_t nf) { float* p = ws + off; off += nf; return p; };
    float* di    = alloc(512);
    ushort_t* Anb  = (ushort_t*)alloc(512 * 512 / 2);
    ushort_t* AnTb = (ushort_t*)alloc(512 * 512 / 2);
    float* bkc   = alloc((size_t)EE * BATCH * 12 * 512 * 2);
    float* acc   = alloc((size_t)EE * BATCH * 12 * 512);
    float* stats = alloc(32);
    float* mixT  = alloc(2 * 5 * 32 * 32);
    float* bsum  = alloc(64);
    ushort_t* Wb = (ushort_t*)alloc(14336);          // 28672 ushorts
    float* x     = alloc((size_t)16 * 26 * 32 * 512);
    ushort_t* xb = (ushort_t*)alloc((size_t)16 * 26 * 512 * 32 / 2);
    size_t hbuf_f = (size_t)16 * 20 * 32 * 512 / 2;  // bf16 buffers, float units
    ushort_t* h   = (ushort_t*)alloc(hbuf_f);
    ushort_t* u1  = (ushort_t*)alloc(hbuf_f);
    ushort_t* v1  = (ushort_t*)alloc(hbuf_f);
    ushort_t* u1t = (ushort_t*)alloc(hbuf_f);
    ushort_t* v1t = (ushort_t*)alloc(hbuf_f);
    if (off * sizeof(float) > ws_size) return;  // workspace too small: bail

    // Graph normalization
    k_rowsum<<<512, 256, 0, stream>>>(adj, di);
    k_norm<<<1024, 256, 0, stream>>>(adj, di, Anb, AnTb);

    // Residual init (both experts start from X) + output accumulator zero
    hipMemcpyAsync(bkc, X, (size_t)98304 * 4, hipMemcpyDeviceToDevice, stream);
    hipMemcpyAsync(bkc + 98304, X, (size_t)98304 * 4, hipMemcpyDeviceToDevice, stream);
    hipMemsetAsync(acc, 0, (size_t)EE * BATCH * 12 * 512 * 4, stream);

    for (int kb = 0; kb < NBK; ++kb) {
        k_prepmix<<<2, 256, 0, stream>>>(Wgc1, bgc1, Wgc2, bgc2, mixT, bsum, kb);
        k_prepw<<<112, 256, 0, stream>>>(Wf2, Wf3, Wf5, Wf7, Wg2, Wg3, Wg5, Wg7, Wb, kb);
        k_start<<<dim3(2, 26, 16), 256, 0, stream>>>(bkc, x, xb, Wst, bst, kb);
        int cur = 26;
        for (int it = 0; it < 4; ++it) {
            int L = cur - 6;
            k_incept_mfma<<<dim3(4, L, 16), 256, 0, stream>>>(
                xb, h, Wb, bf, bg, kb, cur, L);
            // M = 512*L rows; grid.x = M/256 = 2L
            k_gemm_bf16<<<dim3(2 * L, 8, 2), 256, 0, stream>>>(h, Anb, u1, h, AnTb, u1t);
            k_gemm_bf16<<<dim3(2 * L, 8, 2), 256, 0, stream>>>(u1, Anb, v1, u1t, AnTb, v1t);
            k_combine<<<dim3(2, L, 16), 256, 0, stream>>>(x, xb, h, u1, v1, u1t, v1t,
                                                          mixT, bsum, L);
            cur -= 6;
        }
        k_lnstats<<<16, 256, 0, stream>>>(x, stats);
        k_heads<<<dim3(2, 16), 256, 0, stream>>>(x, stats, bkc, acc, Wb1, bb1, Wb2, bb2,
                                                 Wfc1, bfc1, Wfc2, bfc2, kb);
    }
    k_final<<<192, 256, 0, stream>>>(acc, ew, (float*)d_out);
}

// Round 6
// 1260.570 us; speedup vs baseline: 2.6945x; 1.1814x over previous
//
#include <hip/hip_runtime.h>
#include <stddef.h>

// Problem constants (E=2 experts, NB=2 blocks, B=8 batch, N=512 nodes)
#define EE 2
#define NBK 2
#define BATCH 8

typedef unsigned short ushort_t;
typedef short bf16x8 __attribute__((ext_vector_type(8)));
typedef float f32x4 __attribute__((ext_vector_type(4)));

__device__ __forceinline__ ushort_t f2bf(float f) {
    unsigned int u = __float_as_uint(f);
    u += 0x7FFF + ((u >> 16) & 1);
    return (ushort_t)(u >> 16);
}
__device__ __forceinline__ float bf2f(ushort_t h) {
    return __uint_as_float(((unsigned int)h) << 16);
}

// ---------------------------------------------------------------------------
__global__ __launch_bounds__(256) void k_rowsum(const float* __restrict__ adj,
                                                float* __restrict__ di) {
    int v = blockIdx.x;
    int tid = threadIdx.x;
    float s = 0.f;
    for (int w = tid; w < 512; w += 256)
        s += adj[v * 512 + w] + (w == v ? 1.f : 0.f);
    for (int off = 32; off; off >>= 1) s += __shfl_down(s, off);
    __shared__ float red[4];
    if ((tid & 63) == 0) red[tid >> 6] = s;
    __syncthreads();
    if (tid == 0) {
        float t = red[0] + red[1] + red[2] + red[3];
        di[v] = rsqrtf(t);
    }
}

__global__ __launch_bounds__(256) void k_norm(const float* __restrict__ adj,
                                              const float* __restrict__ di,
                                              ushort_t* __restrict__ An,
                                              ushort_t* __restrict__ AnT) {
    int idx = blockIdx.x * 256 + threadIdx.x;  // 0..262143
    int v = idx >> 9, w = idx & 511;
    float a = adj[idx] + (v == w ? 1.f : 0.f);
    ushort_t val = f2bf(di[v] * a * di[w]);
    An[idx] = val;
    AnT[w * 512 + v] = val;
}

// ---------------------------------------------------------------------------
// Pack inception weights into dense bf16 Weff[e][fg][dt][ot][o16][c32]
__global__ __launch_bounds__(256) void k_prepw(
    const float* __restrict__ Wf2, const float* __restrict__ Wf3,
    const float* __restrict__ Wf5, const float* __restrict__ Wf7,
    const float* __restrict__ Wg2, const float* __restrict__ Wg3,
    const float* __restrict__ Wg5, const float* __restrict__ Wg7,
    ushort_t* __restrict__ Wb, int kb) {
    int idx = blockIdx.x * 256 + threadIdx.x;  // 28672 total
    if (idx >= 2 * 2 * 7 * 2 * 16 * 32) return;
    int c = idx & 31;
    int t1 = idx >> 5;
    int o16 = t1 & 15;
    int t2 = t1 >> 4;
    int ot = t2 & 1;
    int t3 = t2 >> 1;
    int dt = t3 % 7;
    int t4 = t3 / 7;
    int fg = t4 & 1;
    int e = t4 >> 1;
    int ek = e * NBK + kb;
    int o = ot * 16 + o16;
    int grp = o >> 3, oo = o & 7;
    const int kstab[4] = {2, 3, 5, 7};
    int ks = kstab[grp];
    int lo = 7 - ks;
    float val = 0.f;
    if (dt >= lo) {
        int di = dt - lo;
        const float* W;
        if (grp == 0) W = (fg ? Wg2 : Wf2) + (size_t)ek * 512 + oo * 64 + c * 2 + di;
        else if (grp == 1) W = (fg ? Wg3 : Wf3) + (size_t)ek * 768 + oo * 96 + c * 3 + di;
        else if (grp == 2) W = (fg ? Wg5 : Wf5) + (size_t)ek * 1280 + oo * 160 + c * 5 + di;
        else W = (fg ? Wg7 : Wf7) + (size_t)ek * 1792 + oo * 224 + c * 7 + di;
        val = *W;
    }
    Wb[idx] = f2bf(val);
}

// ---------------------------------------------------------------------------
// Pack head weights: per e: Hb1[64][32], Hb2p[16][64], Hf1[64][32], Hf2p[16][64]
// (bf16) + fp32 rowsums of Hb1/Hf1 into rS[e][2][64]
__global__ __launch_bounds__(256) void k_preph(
    const float* __restrict__ Wb1, const float* __restrict__ Wb2,
    const float* __restrict__ Wfc1, const float* __restrict__ Wfc2,
    ushort_t* __restrict__ Whd, float* __restrict__ rS, int kb) {
    int e = blockIdx.x;
    int ek = e * NBK + kb;
    ushort_t* Wh = Whd + (size_t)e * 6144;
    for (int i = threadIdx.x; i < 2048; i += 256)
        Wh[i] = f2bf(Wb1[(size_t)ek * 2048 + i]);
    for (int i = threadIdx.x; i < 1024; i += 256) {
        int r = i >> 6, d = i & 63;
        Wh[2048 + i] = f2bf(r < 12 ? Wb2[(size_t)ek * 768 + r * 64 + d] : 0.f);
    }
    for (int i = threadIdx.x; i < 2048; i += 256)
        Wh[3072 + i] = f2bf(Wfc1[(size_t)ek * 2048 + i]);
    for (int i = threadIdx.x; i < 1024; i += 256) {
        int r = i >> 6, d = i & 63;
        Wh[5120 + i] = f2bf(r < 12 ? Wfc2[(size_t)ek * 768 + r * 64 + d] : 0.f);
    }
    if (threadIdx.x < 64) {
        int d = threadIdx.x;
        float s1 = 0.f, s2 = 0.f;
        for (int c = 0; c < 32; ++c) {
            s1 += Wb1[(size_t)ek * 2048 + d * 32 + c];
            s2 += Wfc1[(size_t)ek * 2048 + d * 32 + c];
        }
        rS[e * 128 + d] = s1;
        rS[e * 128 + 64 + d] = s2;
    }
}

// ---------------------------------------------------------------------------
// start: writes x fp32 [eb][t][c][n] and bf16 mirror xb [eb][t][n][c]
__global__ __launch_bounds__(256) void k_start(const float* __restrict__ bkc,
                                               float* __restrict__ x,
                                               ushort_t* __restrict__ xb,
                                               const float* __restrict__ Wst,
                                               const float* __restrict__ bst,
                                               int kb) {
    int n = blockIdx.x * 256 + threadIdx.x;
    int t = blockIdx.y;
    int eb = blockIdx.z;
    int e = eb >> 3;
    int ek = e * NBK + kb;
    const float* Wp = Wst + (size_t)ek * 32 * 2;
    const float* bp = bst + (size_t)ek * 32;
    float in0 = 0.f, in1 = 0.f;
    if (t >= 14) {
        const float* p = bkc + ((size_t)(eb * 12 + (t - 14)) * 512 + n) * 2;
        in0 = p[0];
        in1 = p[1];
    }
    float* xo = x + ((size_t)(eb * 26 + t) * 32) * 512 + n;
    ushort_t tmp[32];
#pragma unroll
    for (int c = 0; c < 32; ++c) {
        float v = bp[c] + Wp[c * 2] * in0 + Wp[c * 2 + 1] * in1;
        xo[(size_t)c * 512] = v;
        tmp[c] = f2bf(v);
    }
    ushort_t* xbp = xb + ((size_t)(eb * 26 + t) * 512 + n) * 32;
#pragma unroll
    for (int q = 0; q < 4; ++q)
        *(bf16x8*)(xbp + q * 8) = *(bf16x8*)(tmp + q * 8);
}

// ---------------------------------------------------------------------------
// MFMA inception
__global__ __launch_bounds__(256) void k_incept_mfma(
    const ushort_t* __restrict__ xb, ushort_t* __restrict__ h,
    const ushort_t* __restrict__ Wb,
    const float* __restrict__ bf, const float* __restrict__ bg,
    int kb, int cur_len, int L) {
    int j = blockIdx.y, eb = blockIdx.z, e = eb >> 3, ek = e * NBK + kb;
    int tid = threadIdx.x;
    int w = tid >> 6, lane = tid & 63;
    int l15 = lane & 15, lg = lane >> 4;
    int ot = w >> 1;
    int n0base = blockIdx.x * 128 + (w & 1) * 64;
    int t0 = 26 - cur_len + j;

    const ushort_t* WbE = Wb + (size_t)e * 14336;
    bf16x8 af_[7], ag_[7];
#pragma unroll
    for (int dt = 0; dt < 7; ++dt) {
        af_[dt] = *(const bf16x8*)(WbE + ((size_t)(dt * 2 + ot) * 16 + l15) * 32 + lg * 8);
        ag_[dt] = *(const bf16x8*)(WbE + 7168 + ((size_t)(dt * 2 + ot) * 16 + l15) * 32 + lg * 8);
    }
    float bfv[4], bgv[4];
#pragma unroll
    for (int r = 0; r < 4; ++r) {
        int o = ot * 16 + 4 * lg + r;
        bfv[r] = bf[ek * 32 + o];
        bgv[r] = bg[ek * 32 + o];
    }
    size_t colbase = ((size_t)eb * L + j) * 32;
    const ushort_t* xe = xb + ((size_t)eb * 26) * 512 * 32;
#pragma unroll
    for (int nt = 0; nt < 4; ++nt) {
        int n0 = n0base + nt * 16;
        f32x4 accf = {}, accg = {};
#pragma unroll
        for (int dt = 0; dt < 7; ++dt) {
            bf16x8 bfr = *(const bf16x8*)(xe + ((size_t)(t0 + dt) * 512 + n0 + l15) * 32 + lg * 8);
            accf = __builtin_amdgcn_mfma_f32_16x16x32_bf16(af_[dt], bfr, accf, 0, 0, 0);
            accg = __builtin_amdgcn_mfma_f32_16x16x32_bf16(ag_[dt], bfr, accg, 0, 0, 0);
        }
#pragma unroll
        for (int r = 0; r < 4; ++r) {
            float a = accf[r] + bfv[r];
            float b = accg[r] + bgv[r];
            float hv = tanhf(a) * (1.f / (1.f + expf(-b)));
            int o = ot * 16 + 4 * lg + r;
            h[(colbase + o) * 512 + n0 + l15] = f2bf(hv);
        }
    }
}

// ---------------------------------------------------------------------------
// bf16 MFMA NT GEMM: C[m][v] = sum_w A[m][w] * B[v][w]; K=N=512, M % 256 == 0.
__global__ __launch_bounds__(256) void k_gemm_bf16(
    const ushort_t* __restrict__ A0, const ushort_t* __restrict__ B0,
    ushort_t* __restrict__ C0,
    const ushort_t* __restrict__ A1, const ushort_t* __restrict__ B1,
    ushort_t* __restrict__ C1) {
    const ushort_t* A = blockIdx.z ? A1 : A0;
    const ushort_t* B = blockIdx.z ? B1 : B0;
    ushort_t* C = blockIdx.z ? C1 : C0;
    int tid = threadIdx.x;
    int w = tid >> 6, lane = tid & 63;
    int l15 = lane & 15, lg = lane >> 4;
    int wbase = blockIdx.x * 256 + w * 64;  // 64 rows per wave
    int n0 = blockIdx.y * 64;               // 64 cols per block
    f32x4 acc[4][4] = {};
    const ushort_t* Ap = A + (size_t)(wbase + l15) * 512 + lg * 8;
    const ushort_t* Bp = B + (size_t)(n0 + l15) * 512 + lg * 8;
#pragma unroll 4
    for (int k0 = 0; k0 < 512; k0 += 32) {
        bf16x8 av[4], bv[4];
#pragma unroll
        for (int mf = 0; mf < 4; ++mf)
            av[mf] = *(const bf16x8*)(Ap + (size_t)mf * 16 * 512 + k0);
#pragma unroll
        for (int nf = 0; nf < 4; ++nf)
            bv[nf] = *(const bf16x8*)(Bp + (size_t)nf * 16 * 512 + k0);
#pragma unroll
        for (int mf = 0; mf < 4; ++mf)
#pragma unroll
            for (int nf = 0; nf < 4; ++nf)
                acc[mf][nf] = __builtin_amdgcn_mfma_f32_16x16x32_bf16(
                    av[mf], bv[nf], acc[mf][nf], 0, 0, 0);
    }
#pragma unroll
    for (int mf = 0; mf < 4; ++mf)
#pragma unroll
        for (int nf = 0; nf < 4; ++nf)
#pragma unroll
            for (int r = 0; r < 4; ++r) {
                int row = wbase + 16 * mf + 4 * lg + r;
                int col = n0 + 16 * nf + l15;
                C[(size_t)row * 512 + col] = f2bf(acc[mf][nf][r]);
            }
}

// ---------------------------------------------------------------------------
__global__ __launch_bounds__(256) void k_prepmix(const float* __restrict__ Wgc1,
                                                 const float* __restrict__ bgc1,
                                                 const float* __restrict__ Wgc2,
                                                 const float* __restrict__ bgc2,
                                                 float* __restrict__ mixT,
                                                 float* __restrict__ bsum, int kb) {
    int e = blockIdx.x;
    int ek = e * NBK + kb;
    const float* W1 = Wgc1 + (size_t)ek * 32 * 96;
    const float* W2 = Wgc2 + (size_t)ek * 32 * 96;
    for (int idx = threadIdx.x; idx < 5 * 32 * 32; idx += 256) {
        int m = idx >> 10, cp = (idx >> 5) & 31, c = idx & 31;
        float w0 = W1[c * 96 + cp], w1 = W1[c * 96 + 32 + cp], w2 = W1[c * 96 + 64 + cp];
        float v0 = W2[c * 96 + cp], v1 = W2[c * 96 + 32 + cp], v2 = W2[c * 96 + 64 + cp];
        float val;
        if (m == 0) val = w0 + w1 + w2 + v0 + v1 + v2;
        else if (m == 1) val = 0.5f * w1 + w2;
        else if (m == 2) val = 0.25f * w2;
        else if (m == 3) val = 0.5f * v1 + v2;
        else val = 0.25f * v2;
        mixT[((size_t)(e * 5 + m) * 32 + cp) * 32 + c] = val;
    }
    if (threadIdx.x < 32)
        bsum[e * 32 + threadIdx.x] =
            bgc1[ek * 32 + threadIdx.x] + bgc2[ek * 32 + threadIdx.x];
}

// ---------------------------------------------------------------------------
// combine: x -= 0.25*g; refresh bf16 mirror xb
__global__ __launch_bounds__(256) void k_combine(
    float* __restrict__ x, ushort_t* __restrict__ xb,
    const ushort_t* __restrict__ h,
    const ushort_t* __restrict__ u1, const ushort_t* __restrict__ v1,
    const ushort_t* __restrict__ u1t, const ushort_t* __restrict__ v1t,
    const float* __restrict__ mixT, const float* __restrict__ bsum, int L) {
    int n = blockIdx.x * 256 + threadIdx.x;
    int j = blockIdx.y;
    int eb = blockIdx.z;
    int e = eb >> 3;
    size_t colbase = ((size_t)eb * L + j) * 32;
    const ushort_t* bufs[5] = {h, u1, v1, u1t, v1t};
    float g[32];
#pragma unroll
    for (int c = 0; c < 32; ++c) g[c] = bsum[e * 32 + c];
#pragma unroll
    for (int m = 0; m < 5; ++m) {
        const ushort_t* in = bufs[m] + colbase * 512 + n;
        const float* Mp = mixT + ((size_t)(e * 5 + m) * 32) * 32;
        for (int cp = 0; cp < 32; ++cp) {
            float v = bf2f(in[(size_t)cp * 512]);
#pragma unroll
            for (int c = 0; c < 32; ++c) g[c] += Mp[cp * 32 + c] * v;
        }
    }
    int t = 26 - L + j;
    float* xo = x + ((size_t)(eb * 26 + t) * 32) * 512 + n;
    ushort_t tmp[32];
#pragma unroll
    for (int c = 0; c < 32; ++c) {
        float nv = xo[(size_t)c * 512] - 0.25f * g[c];
        xo[(size_t)c * 512] = nv;
        tmp[c] = f2bf(nv);
    }
    ushort_t* xbp = xb + ((size_t)(eb * 26 + t) * 512 + n) * 32;
#pragma unroll
    for (int q = 0; q < 4; ++q)
        *(bf16x8*)(xbp + q * 8) = *(bf16x8*)(tmp + q * 8);
}

// ---------------------------------------------------------------------------
__global__ __launch_bounds__(256) void k_lnstats(const float* __restrict__ x,
                                                 float* __restrict__ stats) {
    int eb = blockIdx.x;
    const float* p = x + ((size_t)(eb * 26 + 24) * 32) * 512;
    float s = 0.f, s2 = 0.f;
    for (int i = threadIdx.x; i < 32768; i += 256) {
        float v = p[i];
        s += v;
        s2 += v * v;
    }
    for (int off = 32; off; off >>= 1) {
        s += __shfl_down(s, off);
        s2 += __shfl_down(s2, off);
    }
    __shared__ float r1[4], r2[4];
    if ((threadIdx.x & 63) == 0) {
        r1[threadIdx.x >> 6] = s;
        r2[threadIdx.x >> 6] = s2;
    }
    __syncthreads();
    if (threadIdx.x == 0) {
        float S = r1[0] + r1[1] + r1[2] + r1[3];
        float S2 = r2[0] + r2[1] + r2[2] + r2[3];
        float mu = S / 32768.f;
        float var = S2 / 32768.f - mu * mu;
        stats[eb * 2] = mu;
        stats[eb * 2 + 1] = rsqrtf(var + 1e-5f);
    }
}

// ---------------------------------------------------------------------------
// MFMA heads: stage1 hid=relu(rs*(W1@x_bf) + (b1 - rs*mu*rowsum)), LDS
// transpose, stage2 out = W2p@hid. bc -> bkc (w=0,1); fc -> acc (w=1).
// grid (2 nchunk, 2 w, 16 eb), 4 waves/block, wave owns 64 cols.
__global__ __launch_bounds__(256) void k_heads_mfma(
    const ushort_t* __restrict__ xb, const float* __restrict__ stats,
    float* __restrict__ bkc, float* __restrict__ acc,
    const ushort_t* __restrict__ Whd, const float* __restrict__ rS,
    const float* __restrict__ bb1, const float* __restrict__ bb2,
    const float* __restrict__ bfc1, const float* __restrict__ bfc2,
    int kb) {
    __shared__ __align__(16) ushort_t lds[4][64][72];
    int w = blockIdx.y, eb = blockIdx.z;
    int e = eb >> 3, ek = e * NBK + kb;
    int tid = threadIdx.x, wv = tid >> 6, lane = tid & 63;
    int l15 = lane & 15, lg = lane >> 4;
    int n0 = blockIdx.x * 256 + wv * 64;
    float mu = stats[eb * 2], rsv = stats[eb * 2 + 1];
    const ushort_t* Wh = Whd + (size_t)e * 6144;
    const ushort_t* xrow = xb + ((size_t)(eb * 26 + 24 + w) * 512) * 32;

#pragma unroll
    for (int head = 0; head < 2; ++head) {
        if (head == 1 && w == 0) break;  // fc only for w==1
        int woff = head ? 3072 : 0;
        const float* b1 = head ? bfc1 : bb1;
        const float* b2 = head ? bfc2 : bb2;
        const float* rs1 = rS + e * 128 + (head ? 64 : 0);
        // stage-1 A fragments (W1[d][c], row=d=l15.., k=c)
        bf16x8 a1[4];
#pragma unroll
        for (int rt = 0; rt < 4; ++rt)
            a1[rt] = *(const bf16x8*)(Wh + woff + (size_t)(rt * 16 + l15) * 32 + lg * 8);
        float be[4][4];
#pragma unroll
        for (int rt = 0; rt < 4; ++rt)
#pragma unroll
            for (int r = 0; r < 4; ++r) {
                int d = rt * 16 + 4 * lg + r;
                be[rt][r] = b1[ek * 64 + d] - rsv * mu * rs1[d];
            }
#pragma unroll
        for (int nt = 0; nt < 4; ++nt) {
            bf16x8 bv = *(const bf16x8*)(xrow + (size_t)(n0 + nt * 16 + l15) * 32 + lg * 8);
            f32x4 ac[4] = {};
#pragma unroll
            for (int rt = 0; rt < 4; ++rt)
                ac[rt] = __builtin_amdgcn_mfma_f32_16x16x32_bf16(a1[rt], bv, ac[rt], 0, 0, 0);
#pragma unroll
            for (int rt = 0; rt < 4; ++rt)
#pragma unroll
                for (int r = 0; r < 4; ++r) {
                    float hv = fmaxf(rsv * ac[rt][r] + be[rt][r], 0.f);
                    lds[wv][nt * 16 + l15][rt * 16 + 4 * lg + r] = f2bf(hv);
                }
        }
        // stage-2: A = W2p[16][64]
        bf16x8 a2[2];
        a2[0] = *(const bf16x8*)(Wh + woff + 2048 + (size_t)l15 * 64 + lg * 8);
        a2[1] = *(const bf16x8*)(Wh + woff + 2048 + (size_t)l15 * 64 + 32 + lg * 8);
        float b2v[4];
#pragma unroll
        for (int r = 0; r < 4; ++r) {
            int s = 4 * lg + r;
            b2v[r] = (s < 12) ? b2[ek * 12 + s] : 0.f;
        }
#pragma unroll
        for (int nt = 0; nt < 4; ++nt) {
            bf16x8 b0 = *(const bf16x8*)&lds[wv][nt * 16 + l15][lg * 8];
            bf16x8 b1f = *(const bf16x8*)&lds[wv][nt * 16 + l15][32 + lg * 8];
            f32x4 ac2 = {};
            ac2 = __builtin_amdgcn_mfma_f32_16x16x32_bf16(a2[0], b0, ac2, 0, 0, 0);
            ac2 = __builtin_amdgcn_mfma_f32_16x16x32_bf16(a2[1], b1f, ac2, 0, 0, 0);
#pragma unroll
            for (int r = 0; r < 4; ++r) {
                int s = 4 * lg + r;
                if (s < 12) {
                    int n = n0 + nt * 16 + l15;
                    float val = ac2[r] + b2v[r];
                    if (head == 0)
                        bkc[((size_t)(eb * 12 + s) * 512 + n) * 2 + w] -= val;
                    else
                        acc[(size_t)(eb * 12 + s) * 512 + n] += val;
                }
            }
        }
    }
}

// ---------------------------------------------------------------------------
__global__ __launch_bounds__(256) void k_final(const float* __restrict__ acc,
                                               const float* __restrict__ ew,
                                               float* __restrict__ out) {
    int i = blockIdx.x * 256 + threadIdx.x;  // 49152
    out[i] = ew[0] * acc[i] + ew[1] * acc[49152 + i];
}

// ---------------------------------------------------------------------------
extern "C" void kernel_launch(void* const* d_in, const int* in_sizes, int n_in,
                              void* d_out, int out_size, void* d_ws, size_t ws_size,
                              hipStream_t stream) {
    const float* X    = (const float*)d_in[0];
    const float* adj  = (const float*)d_in[1];
    const float* ew   = (const float*)d_in[2];
    const float* Wst  = (const float*)d_in[3];
    const float* bst  = (const float*)d_in[4];
    const float* Wf2  = (const float*)d_in[5];
    const float* Wf3  = (const float*)d_in[6];
    const float* Wf5  = (const float*)d_in[7];
    const float* Wf7  = (const float*)d_in[8];
    const float* bf   = (const float*)d_in[9];
    const float* Wg2  = (const float*)d_in[10];
    const float* Wg3  = (const float*)d_in[11];
    const float* Wg5  = (const float*)d_in[12];
    const float* Wg7  = (const float*)d_in[13];
    const float* bg   = (const float*)d_in[14];
    const float* Wgc1 = (const float*)d_in[15];
    const float* bgc1 = (const float*)d_in[16];
    const float* Wgc2 = (const float*)d_in[17];
    const float* bgc2 = (const float*)d_in[18];
    const float* Wb1  = (const float*)d_in[19];
    const float* bb1  = (const float*)d_in[20];
    const float* Wb2  = (const float*)d_in[21];
    const float* bb2  = (const float*)d_in[22];
    const float* Wfc1 = (const float*)d_in[23];
    const float* bfc1 = (const float*)d_in[24];
    const float* Wfc2 = (const float*)d_in[25];
    const float* bfc2 = (const float*)d_in[26];

    float* ws = (float*)d_ws;
    size_t off = 0;
    auto alloc = [&](size_t nf) { float* p = ws + off; off += nf; return p; };
    float* di    = alloc(512);
    ushort_t* Anb  = (ushort_t*)alloc(512 * 512 / 2);
    ushort_t* AnTb = (ushort_t*)alloc(512 * 512 / 2);
    float* bkc   = alloc((size_t)EE * BATCH * 12 * 512 * 2);
    float* acc   = alloc((size_t)EE * BATCH * 12 * 512);
    float* stats = alloc(32);
    float* mixT  = alloc(2 * 5 * 32 * 32);
    float* bsum  = alloc(64);
    ushort_t* Wb = (ushort_t*)alloc(14336);          // 28672 ushorts
    ushort_t* Whd = (ushort_t*)alloc(6144);          // 12288 ushorts
    float* rSb   = alloc(256);
    float* x     = alloc((size_t)16 * 26 * 32 * 512);
    ushort_t* xb = (ushort_t*)alloc((size_t)16 * 26 * 512 * 32 / 2);
    size_t hbuf_f = (size_t)16 * 20 * 32 * 512 / 2;  // bf16 buffers, float units
    ushort_t* h   = (ushort_t*)alloc(hbuf_f);
    ushort_t* u1  = (ushort_t*)alloc(hbuf_f);
    ushort_t* v1  = (ushort_t*)alloc(hbuf_f);
    ushort_t* u1t = (ushort_t*)alloc(hbuf_f);
    ushort_t* v1t = (ushort_t*)alloc(hbuf_f);
    if (off * sizeof(float) > ws_size) return;  // workspace too small: bail

    // Graph normalization
    k_rowsum<<<512, 256, 0, stream>>>(adj, di);
    k_norm<<<1024, 256, 0, stream>>>(adj, di, Anb, AnTb);

    // Residual init (both experts start from X) + output accumulator zero
    hipMemcpyAsync(bkc, X, (size_t)98304 * 4, hipMemcpyDeviceToDevice, stream);
    hipMemcpyAsync(bkc + 98304, X, (size_t)98304 * 4, hipMemcpyDeviceToDevice, stream);
    hipMemsetAsync(acc, 0, (size_t)EE * BATCH * 12 * 512 * 4, stream);

    for (int kb = 0; kb < NBK; ++kb) {
        k_prepmix<<<2, 256, 0, stream>>>(Wgc1, bgc1, Wgc2, bgc2, mixT, bsum, kb);
        k_prepw<<<112, 256, 0, stream>>>(Wf2, Wf3, Wf5, Wf7, Wg2, Wg3, Wg5, Wg7, Wb, kb);
        k_preph<<<2, 256, 0, stream>>>(Wb1, Wb2, Wfc1, Wfc2, Whd, rSb, kb);
        k_start<<<dim3(2, 26, 16), 256, 0, stream>>>(bkc, x, xb, Wst, bst, kb);
        int cur = 26;
        for (int it = 0; it < 4; ++it) {
            int L = cur - 6;
            k_incept_mfma<<<dim3(4, L, 16), 256, 0, stream>>>(
                xb, h, Wb, bf, bg, kb, cur, L);
            k_gemm_bf16<<<dim3(2 * L, 8, 2), 256, 0, stream>>>(h, Anb, u1, h, AnTb, u1t);
            k_gemm_bf16<<<dim3(2 * L, 8, 2), 256, 0, stream>>>(u1, Anb, v1, u1t, AnTb, v1t);
            k_combine<<<dim3(2, L, 16), 256, 0, stream>>>(x, xb, h, u1, v1, u1t, v1t,
                                                          mixT, bsum, L);
            cur -= 6;
        }
        k_lnstats<<<16, 256, 0, stream>>>(x, stats);
        k_heads_mfma<<<dim3(2, 2, 16), 256, 0, stream>>>(xb, stats, bkc, acc, Whd, rSb,
                                                         bb1, bb2, bfc1, bfc2, kb);
    }
    k_final<<<192, 256, 0, stream>>>(acc, ew, (float*)d_out);
}

// Round 7
// 1082.642 us; speedup vs baseline: 3.1373x; 1.1643x over previous
//
#include <hip/hip_runtime.h>
#include <stddef.h>

// Problem constants (E=2 experts, NB=2 blocks, B=8 batch, N=512 nodes)
#define EE 2
#define NBK 2
#define BATCH 8

typedef unsigned short ushort_t;
typedef short bf16x8 __attribute__((ext_vector_type(8)));
typedef float f32x4 __attribute__((ext_vector_type(4)));
typedef unsigned short u16x4 __attribute__((ext_vector_type(4)));

__device__ __forceinline__ ushort_t f2bf(float f) {
    unsigned int u = __float_as_uint(f);
    u += 0x7FFF + ((u >> 16) & 1);
    return (ushort_t)(u >> 16);
}
__device__ __forceinline__ float bf2f(ushort_t h) {
    return __uint_as_float(((unsigned int)h) << 16);
}

// ---------------------------------------------------------------------------
__global__ __launch_bounds__(256) void k_rowsum(const float* __restrict__ adj,
                                                float* __restrict__ di) {
    int v = blockIdx.x;
    int tid = threadIdx.x;
    float s = 0.f;
    for (int w = tid; w < 512; w += 256)
        s += adj[v * 512 + w] + (w == v ? 1.f : 0.f);
    for (int off = 32; off; off >>= 1) s += __shfl_down(s, off);
    __shared__ float red[4];
    if ((tid & 63) == 0) red[tid >> 6] = s;
    __syncthreads();
    if (tid == 0) {
        float t = red[0] + red[1] + red[2] + red[3];
        di[v] = rsqrtf(t);
    }
}

__global__ __launch_bounds__(256) void k_norm(const float* __restrict__ adj,
                                              const float* __restrict__ di,
                                              ushort_t* __restrict__ An,
                                              ushort_t* __restrict__ AnT) {
    int idx = blockIdx.x * 256 + threadIdx.x;  // 0..262143
    int v = idx >> 9, w = idx & 511;
    float a = adj[idx] + (v == w ? 1.f : 0.f);
    ushort_t val = f2bf(di[v] * a * di[w]);
    An[idx] = val;
    AnT[w * 512 + v] = val;
}

// ---------------------------------------------------------------------------
// Pack inception weights into dense bf16 Weff[e][fg][dt][ot][o16][c32]
__global__ __launch_bounds__(256) void k_prepw(
    const float* __restrict__ Wf2, const float* __restrict__ Wf3,
    const float* __restrict__ Wf5, const float* __restrict__ Wf7,
    const float* __restrict__ Wg2, const float* __restrict__ Wg3,
    const float* __restrict__ Wg5, const float* __restrict__ Wg7,
    ushort_t* __restrict__ Wb, int kb) {
    int idx = blockIdx.x * 256 + threadIdx.x;  // 28672 total
    if (idx >= 2 * 2 * 7 * 2 * 16 * 32) return;
    int c = idx & 31;
    int t1 = idx >> 5;
    int o16 = t1 & 15;
    int t2 = t1 >> 4;
    int ot = t2 & 1;
    int t3 = t2 >> 1;
    int dt = t3 % 7;
    int t4 = t3 / 7;
    int fg = t4 & 1;
    int e = t4 >> 1;
    int ek = e * NBK + kb;
    int o = ot * 16 + o16;
    int grp = o >> 3, oo = o & 7;
    const int kstab[4] = {2, 3, 5, 7};
    int ks = kstab[grp];
    int lo = 7 - ks;
    float val = 0.f;
    if (dt >= lo) {
        int di = dt - lo;
        const float* W;
        if (grp == 0) W = (fg ? Wg2 : Wf2) + (size_t)ek * 512 + oo * 64 + c * 2 + di;
        else if (grp == 1) W = (fg ? Wg3 : Wf3) + (size_t)ek * 768 + oo * 96 + c * 3 + di;
        else if (grp == 2) W = (fg ? Wg5 : Wf5) + (size_t)ek * 1280 + oo * 160 + c * 5 + di;
        else W = (fg ? Wg7 : Wf7) + (size_t)ek * 1792 + oo * 224 + c * 7 + di;
        val = *W;
    }
    Wb[idx] = f2bf(val);
}

// ---------------------------------------------------------------------------
// Pack head weights: per e: Hb1[64][32], Hb2p[16][64], Hf1[64][32], Hf2p[16][64]
// (bf16) + fp32 rowsums of Hb1/Hf1 into rS[e][2][64]
__global__ __launch_bounds__(256) void k_preph(
    const float* __restrict__ Wb1, const float* __restrict__ Wb2,
    const float* __restrict__ Wfc1, const float* __restrict__ Wfc2,
    ushort_t* __restrict__ Whd, float* __restrict__ rS, int kb) {
    int e = blockIdx.x;
    int ek = e * NBK + kb;
    ushort_t* Wh = Whd + (size_t)e * 6144;
    for (int i = threadIdx.x; i < 2048; i += 256)
        Wh[i] = f2bf(Wb1[(size_t)ek * 2048 + i]);
    for (int i = threadIdx.x; i < 1024; i += 256) {
        int r = i >> 6, d = i & 63;
        Wh[2048 + i] = f2bf(r < 12 ? Wb2[(size_t)ek * 768 + r * 64 + d] : 0.f);
    }
    for (int i = threadIdx.x; i < 2048; i += 256)
        Wh[3072 + i] = f2bf(Wfc1[(size_t)ek * 2048 + i]);
    for (int i = threadIdx.x; i < 1024; i += 256) {
        int r = i >> 6, d = i & 63;
        Wh[5120 + i] = f2bf(r < 12 ? Wfc2[(size_t)ek * 768 + r * 64 + d] : 0.f);
    }
    if (threadIdx.x < 64) {
        int d = threadIdx.x;
        float s1 = 0.f, s2 = 0.f;
        for (int c = 0; c < 32; ++c) {
            s1 += Wb1[(size_t)ek * 2048 + d * 32 + c];
            s2 += Wfc1[(size_t)ek * 2048 + d * 32 + c];
        }
        rS[e * 128 + d] = s1;
        rS[e * 128 + 64 + d] = s2;
    }
}

// ---------------------------------------------------------------------------
// Pack mix matrices bf16 Amix[e][c_out=32][k=160], k = slot*32+cp:
// slot0 (h):  W0+W1+W2+V0+V1+V2 ; slot1 (u1): .5W1+W2 ; slot2 (v1): .25W2
// slot3 (u1t): .5V1+V2 ; slot4 (v1t): .25V2.  Also bsum fp32[e][32].
__global__ __launch_bounds__(256) void k_prepmixA(const float* __restrict__ Wgc1,
                                                  const float* __restrict__ bgc1,
                                                  const float* __restrict__ Wgc2,
                                                  const float* __restrict__ bgc2,
                                                  ushort_t* __restrict__ Amix,
                                                  float* __restrict__ bsum, int kb) {
    int e = blockIdx.x;
    int ek = e * NBK + kb;
    const float* W1 = Wgc1 + (size_t)ek * 32 * 96;
    const float* W2 = Wgc2 + (size_t)ek * 32 * 96;
    for (int idx = threadIdx.x; idx < 32 * 160; idx += 256) {
        int co = idx / 160, k = idx % 160;
        int slot = k >> 5, cp = k & 31;
        float val;
        if (slot == 0)
            val = W1[co * 96 + cp] + W1[co * 96 + 32 + cp] + W1[co * 96 + 64 + cp] +
                  W2[co * 96 + cp] + W2[co * 96 + 32 + cp] + W2[co * 96 + 64 + cp];
        else if (slot == 1) val = 0.5f * W1[co * 96 + 32 + cp] + W1[co * 96 + 64 + cp];
        else if (slot == 2) val = 0.25f * W1[co * 96 + 64 + cp];
        else if (slot == 3) val = 0.5f * W2[co * 96 + 32 + cp] + W2[co * 96 + 64 + cp];
        else val = 0.25f * W2[co * 96 + 64 + cp];
        Amix[((size_t)e * 32 + co) * 160 + k] = f2bf(val);
    }
    if (threadIdx.x < 32)
        bsum[e * 32 + threadIdx.x] =
            bgc1[ek * 32 + threadIdx.x] + bgc2[ek * 32 + threadIdx.x];
}

// ---------------------------------------------------------------------------
// start: writes x fp32 [eb][t][c][n] and bf16 mirror xb [eb][t][n][c]
__global__ __launch_bounds__(256) void k_start(const float* __restrict__ bkc,
                                               float* __restrict__ x,
                                               ushort_t* __restrict__ xb,
                                               const float* __restrict__ Wst,
                                               const float* __restrict__ bst,
                                               int kb) {
    int n = blockIdx.x * 256 + threadIdx.x;
    int t = blockIdx.y;
    int eb = blockIdx.z;
    int e = eb >> 3;
    int ek = e * NBK + kb;
    const float* Wp = Wst + (size_t)ek * 32 * 2;
    const float* bp = bst + (size_t)ek * 32;
    float in0 = 0.f, in1 = 0.f;
    if (t >= 14) {
        const float* p = bkc + ((size_t)(eb * 12 + (t - 14)) * 512 + n) * 2;
        in0 = p[0];
        in1 = p[1];
    }
    float* xo = x + ((size_t)(eb * 26 + t) * 32) * 512 + n;
    ushort_t tmp[32];
#pragma unroll
    for (int c = 0; c < 32; ++c) {
        float v = bp[c] + Wp[c * 2] * in0 + Wp[c * 2 + 1] * in1;
        xo[(size_t)c * 512] = v;
        tmp[c] = f2bf(v);
    }
    ushort_t* xbp = xb + ((size_t)(eb * 26 + t) * 512 + n) * 32;
#pragma unroll
    for (int q = 0; q < 4; ++q)
        *(bf16x8*)(xbp + q * 8) = *(bf16x8*)(tmp + q * 8);
}

// ---------------------------------------------------------------------------
// MFMA inception: writes h_old [col][n] (GEMM1 A operand) + buf5 slot0 (Y)
__global__ __launch_bounds__(256) void k_incept_mfma(
    const ushort_t* __restrict__ xb, ushort_t* __restrict__ h,
    ushort_t* __restrict__ buf5, const ushort_t* __restrict__ Wb,
    const float* __restrict__ bf, const float* __restrict__ bg,
    int kb, int cur_len, int L) {
    int j = blockIdx.y, eb = blockIdx.z, e = eb >> 3, ek = e * NBK + kb;
    int tid = threadIdx.x;
    int w = tid >> 6, lane = tid & 63;
    int l15 = lane & 15, lg = lane >> 4;
    int ot = w >> 1;
    int n0base = blockIdx.x * 128 + (w & 1) * 64;
    int t0 = 26 - cur_len + j;

    const ushort_t* WbE = Wb + (size_t)e * 14336;
    bf16x8 af_[7], ag_[7];
#pragma unroll
    for (int dt = 0; dt < 7; ++dt) {
        af_[dt] = *(const bf16x8*)(WbE + ((size_t)(dt * 2 + ot) * 16 + l15) * 32 + lg * 8);
        ag_[dt] = *(const bf16x8*)(WbE + 7168 + ((size_t)(dt * 2 + ot) * 16 + l15) * 32 + lg * 8);
    }
    float bfv[4], bgv[4];
#pragma unroll
    for (int r = 0; r < 4; ++r) {
        int o = ot * 16 + 4 * lg + r;
        bfv[r] = bf[ek * 32 + o];
        bgv[r] = bg[ek * 32 + o];
    }
    size_t colbase = ((size_t)eb * L + j) * 32;
    size_t rowb = ((size_t)eb * L + j) * 512;
    const ushort_t* xe = xb + ((size_t)eb * 26) * 512 * 32;
#pragma unroll
    for (int nt = 0; nt < 4; ++nt) {
        int n0 = n0base + nt * 16;
        f32x4 accf = {}, accg = {};
#pragma unroll
        for (int dt = 0; dt < 7; ++dt) {
            bf16x8 bfr = *(const bf16x8*)(xe + ((size_t)(t0 + dt) * 512 + n0 + l15) * 32 + lg * 8);
            accf = __builtin_amdgcn_mfma_f32_16x16x32_bf16(af_[dt], bfr, accf, 0, 0, 0);
            accg = __builtin_amdgcn_mfma_f32_16x16x32_bf16(ag_[dt], bfr, accg, 0, 0, 0);
        }
        u16x4 q;
#pragma unroll
        for (int r = 0; r < 4; ++r) {
            float a = accf[r] + bfv[r];
            float b = accg[r] + bgv[r];
            float hv = tanhf(a) * (1.f / (1.f + expf(-b)));
            ushort_t hb = f2bf(hv);
            q[r] = hb;
            int o = ot * 16 + 4 * lg + r;
            h[(colbase + o) * 512 + n0 + l15] = hb;
        }
        *(u16x4*)(buf5 + (rowb + n0 + l15) * 160 + ot * 16 + 4 * lg) = q;
    }
}

// ---------------------------------------------------------------------------
// bf16 MFMA NT GEMM + dual store: old layout C[m][v] + Y layout buf5 slot.
// C[m][v] = sum_w A[m][w] * B[v][w]; K=N=512, M % 256 == 0.
__global__ __launch_bounds__(256) void k_gemm_dual(
    const ushort_t* __restrict__ A0, const ushort_t* __restrict__ B0,
    ushort_t* __restrict__ C0,
    const ushort_t* __restrict__ A1, const ushort_t* __restrict__ B1,
    ushort_t* __restrict__ C1,
    ushort_t* __restrict__ buf5, int s0, int s1) {
    const ushort_t* A = blockIdx.z ? A1 : A0;
    const ushort_t* B = blockIdx.z ? B1 : B0;
    ushort_t* C = blockIdx.z ? C1 : C0;
    int slot = blockIdx.z ? s1 : s0;
    int tid = threadIdx.x;
    int w = tid >> 6, lane = tid & 63;
    int l15 = lane & 15, lg = lane >> 4;
    int wbase = blockIdx.x * 256 + w * 64;
    int n0 = blockIdx.y * 64;
    f32x4 acc[4][4] = {};
    const ushort_t* Ap = A + (size_t)(wbase + l15) * 512 + lg * 8;
    const ushort_t* Bp = B + (size_t)(n0 + l15) * 512 + lg * 8;
#pragma unroll 4
    for (int k0 = 0; k0 < 512; k0 += 32) {
        bf16x8 av[4], bv[4];
#pragma unroll
        for (int mf = 0; mf < 4; ++mf)
            av[mf] = *(const bf16x8*)(Ap + (size_t)mf * 16 * 512 + k0);
#pragma unroll
        for (int nf = 0; nf < 4; ++nf)
            bv[nf] = *(const bf16x8*)(Bp + (size_t)nf * 16 * 512 + k0);
#pragma unroll
        for (int mf = 0; mf < 4; ++mf)
#pragma unroll
            for (int nf = 0; nf < 4; ++nf)
                acc[mf][nf] = __builtin_amdgcn_mfma_f32_16x16x32_bf16(
                    av[mf], bv[nf], acc[mf][nf], 0, 0, 0);
    }
#pragma unroll
    for (int mf = 0; mf < 4; ++mf) {
        int jeb = (wbase >> 5) + (mf >> 1);
        int c0 = 16 * (mf & 1) + 4 * lg;
#pragma unroll
        for (int nf = 0; nf < 4; ++nf) {
            int col = n0 + 16 * nf + l15;
            u16x4 q;
#pragma unroll
            for (int r = 0; r < 4; ++r) {
                ushort_t vb = f2bf(acc[mf][nf][r]);
                q[r] = vb;
                int row = wbase + 16 * mf + 4 * lg + r;
                C[(size_t)row * 512 + col] = vb;
            }
            *(u16x4*)(buf5 + ((size_t)jeb * 512 + col) * 160 + slot * 32 + c0) = q;
        }
    }
}

// Same GEMM but Y-layout store only (for v1/v1t, consumed only by combine)
__global__ __launch_bounds__(256) void k_gemm_y(
    const ushort_t* __restrict__ A0, const ushort_t* __restrict__ B0,
    const ushort_t* __restrict__ A1, const ushort_t* __restrict__ B1,
    ushort_t* __restrict__ buf5, int s0, int s1) {
    const ushort_t* A = blockIdx.z ? A1 : A0;
    const ushort_t* B = blockIdx.z ? B1 : B0;
    int slot = blockIdx.z ? s1 : s0;
    int tid = threadIdx.x;
    int w = tid >> 6, lane = tid & 63;
    int l15 = lane & 15, lg = lane >> 4;
    int wbase = blockIdx.x * 256 + w * 64;
    int n0 = blockIdx.y * 64;
    f32x4 acc[4][4] = {};
    const ushort_t* Ap = A + (size_t)(wbase + l15) * 512 + lg * 8;
    const ushort_t* Bp = B + (size_t)(n0 + l15) * 512 + lg * 8;
#pragma unroll 4
    for (int k0 = 0; k0 < 512; k0 += 32) {
        bf16x8 av[4], bv[4];
#pragma unroll
        for (int mf = 0; mf < 4; ++mf)
            av[mf] = *(const bf16x8*)(Ap + (size_t)mf * 16 * 512 + k0);
#pragma unroll
        for (int nf = 0; nf < 4; ++nf)
            bv[nf] = *(const bf16x8*)(Bp + (size_t)nf * 16 * 512 + k0);
#pragma unroll
        for (int mf = 0; mf < 4; ++mf)
#pragma unroll
            for (int nf = 0; nf < 4; ++nf)
                acc[mf][nf] = __builtin_amdgcn_mfma_f32_16x16x32_bf16(
                    av[mf], bv[nf], acc[mf][nf], 0, 0, 0);
    }
#pragma unroll
    for (int mf = 0; mf < 4; ++mf) {
        int jeb = (wbase >> 5) + (mf >> 1);
        int c0 = 16 * (mf & 1) + 4 * lg;
#pragma unroll
        for (int nf = 0; nf < 4; ++nf) {
            int col = n0 + 16 * nf + l15;
            u16x4 q;
#pragma unroll
            for (int r = 0; r < 4; ++r) q[r] = f2bf(acc[mf][nf][r]);
            *(u16x4*)(buf5 + ((size_t)jeb * 512 + col) * 160 + slot * 32 + c0) = q;
        }
    }
}

// ---------------------------------------------------------------------------
// MFMA combine: g[c_out][n] = Amix[c_out][0:160] @ buf5[n][0:160] + bsum;
// x[t][c][n] -= 0.25*g; xb[t][n][c] = bf16(x). grid (L, 16), 4 waves/block.
__global__ __launch_bounds__(256) void k_combine_mfma(
    float* __restrict__ x, ushort_t* __restrict__ xb,
    const ushort_t* __restrict__ buf5, const ushort_t* __restrict__ Amix,
    const float* __restrict__ bsum, int L) {
    int j = blockIdx.x, eb = blockIdx.y, e = eb >> 3;
    int tid = threadIdx.x, wv = tid >> 6, lane = tid & 63;
    int l15 = lane & 15, lg = lane >> 4;
    int t = 26 - L + j;
    const ushort_t* Ae = Amix + (size_t)e * 32 * 160;
    bf16x8 a[2][5];
#pragma unroll
    for (int ct = 0; ct < 2; ++ct)
#pragma unroll
        for (int ks = 0; ks < 5; ++ks)
            a[ct][ks] = *(const bf16x8*)(Ae + (size_t)(ct * 16 + l15) * 160 + ks * 32 + lg * 8);
    float bs[2][4];
#pragma unroll
    for (int ct = 0; ct < 2; ++ct)
#pragma unroll
        for (int r = 0; r < 4; ++r) bs[ct][r] = bsum[e * 32 + ct * 16 + 4 * lg + r];
    size_t rowb = ((size_t)eb * L + j) * 512;
    size_t xtb = ((size_t)(eb * 26 + t) * 32) * 512;
    ushort_t* xbt = xb + ((size_t)(eb * 26 + t) * 512) * 32;
#pragma unroll
    for (int nt = 0; nt < 8; ++nt) {
        int n = wv * 128 + nt * 16 + l15;
        const ushort_t* bp = buf5 + (rowb + n) * 160 + lg * 8;
        f32x4 acc[2] = {};
#pragma unroll
        for (int ks = 0; ks < 5; ++ks) {
            bf16x8 b = *(const bf16x8*)(bp + ks * 32);
            acc[0] = __builtin_amdgcn_mfma_f32_16x16x32_bf16(a[0][ks], b, acc[0], 0, 0, 0);
            acc[1] = __builtin_amdgcn_mfma_f32_16x16x32_bf16(a[1][ks], b, acc[1], 0, 0, 0);
        }
#pragma unroll
        for (int ct = 0; ct < 2; ++ct) {
            u16x4 q;
#pragma unroll
            for (int r = 0; r < 4; ++r) {
                int co = ct * 16 + 4 * lg + r;
                float* xp = x + xtb + (size_t)co * 512 + n;
                float nv = *xp - 0.25f * (acc[ct][r] + bs[ct][r]);
                *xp = nv;
                q[r] = f2bf(nv);
            }
            *(u16x4*)(xbt + (size_t)n * 32 + ct * 16 + 4 * lg) = q;
        }
    }
}

// ---------------------------------------------------------------------------
__global__ __launch_bounds__(256) void k_lnstats(const float* __restrict__ x,
                                                 float* __restrict__ stats) {
    int eb = blockIdx.x;
    const float* p = x + ((size_t)(eb * 26 + 24) * 32) * 512;
    float s = 0.f, s2 = 0.f;
    for (int i = threadIdx.x; i < 32768; i += 256) {
        float v = p[i];
        s += v;
        s2 += v * v;
    }
    for (int off = 32; off; off >>= 1) {
        s += __shfl_down(s, off);
        s2 += __shfl_down(s2, off);
    }
    __shared__ float r1[4], r2[4];
    if ((threadIdx.x & 63) == 0) {
        r1[threadIdx.x >> 6] = s;
        r2[threadIdx.x >> 6] = s2;
    }
    __syncthreads();
    if (threadIdx.x == 0) {
        float S = r1[0] + r1[1] + r1[2] + r1[3];
        float S2 = r2[0] + r2[1] + r2[2] + r2[3];
        float mu = S / 32768.f;
        float var = S2 / 32768.f - mu * mu;
        stats[eb * 2] = mu;
        stats[eb * 2 + 1] = rsqrtf(var + 1e-5f);
    }
}

// ---------------------------------------------------------------------------
__global__ __launch_bounds__(256) void k_heads_mfma(
    const ushort_t* __restrict__ xb, const float* __restrict__ stats,
    float* __restrict__ bkc, float* __restrict__ acc,
    const ushort_t* __restrict__ Whd, const float* __restrict__ rS,
    const float* __restrict__ bb1, const float* __restrict__ bb2,
    const float* __restrict__ bfc1, const float* __restrict__ bfc2,
    int kb) {
    __shared__ __align__(16) ushort_t lds[4][64][72];
    int w = blockIdx.y, eb = blockIdx.z;
    int e = eb >> 3, ek = e * NBK + kb;
    int tid = threadIdx.x, wv = tid >> 6, lane = tid & 63;
    int l15 = lane & 15, lg = lane >> 4;
    int n0 = blockIdx.x * 256 + wv * 64;
    float mu = stats[eb * 2], rsv = stats[eb * 2 + 1];
    const ushort_t* Wh = Whd + (size_t)e * 6144;
    const ushort_t* xrow = xb + ((size_t)(eb * 26 + 24 + w) * 512) * 32;

#pragma unroll
    for (int head = 0; head < 2; ++head) {
        if (head == 1 && w == 0) break;  // fc only for w==1
        int woff = head ? 3072 : 0;
        const float* b1 = head ? bfc1 : bb1;
        const float* b2 = head ? bfc2 : bb2;
        const float* rs1 = rS + e * 128 + (head ? 64 : 0);
        bf16x8 a1[4];
#pragma unroll
        for (int rt = 0; rt < 4; ++rt)
            a1[rt] = *(const bf16x8*)(Wh + woff + (size_t)(rt * 16 + l15) * 32 + lg * 8);
        float be[4][4];
#pragma unroll
        for (int rt = 0; rt < 4; ++rt)
#pragma unroll
            for (int r = 0; r < 4; ++r) {
                int d = rt * 16 + 4 * lg + r;
                be[rt][r] = b1[ek * 64 + d] - rsv * mu * rs1[d];
            }
#pragma unroll
        for (int nt = 0; nt < 4; ++nt) {
            bf16x8 bv = *(const bf16x8*)(xrow + (size_t)(n0 + nt * 16 + l15) * 32 + lg * 8);
            f32x4 ac[4] = {};
#pragma unroll
            for (int rt = 0; rt < 4; ++rt)
                ac[rt] = __builtin_amdgcn_mfma_f32_16x16x32_bf16(a1[rt], bv, ac[rt], 0, 0, 0);
#pragma unroll
            for (int rt = 0; rt < 4; ++rt)
#pragma unroll
                for (int r = 0; r < 4; ++r) {
                    float hv = fmaxf(rsv * ac[rt][r] + be[rt][r], 0.f);
                    lds[wv][nt * 16 + l15][rt * 16 + 4 * lg + r] = f2bf(hv);
                }
        }
        bf16x8 a2[2];
        a2[0] = *(const bf16x8*)(Wh + woff + 2048 + (size_t)l15 * 64 + lg * 8);
        a2[1] = *(const bf16x8*)(Wh + woff + 2048 + (size_t)l15 * 64 + 32 + lg * 8);
        float b2v[4];
#pragma unroll
        for (int r = 0; r < 4; ++r) {
            int s = 4 * lg + r;
            b2v[r] = (s < 12) ? b2[ek * 12 + s] : 0.f;
        }
#pragma unroll
        for (int nt = 0; nt < 4; ++nt) {
            bf16x8 b0 = *(const bf16x8*)&lds[wv][nt * 16 + l15][lg * 8];
            bf16x8 b1f = *(const bf16x8*)&lds[wv][nt * 16 + l15][32 + lg * 8];
            f32x4 ac2 = {};
            ac2 = __builtin_amdgcn_mfma_f32_16x16x32_bf16(a2[0], b0, ac2, 0, 0, 0);
            ac2 = __builtin_amdgcn_mfma_f32_16x16x32_bf16(a2[1], b1f, ac2, 0, 0, 0);
#pragma unroll
            for (int r = 0; r < 4; ++r) {
                int s = 4 * lg + r;
                if (s < 12) {
                    int n = n0 + nt * 16 + l15;
                    float val = ac2[r] + b2v[r];
                    if (head == 0)
                        bkc[((size_t)(eb * 12 + s) * 512 + n) * 2 + w] -= val;
                    else
                        acc[(size_t)(eb * 12 + s) * 512 + n] += val;
                }
            }
        }
    }
}

// ---------------------------------------------------------------------------
__global__ __launch_bounds__(256) void k_final(const float* __restrict__ acc,
                                               const float* __restrict__ ew,
                                               float* __restrict__ out) {
    int i = blockIdx.x * 256 + threadIdx.x;  // 49152
    out[i] = ew[0] * acc[i] + ew[1] * acc[49152 + i];
}

// ---------------------------------------------------------------------------
extern "C" void kernel_launch(void* const* d_in, const int* in_sizes, int n_in,
                              void* d_out, int out_size, void* d_ws, size_t ws_size,
                              hipStream_t stream) {
    const float* X    = (const float*)d_in[0];
    const float* adj  = (const float*)d_in[1];
    const float* ew   = (const float*)d_in[2];
    const float* Wst  = (const float*)d_in[3];
    const float* bst  = (const float*)d_in[4];
    const float* Wf2  = (const float*)d_in[5];
    const float* Wf3  = (const float*)d_in[6];
    const float* Wf5  = (const float*)d_in[7];
    const float* Wf7  = (const float*)d_in[8];
    const float* bf   = (const float*)d_in[9];
    const float* Wg2  = (const float*)d_in[10];
    const float* Wg3  = (const float*)d_in[11];
    const float* Wg5  = (const float*)d_in[12];
    const float* Wg7  = (const float*)d_in[13];
    const float* bg   = (const float*)d_in[14];
    const float* Wgc1 = (const float*)d_in[15];
    const float* bgc1 = (const float*)d_in[16];
    const float* Wgc2 = (const float*)d_in[17];
    const float* bgc2 = (const float*)d_in[18];
    const float* Wb1  = (const float*)d_in[19];
    const float* bb1  = (const float*)d_in[20];
    const float* Wb2  = (const float*)d_in[21];
    const float* bb2  = (const float*)d_in[22];
    const float* Wfc1 = (const float*)d_in[23];
    const float* bfc1 = (const float*)d_in[24];
    const float* Wfc2 = (const float*)d_in[25];
    const float* bfc2 = (const float*)d_in[26];

    float* ws = (float*)d_ws;
    size_t off = 0;
    auto alloc = [&](size_t nf) { float* p = ws + off; off += nf; return p; };
    float* di    = alloc(512);
    ushort_t* Anb  = (ushort_t*)alloc(512 * 512 / 2);
    ushort_t* AnTb = (ushort_t*)alloc(512 * 512 / 2);
    float* bkc   = alloc((size_t)EE * BATCH * 12 * 512 * 2);
    float* acc   = alloc((size_t)EE * BATCH * 12 * 512);
    float* stats = alloc(32);
    ushort_t* Amix = (ushort_t*)alloc(2 * 32 * 160 / 2);
    float* bsum  = alloc(64);
    ushort_t* Wb = (ushort_t*)alloc(14336);
    ushort_t* Whd = (ushort_t*)alloc(6144);
    float* rSb   = alloc(256);
    float* x     = alloc((size_t)16 * 26 * 32 * 512);
    ushort_t* xb = (ushort_t*)alloc((size_t)16 * 26 * 512 * 32 / 2);
    size_t hbuf_f = (size_t)16 * 20 * 32 * 512 / 2;  // bf16 old-layout, float units
    ushort_t* h   = (ushort_t*)alloc(hbuf_f);
    ushort_t* u1  = (ushort_t*)alloc(hbuf_f);
    ushort_t* u1t = (ushort_t*)alloc(hbuf_f);
    ushort_t* buf5 = (ushort_t*)alloc((size_t)16 * 20 * 512 * 160 / 2);
    if (off * sizeof(float) > ws_size) return;  // workspace too small: bail

    // Graph normalization
    k_rowsum<<<512, 256, 0, stream>>>(adj, di);
    k_norm<<<1024, 256, 0, stream>>>(adj, di, Anb, AnTb);

    // Residual init (both experts start from X) + output accumulator zero
    hipMemcpyAsync(bkc, X, (size_t)98304 * 4, hipMemcpyDeviceToDevice, stream);
    hipMemcpyAsync(bkc + 98304, X, (size_t)98304 * 4, hipMemcpyDeviceToDevice, stream);
    hipMemsetAsync(acc, 0, (size_t)EE * BATCH * 12 * 512 * 4, stream);

    for (int kb = 0; kb < NBK; ++kb) {
        k_prepmixA<<<2, 256, 0, stream>>>(Wgc1, bgc1, Wgc2, bgc2, Amix, bsum, kb);
        k_prepw<<<112, 256, 0, stream>>>(Wf2, Wf3, Wf5, Wf7, Wg2, Wg3, Wg5, Wg7, Wb, kb);
        k_preph<<<2, 256, 0, stream>>>(Wb1, Wb2, Wfc1, Wfc2, Whd, rSb, kb);
        k_start<<<dim3(2, 26, 16), 256, 0, stream>>>(bkc, x, xb, Wst, bst, kb);
        int cur = 26;
        for (int it = 0; it < 4; ++it) {
            int L = cur - 6;
            k_incept_mfma<<<dim3(4, L, 16), 256, 0, stream>>>(
                xb, h, buf5, Wb, bf, bg, kb, cur, L);
            k_gemm_dual<<<dim3(2 * L, 8, 2), 256, 0, stream>>>(
                h, Anb, u1, h, AnTb, u1t, buf5, 1, 3);
            k_gemm_y<<<dim3(2 * L, 8, 2), 256, 0, stream>>>(
                u1, Anb, u1t, AnTb, buf5, 2, 4);
            k_combine_mfma<<<dim3(L, 16), 256, 0, stream>>>(x, xb, buf5, Amix, bsum, L);
            cur -= 6;
        }
        k_lnstats<<<16, 256, 0, stream>>>(x, stats);
        k_heads_mfma<<<dim3(2, 2, 16), 256, 0, stream>>>(xb, stats, bkc, acc, Whd, rSb,
                                                         bb1, bb2, bfc1, bfc2, kb);
    }
    k_final<<<192, 256, 0, stream>>>(acc, ew, (float*)d_out);
}

// Round 9
// 994.589 us; speedup vs baseline: 3.4151x; 1.0885x over previous
//
#include <hip/hip_runtime.h>
#include <stddef.h>

// Problem constants (E=2 experts, NB=2 blocks, B=8 batch, N=512 nodes)
#define EE 2
#define NBK 2
#define BATCH 8

typedef unsigned short ushort_t;
typedef short bf16x8 __attribute__((ext_vector_type(8)));
typedef float f32x4 __attribute__((ext_vector_type(4)));
typedef unsigned short u16x4 __attribute__((ext_vector_type(4)));

__device__ __forceinline__ ushort_t f2bf(float f) {
    unsigned int u = __float_as_uint(f);
    u += 0x7FFF + ((u >> 16) & 1);
    return (ushort_t)(u >> 16);
}
__device__ __forceinline__ float bf2f(ushort_t h) {
    return __uint_as_float(((unsigned int)h) << 16);
}

// ---------------------------------------------------------------------------
__global__ __launch_bounds__(256) void k_rowsum(const float* __restrict__ adj,
                                                float* __restrict__ di) {
    int v = blockIdx.x;
    int tid = threadIdx.x;
    float s = 0.f;
    for (int w = tid; w < 512; w += 256)
        s += adj[v * 512 + w] + (w == v ? 1.f : 0.f);
    for (int off = 32; off; off >>= 1) s += __shfl_down(s, off);
    __shared__ float red[4];
    if ((tid & 63) == 0) red[tid >> 6] = s;
    __syncthreads();
    if (tid == 0) {
        float t = red[0] + red[1] + red[2] + red[3];
        di[v] = rsqrtf(t);
    }
}

__global__ __launch_bounds__(256) void k_norm(const float* __restrict__ adj,
                                              const float* __restrict__ di,
                                              ushort_t* __restrict__ An,
                                              ushort_t* __restrict__ AnT) {
    int idx = blockIdx.x * 256 + threadIdx.x;  // 0..262143
    int v = idx >> 9, w = idx & 511;
    float a = adj[idx] + (v == w ? 1.f : 0.f);
    ushort_t val = f2bf(di[v] * a * di[w]);
    An[idx] = val;
    AnT[w * 512 + v] = val;
}

// ---------------------------------------------------------------------------
// An2 = An·An (row-major); An2T = (An2)^T. NT GEMM: An2[p][w] = sum_v An[p][v]*AnT[w][v]
// grid (2, 8), 4 waves/block: wave = 64 rows x 64 cols block tile.
__global__ __launch_bounds__(256) void k_An2(
    const ushort_t* __restrict__ Anb, const ushort_t* __restrict__ AnTb,
    ushort_t* __restrict__ An2, ushort_t* __restrict__ An2T) {
    int tid = threadIdx.x;
    int w = tid >> 6, lane = tid & 63;
    int l15 = lane & 15, lg = lane >> 4;
    int wbase = blockIdx.x * 256 + w * 64;
    int n0 = blockIdx.y * 64;
    f32x4 acc[4][4] = {};
    const ushort_t* Ap = Anb + (size_t)(wbase + l15) * 512 + lg * 8;
    const ushort_t* Bp = AnTb + (size_t)(n0 + l15) * 512 + lg * 8;
#pragma unroll 4
    for (int k0 = 0; k0 < 512; k0 += 32) {
        bf16x8 av[4], bv[4];
#pragma unroll
        for (int mf = 0; mf < 4; ++mf)
            av[mf] = *(const bf16x8*)(Ap + (size_t)mf * 16 * 512 + k0);
#pragma unroll
        for (int nf = 0; nf < 4; ++nf)
            bv[nf] = *(const bf16x8*)(Bp + (size_t)nf * 16 * 512 + k0);
#pragma unroll
        for (int mf = 0; mf < 4; ++mf)
#pragma unroll
            for (int nf = 0; nf < 4; ++nf)
                acc[mf][nf] = __builtin_amdgcn_mfma_f32_16x16x32_bf16(
                    av[mf], bv[nf], acc[mf][nf], 0, 0, 0);
    }
#pragma unroll
    for (int mf = 0; mf < 4; ++mf)
#pragma unroll
        for (int nf = 0; nf < 4; ++nf) {
            int col = n0 + 16 * nf + l15;
            int row0 = wbase + 16 * mf + 4 * lg;
            u16x4 q;
#pragma unroll
            for (int r = 0; r < 4; ++r) {
                ushort_t vb = f2bf(acc[mf][nf][r]);
                q[r] = vb;
                An2[(size_t)(row0 + r) * 512 + col] = vb;
            }
            *(u16x4*)(An2T + (size_t)col * 512 + row0) = q;
        }
}

// ---------------------------------------------------------------------------
// Pack inception weights into dense bf16 Weff[e][fg][dt][ot][o16][c32]
__global__ __launch_bounds__(256) void k_prepw(
    const float* __restrict__ Wf2, const float* __restrict__ Wf3,
    const float* __restrict__ Wf5, const float* __restrict__ Wf7,
    const float* __restrict__ Wg2, const float* __restrict__ Wg3,
    const float* __restrict__ Wg5, const float* __restrict__ Wg7,
    ushort_t* __restrict__ Wb, int kb) {
    int idx = blockIdx.x * 256 + threadIdx.x;  // 28672 total
    if (idx >= 2 * 2 * 7 * 2 * 16 * 32) return;
    int c = idx & 31;
    int t1 = idx >> 5;
    int o16 = t1 & 15;
    int t2 = t1 >> 4;
    int ot = t2 & 1;
    int t3 = t2 >> 1;
    int dt = t3 % 7;
    int t4 = t3 / 7;
    int fg = t4 & 1;
    int e = t4 >> 1;
    int ek = e * NBK + kb;
    int o = ot * 16 + o16;
    int grp = o >> 3, oo = o & 7;
    const int kstab[4] = {2, 3, 5, 7};
    int ks = kstab[grp];
    int lo = 7 - ks;
    float val = 0.f;
    if (dt >= lo) {
        int di = dt - lo;
        const float* W;
        if (grp == 0) W = (fg ? Wg2 : Wf2) + (size_t)ek * 512 + oo * 64 + c * 2 + di;
        else if (grp == 1) W = (fg ? Wg3 : Wf3) + (size_t)ek * 768 + oo * 96 + c * 3 + di;
        else if (grp == 2) W = (fg ? Wg5 : Wf5) + (size_t)ek * 1280 + oo * 160 + c * 5 + di;
        else W = (fg ? Wg7 : Wf7) + (size_t)ek * 1792 + oo * 224 + c * 7 + di;
        val = *W;
    }
    Wb[idx] = f2bf(val);
}

// ---------------------------------------------------------------------------
// Pack head weights + fp32 rowsums
__global__ __launch_bounds__(256) void k_preph(
    const float* __restrict__ Wb1, const float* __restrict__ Wb2,
    const float* __restrict__ Wfc1, const float* __restrict__ Wfc2,
    ushort_t* __restrict__ Whd, float* __restrict__ rS, int kb) {
    int e = blockIdx.x;
    int ek = e * NBK + kb;
    ushort_t* Wh = Whd + (size_t)e * 6144;
    for (int i = threadIdx.x; i < 2048; i += 256)
        Wh[i] = f2bf(Wb1[(size_t)ek * 2048 + i]);
    for (int i = threadIdx.x; i < 1024; i += 256) {
        int r = i >> 6, d = i & 63;
        Wh[2048 + i] = f2bf(r < 12 ? Wb2[(size_t)ek * 768 + r * 64 + d] : 0.f);
    }
    for (int i = threadIdx.x; i < 2048; i += 256)
        Wh[3072 + i] = f2bf(Wfc1[(size_t)ek * 2048 + i]);
    for (int i = threadIdx.x; i < 1024; i += 256) {
        int r = i >> 6, d = i & 63;
        Wh[5120 + i] = f2bf(r < 12 ? Wfc2[(size_t)ek * 768 + r * 64 + d] : 0.f);
    }
    if (threadIdx.x < 64) {
        int d = threadIdx.x;
        float s1 = 0.f, s2 = 0.f;
        for (int c = 0; c < 32; ++c) {
            s1 += Wb1[(size_t)ek * 2048 + d * 32 + c];
            s2 += Wfc1[(size_t)ek * 2048 + d * 32 + c];
        }
        rS[e * 128 + d] = s1;
        rS[e * 128 + 64 + d] = s2;
    }
}

// ---------------------------------------------------------------------------
// Pack mix matrices bf16 Amix[e][c_out=32][k=160] + bsum fp32[e][32]
__global__ __launch_bounds__(256) void k_prepmixA(const float* __restrict__ Wgc1,
                                                  const float* __restrict__ bgc1,
                                                  const float* __restrict__ Wgc2,
                                                  const float* __restrict__ bgc2,
                                                  ushort_t* __restrict__ Amix,
                                                  float* __restrict__ bsum, int kb) {
    int e = blockIdx.x;
    int ek = e * NBK + kb;
    const float* W1 = Wgc1 + (size_t)ek * 32 * 96;
    const float* W2 = Wgc2 + (size_t)ek * 32 * 96;
    for (int idx = threadIdx.x; idx < 32 * 160; idx += 256) {
        int co = idx / 160, k = idx % 160;
        int slot = k >> 5, cp = k & 31;
        float val;
        if (slot == 0)
            val = W1[co * 96 + cp] + W1[co * 96 + 32 + cp] + W1[co * 96 + 64 + cp] +
                  W2[co * 96 + cp] + W2[co * 96 + 32 + cp] + W2[co * 96 + 64 + cp];
        else if (slot == 1) val = 0.5f * W1[co * 96 + 32 + cp] + W1[co * 96 + 64 + cp];
        else if (slot == 2) val = 0.25f * W1[co * 96 + 64 + cp];
        else if (slot == 3) val = 0.5f * W2[co * 96 + 32 + cp] + W2[co * 96 + 64 + cp];
        else val = 0.25f * W2[co * 96 + 64 + cp];
        Amix[((size_t)e * 32 + co) * 160 + k] = f2bf(val);
    }
    if (threadIdx.x < 32)
        bsum[e * 32 + threadIdx.x] =
            bgc1[ek * 32 + threadIdx.x] + bgc2[ek * 32 + threadIdx.x];
}

// ---------------------------------------------------------------------------
// start: writes x fp32 [eb][t][c][n] and bf16 mirror xb [eb][t][n][c]
__global__ __launch_bounds__(256) void k_start(const float* __restrict__ bkc,
                                               float* __restrict__ x,
                                               ushort_t* __restrict__ xb,
                                               const float* __restrict__ Wst,
                                               const float* __restrict__ bst,
                                               int kb) {
    int n = blockIdx.x * 256 + threadIdx.x;
    int t = blockIdx.y;
    int eb = blockIdx.z;
    int e = eb >> 3;
    int ek = e * NBK + kb;
    const float* Wp = Wst + (size_t)ek * 32 * 2;
    const float* bp = bst + (size_t)ek * 32;
    float in0 = 0.f, in1 = 0.f;
    if (t >= 14) {
        const float* p = bkc + ((size_t)(eb * 12 + (t - 14)) * 512 + n) * 2;
        in0 = p[0];
        in1 = p[1];
    }
    float* xo = x + ((size_t)(eb * 26 + t) * 32) * 512 + n;
    ushort_t tmp[32];
#pragma unroll
    for (int c = 0; c < 32; ++c) {
        float v = bp[c] + Wp[c * 2] * in0 + Wp[c * 2 + 1] * in1;
        xo[(size_t)c * 512] = v;
        tmp[c] = f2bf(v);
    }
    ushort_t* xbp = xb + ((size_t)(eb * 26 + t) * 512 + n) * 32;
#pragma unroll
    for (int q = 0; q < 4; ++q)
        *(bf16x8*)(xbp + q * 8) = *(bf16x8*)(tmp + q * 8);
}

// ---------------------------------------------------------------------------
// MFMA inception: writes h_old [col][n] (GEMM A operand) + buf5 slot0 (Y)
__global__ __launch_bounds__(256) void k_incept_mfma(
    const ushort_t* __restrict__ xb, ushort_t* __restrict__ h,
    ushort_t* __restrict__ buf5, const ushort_t* __restrict__ Wb,
    const float* __restrict__ bf, const float* __restrict__ bg,
    int kb, int cur_len, int L) {
    int j = blockIdx.y, eb = blockIdx.z, e = eb >> 3, ek = e * NBK + kb;
    int tid = threadIdx.x;
    int w = tid >> 6, lane = tid & 63;
    int l15 = lane & 15, lg = lane >> 4;
    int ot = w >> 1;
    int n0base = blockIdx.x * 128 + (w & 1) * 64;
    int t0 = 26 - cur_len + j;

    const ushort_t* WbE = Wb + (size_t)e * 14336;
    bf16x8 af_[7], ag_[7];
#pragma unroll
    for (int dt = 0; dt < 7; ++dt) {
        af_[dt] = *(const bf16x8*)(WbE + ((size_t)(dt * 2 + ot) * 16 + l15) * 32 + lg * 8);
        ag_[dt] = *(const bf16x8*)(WbE + 7168 + ((size_t)(dt * 2 + ot) * 16 + l15) * 32 + lg * 8);
    }
    float bfv[4], bgv[4];
#pragma unroll
    for (int r = 0; r < 4; ++r) {
        int o = ot * 16 + 4 * lg + r;
        bfv[r] = bf[ek * 32 + o];
        bgv[r] = bg[ek * 32 + o];
    }
    size_t colbase = ((size_t)eb * L + j) * 32;
    size_t rowb = ((size_t)eb * L + j) * 512;
    const ushort_t* xe = xb + ((size_t)eb * 26) * 512 * 32;
#pragma unroll
    for (int nt = 0; nt < 4; ++nt) {
        int n0 = n0base + nt * 16;
        f32x4 accf = {}, accg = {};
#pragma unroll
        for (int dt = 0; dt < 7; ++dt) {
            bf16x8 bfr = *(const bf16x8*)(xe + ((size_t)(t0 + dt) * 512 + n0 + l15) * 32 + lg * 8);
            accf = __builtin_amdgcn_mfma_f32_16x16x32_bf16(af_[dt], bfr, accf, 0, 0, 0);
            accg = __builtin_amdgcn_mfma_f32_16x16x32_bf16(ag_[dt], bfr, accg, 0, 0, 0);
        }
        u16x4 q;
#pragma unroll
        for (int r = 0; r < 4; ++r) {
            float a = accf[r] + bfv[r];
            float b = accg[r] + bgv[r];
            float hv = tanhf(a) * (1.f / (1.f + expf(-b)));
            ushort_t hb = f2bf(hv);
            q[r] = hb;
            int o = ot * 16 + 4 * lg + r;
            h[(colbase + o) * 512 + n0 + l15] = hb;
        }
        *(u16x4*)(buf5 + (rowb + n0 + l15) * 160 + ot * 16 + 4 * lg) = q;
    }
}

// ---------------------------------------------------------------------------
// 4-way NT GEMM from h: slot z+1 of buf5 = h @ Bz^T, Y-layout store only.
// z: 0->An (u1), 1->An2 (v1), 2->AnT (u1t), 3->An2T (v1t)
__global__ __launch_bounds__(256) void k_gemm4(
    const ushort_t* __restrict__ A,
    const ushort_t* __restrict__ B0, const ushort_t* __restrict__ B1,
    const ushort_t* __restrict__ B2, const ushort_t* __restrict__ B3,
    ushort_t* __restrict__ buf5) {
    int z = blockIdx.z;
    const ushort_t* B = (z == 0) ? B0 : (z == 1) ? B1 : (z == 2) ? B2 : B3;
    int slot = z + 1;
    int tid = threadIdx.x;
    int w = tid >> 6, lane = tid & 63;
    int l15 = lane & 15, lg = lane >> 4;
    int wbase = blockIdx.x * 256 + w * 64;
    int n0 = blockIdx.y * 64;
    f32x4 acc[4][4] = {};
    const ushort_t* Ap = A + (size_t)(wbase + l15) * 512 + lg * 8;
    const ushort_t* Bp = B + (size_t)(n0 + l15) * 512 + lg * 8;
#pragma unroll 4
    for (int k0 = 0; k0 < 512; k0 += 32) {
        bf16x8 av[4], bv[4];
#pragma unroll
        for (int mf = 0; mf < 4; ++mf)
            av[mf] = *(const bf16x8*)(Ap + (size_t)mf * 16 * 512 + k0);
#pragma unroll
        for (int nf = 0; nf < 4; ++nf)
            bv[nf] = *(const bf16x8*)(Bp + (size_t)nf * 16 * 512 + k0);
#pragma unroll
        for (int mf = 0; mf < 4; ++mf)
#pragma unroll
            for (int nf = 0; nf < 4; ++nf)
                acc[mf][nf] = __builtin_amdgcn_mfma_f32_16x16x32_bf16(
                    av[mf], bv[nf], acc[mf][nf], 0, 0, 0);
    }
#pragma unroll
    for (int mf = 0; mf < 4; ++mf) {
        int jeb = (wbase >> 5) + (mf >> 1);
        int c0 = 16 * (mf & 1) + 4 * lg;
#pragma unroll
        for (int nf = 0; nf < 4; ++nf) {
            int col = n0 + 16 * nf + l15;
            u16x4 q;
#pragma unroll
            for (int r = 0; r < 4; ++r) q[r] = f2bf(acc[mf][nf][r]);
            *(u16x4*)(buf5 + ((size_t)jeb * 512 + col) * 160 + slot * 32 + c0) = q;
        }
    }
}

// ---------------------------------------------------------------------------
// MFMA combine: g = Amix @ buf5^T + bsum; x -= 0.25*g; xb = bf16(x)
__global__ __launch_bounds__(256) void k_combine_mfma(
    float* __restrict__ x, ushort_t* __restrict__ xb,
    const ushort_t* __restrict__ buf5, const ushort_t* __restrict__ Amix,
    const float* __restrict__ bsum, int L) {
    int j = blockIdx.x, eb = blockIdx.y, e = eb >> 3;
    int tid = threadIdx.x, wv = tid >> 6, lane = tid & 63;
    int l15 = lane & 15, lg = lane >> 4;
    int t = 26 - L + j;
    const ushort_t* Ae = Amix + (size_t)e * 32 * 160;
    bf16x8 a[2][5];
#pragma unroll
    for (int ct = 0; ct < 2; ++ct)
#pragma unroll
        for (int ks = 0; ks < 5; ++ks)
            a[ct][ks] = *(const bf16x8*)(Ae + (size_t)(ct * 16 + l15) * 160 + ks * 32 + lg * 8);
    float bs[2][4];
#pragma unroll
    for (int ct = 0; ct < 2; ++ct)
#pragma unroll
        for (int r = 0; r < 4; ++r) bs[ct][r] = bsum[e * 32 + ct * 16 + 4 * lg + r];
    size_t rowb = ((size_t)eb * L + j) * 512;
    size_t xtb = ((size_t)(eb * 26 + t) * 32) * 512;
    ushort_t* xbt = xb + ((size_t)(eb * 26 + t) * 512) * 32;
#pragma unroll
    for (int nt = 0; nt < 8; ++nt) {
        int n = wv * 128 + nt * 16 + l15;
        const ushort_t* bp = buf5 + (rowb + n) * 160 + lg * 8;
        f32x4 acc[2] = {};
#pragma unroll
        for (int ks = 0; ks < 5; ++ks) {
            bf16x8 b = *(const bf16x8*)(bp + ks * 32);
            acc[0] = __builtin_amdgcn_mfma_f32_16x16x32_bf16(a[0][ks], b, acc[0], 0, 0, 0);
            acc[1] = __builtin_amdgcn_mfma_f32_16x16x32_bf16(a[1][ks], b, acc[1], 0, 0, 0);
        }
#pragma unroll
        for (int ct = 0; ct < 2; ++ct) {
            u16x4 q;
#pragma unroll
            for (int r = 0; r < 4; ++r) {
                int co = ct * 16 + 4 * lg + r;
                float* xp = x + xtb + (size_t)co * 512 + n;
                float nv = *xp - 0.25f * (acc[ct][r] + bs[ct][r]);
                *xp = nv;
                q[r] = f2bf(nv);
            }
            *(u16x4*)(xbt + (size_t)n * 32 + ct * 16 + 4 * lg) = q;
        }
    }
}

// ---------------------------------------------------------------------------
__global__ __launch_bounds__(256) void k_lnstats(const float* __restrict__ x,
                                                 float* __restrict__ stats) {
    int eb = blockIdx.x;
    const float* p = x + ((size_t)(eb * 26 + 24) * 32) * 512;
    float s = 0.f, s2 = 0.f;
    for (int i = threadIdx.x; i < 32768; i += 256) {
        float v = p[i];
        s += v;
        s2 += v * v;
    }
    for (int off = 32; off; off >>= 1) {
        s += __shfl_down(s, off);
        s2 += __shfl_down(s2, off);
    }
    __shared__ float r1[4], r2[4];
    if ((threadIdx.x & 63) == 0) {
        r1[threadIdx.x >> 6] = s;
        r2[threadIdx.x >> 6] = s2;
    }
    __syncthreads();
    if (threadIdx.x == 0) {
        float S = r1[0] + r1[1] + r1[2] + r1[3];
        float S2 = r2[0] + r2[1] + r2[2] + r2[3];
        float mu = S / 32768.f;
        float var = S2 / 32768.f - mu * mu;
        stats[eb * 2] = mu;
        stats[eb * 2 + 1] = rsqrtf(var + 1e-5f);
    }
}

// ---------------------------------------------------------------------------
__global__ __launch_bounds__(256) void k_heads_mfma(
    const ushort_t* __restrict__ xb, const float* __restrict__ stats,
    float* __restrict__ bkc, float* __restrict__ acc,
    const ushort_t* __restrict__ Whd, const float* __restrict__ rS,
    const float* __restrict__ bb1, const float* __restrict__ bb2,
    const float* __restrict__ bfc1, const float* __restrict__ bfc2,
    int kb) {
    __shared__ __align__(16) ushort_t lds[4][64][72];
    int w = blockIdx.y, eb = blockIdx.z;
    int e = eb >> 3, ek = e * NBK + kb;
    int tid = threadIdx.x, wv = tid >> 6, lane = tid & 63;
    int l15 = lane & 15, lg = lane >> 4;
    int n0 = blockIdx.x * 256 + wv * 64;
    float mu = stats[eb * 2], rsv = stats[eb * 2 + 1];
    const ushort_t* Wh = Whd + (size_t)e * 6144;
    const ushort_t* xrow = xb + ((size_t)(eb * 26 + 24 + w) * 512) * 32;

#pragma unroll
    for (int head = 0; head < 2; ++head) {
        if (head == 1 && w == 0) break;  // fc only for w==1
        int woff = head ? 3072 : 0;
        const float* b1 = head ? bfc1 : bb1;
        const float* b2 = head ? bfc2 : bb2;
        const float* rs1 = rS + e * 128 + (head ? 64 : 0);
        bf16x8 a1[4];
#pragma unroll
        for (int rt = 0; rt < 4; ++rt)
            a1[rt] = *(const bf16x8*)(Wh + woff + (size_t)(rt * 16 + l15) * 32 + lg * 8);
        float be[4][4];
#pragma unroll
        for (int rt = 0; rt < 4; ++rt)
#pragma unroll
            for (int r = 0; r < 4; ++r) {
                int d = rt * 16 + 4 * lg + r;
                be[rt][r] = b1[ek * 64 + d] - rsv * mu * rs1[d];
            }
#pragma unroll
        for (int nt = 0; nt < 4; ++nt) {
            bf16x8 bv = *(const bf16x8*)(xrow + (size_t)(n0 + nt * 16 + l15) * 32 + lg * 8);
            f32x4 ac[4] = {};
#pragma unroll
            for (int rt = 0; rt < 4; ++rt)
                ac[rt] = __builtin_amdgcn_mfma_f32_16x16x32_bf16(a1[rt], bv, ac[rt], 0, 0, 0);
#pragma unroll
            for (int rt = 0; rt < 4; ++rt)
#pragma unroll
                for (int r = 0; r < 4; ++r) {
                    float hv = fmaxf(rsv * ac[rt][r] + be[rt][r], 0.f);
                    lds[wv][nt * 16 + l15][rt * 16 + 4 * lg + r] = f2bf(hv);
                }
        }
        bf16x8 a2[2];
        a2[0] = *(const bf16x8*)(Wh + woff + 2048 + (size_t)l15 * 64 + lg * 8);
        a2[1] = *(const bf16x8*)(Wh + woff + 2048 + (size_t)l15 * 64 + 32 + lg * 8);
        float b2v[4];
#pragma unroll
        for (int r = 0; r < 4; ++r) {
            int s = 4 * lg + r;
            b2v[r] = (s < 12) ? b2[ek * 12 + s] : 0.f;
        }
#pragma unroll
        for (int nt = 0; nt < 4; ++nt) {
            bf16x8 b0 = *(const bf16x8*)&lds[wv][nt * 16 + l15][lg * 8];
            bf16x8 b1f = *(const bf16x8*)&lds[wv][nt * 16 + l15][32 + lg * 8];
            f32x4 ac2 = {};
            ac2 = __builtin_amdgcn_mfma_f32_16x16x32_bf16(a2[0], b0, ac2, 0, 0, 0);
            ac2 = __builtin_amdgcn_mfma_f32_16x16x32_bf16(a2[1], b1f, ac2, 0, 0, 0);
#pragma unroll
            for (int r = 0; r < 4; ++r) {
                int s = 4 * lg + r;
                if (s < 12) {
                    int n = n0 + nt * 16 + l15;
                    float val = ac2[r] + b2v[r];
                    if (head == 0)
                        bkc[((size_t)(eb * 12 + s) * 512 + n) * 2 + w] -= val;
                    else
                        acc[(size_t)(eb * 12 + s) * 512 + n] += val;
                }
            }
        }
    }
}

// ---------------------------------------------------------------------------
__global__ __launch_bounds__(256) void k_final(const float* __restrict__ acc,
                                               const float* __restrict__ ew,
                                               float* __restrict__ out) {
    int i = blockIdx.x * 256 + threadIdx.x;  // 49152
    out[i] = ew[0] * acc[i] + ew[1] * acc[49152 + i];
}

// ---------------------------------------------------------------------------
extern "C" void kernel_launch(void* const* d_in, const int* in_sizes, int n_in,
                              void* d_out, int out_size, void* d_ws, size_t ws_size,
                              hipStream_t stream) {
    const float* X    = (const float*)d_in[0];
    const float* adj  = (const float*)d_in[1];
    const float* ew   = (const float*)d_in[2];
    const float* Wst  = (const float*)d_in[3];
    const float* bst  = (const float*)d_in[4];
    const float* Wf2  = (const float*)d_in[5];
    const float* Wf3  = (const float*)d_in[6];
    const float* Wf5  = (const float*)d_in[7];
    const float* Wf7  = (const float*)d_in[8];
    const float* bf   = (const float*)d_in[9];
    const float* Wg2  = (const float*)d_in[10];
    const float* Wg3  = (const float*)d_in[11];
    const float* Wg5  = (const float*)d_in[12];
    const float* Wg7  = (const float*)d_in[13];
    const float* bg   = (const float*)d_in[14];
    const float* Wgc1 = (const float*)d_in[15];
    const float* bgc1 = (const float*)d_in[16];
    const float* Wgc2 = (const float*)d_in[17];
    const float* bgc2 = (const float*)d_in[18];
    const float* Wb1  = (const float*)d_in[19];
    const float* bb1  = (const float*)d_in[20];
    const float* Wb2  = (const float*)d_in[21];
    const float* bb2  = (const float*)d_in[22];
    const float* Wfc1 = (const float*)d_in[23];
    const float* bfc1 = (const float*)d_in[24];
    const float* Wfc2 = (const float*)d_in[25];
    const float* bfc2 = (const float*)d_in[26];

    float* ws = (float*)d_ws;
    size_t off = 0;
    auto alloc = [&](size_t nf) { float* p = ws + off; off += nf; return p; };
    float* di    = alloc(512);
    ushort_t* Anb   = (ushort_t*)alloc(512 * 512 / 2);
    ushort_t* AnTb  = (ushort_t*)alloc(512 * 512 / 2);
    ushort_t* An2b  = (ushort_t*)alloc(512 * 512 / 2);
    ushort_t* An2Tb = (ushort_t*)alloc(512 * 512 / 2);
    float* bkc   = alloc((size_t)EE * BATCH * 12 * 512 * 2);
    float* acc   = alloc((size_t)EE * BATCH * 12 * 512);
    float* stats = alloc(32);
    ushort_t* Amix = (ushort_t*)alloc(2 * 32 * 160 / 2);
    float* bsum  = alloc(64);
    ushort_t* Wb = (ushort_t*)alloc(14336);
    ushort_t* Whd = (ushort_t*)alloc(6144);
    float* rSb   = alloc(256);
    float* x     = alloc((size_t)16 * 26 * 32 * 512);
    ushort_t* xb = (ushort_t*)alloc((size_t)16 * 26 * 512 * 32 / 2);
    size_t hbuf_f = (size_t)16 * 20 * 32 * 512 / 2;  // bf16 old-layout, float units
    ushort_t* h   = (ushort_t*)alloc(hbuf_f);
    ushort_t* buf5 = (ushort_t*)alloc((size_t)16 * 20 * 512 * 160 / 2);
    if (off * sizeof(float) > ws_size) return;  // workspace too small: bail

    // Graph normalization + An^2 precompute
    k_rowsum<<<512, 256, 0, stream>>>(adj, di);
    k_norm<<<1024, 256, 0, stream>>>(adj, di, Anb, AnTb);
    k_An2<<<dim3(2, 8), 256, 0, stream>>>(Anb, AnTb, An2b, An2Tb);

    // Residual init (both experts start from X) + output accumulator zero
    hipMemcpyAsync(bkc, X, (size_t)98304 * 4, hipMemcpyDeviceToDevice, stream);
    hipMemcpyAsync(bkc + 98304, X, (size_t)98304 * 4, hipMemcpyDeviceToDevice, stream);
    hipMemsetAsync(acc, 0, (size_t)EE * BATCH * 12 * 512 * 4, stream);

    for (int kb = 0; kb < NBK; ++kb) {
        k_prepmixA<<<2, 256, 0, stream>>>(Wgc1, bgc1, Wgc2, bgc2, Amix, bsum, kb);
        k_prepw<<<112, 256, 0, stream>>>(Wf2, Wf3, Wf5, Wf7, Wg2, Wg3, Wg5, Wg7, Wb, kb);
        k_preph<<<2, 256, 0, stream>>>(Wb1, Wb2, Wfc1, Wfc2, Whd, rSb, kb);
        k_start<<<dim3(2, 26, 16), 256, 0, stream>>>(bkc, x, xb, Wst, bst, kb);
        int cur = 26;
        for (int it = 0; it < 4; ++it) {
            int L = cur - 6;
            k_incept_mfma<<<dim3(4, L, 16), 256, 0, stream>>>(
                xb, h, buf5, Wb, bf, bg, kb, cur, L);
            k_gemm4<<<dim3(2 * L, 8, 4), 256, 0, stream>>>(
                h, Anb, An2b, AnTb, An2Tb, buf5);
            k_combine_mfma<<<dim3(L, 16), 256, 0, stream>>>(x, xb, buf5, Amix, bsum, L);
            cur -= 6;
        }
        k_lnstats<<<16, 256, 0, stream>>>(x, stats);
        k_heads_mfma<<<dim3(2, 2, 16), 256, 0, stream>>>(xb, stats, bkc, acc, Whd, rSb,
                                                         bb1, bb2, bfc1, bfc2, kb);
    }
    k_final<<<192, 256, 0, stream>>>(acc, ew, (float*)d_out);
}

// Round 10
// 897.422 us; speedup vs baseline: 3.7848x; 1.1083x over previous
//
#include <hip/hip_runtime.h>
#include <stddef.h>

// Problem constants (E=2 experts, NB=2 blocks, B=8 batch, N=512 nodes)
#define EE 2
#define NBK 2
#define BATCH 8

typedef unsigned short ushort_t;
typedef short bf16x8 __attribute__((ext_vector_type(8)));
typedef float f32x4 __attribute__((ext_vector_type(4)));
typedef unsigned short u16x4 __attribute__((ext_vector_type(4)));

__device__ __forceinline__ ushort_t f2bf(float f) {
    unsigned int u = __float_as_uint(f);
    u += 0x7FFF + ((u >> 16) & 1);
    return (ushort_t)(u >> 16);
}
__device__ __forceinline__ float bf2f(ushort_t h) {
    return __uint_as_float(((unsigned int)h) << 16);
}

// ---------------------------------------------------------------------------
__global__ __launch_bounds__(256) void k_rowsum(const float* __restrict__ adj,
                                                float* __restrict__ di) {
    int v = blockIdx.x;
    int tid = threadIdx.x;
    float s = 0.f;
    for (int w = tid; w < 512; w += 256)
        s += adj[v * 512 + w] + (w == v ? 1.f : 0.f);
    for (int off = 32; off; off >>= 1) s += __shfl_down(s, off);
    __shared__ float red[4];
    if ((tid & 63) == 0) red[tid >> 6] = s;
    __syncthreads();
    if (tid == 0) {
        float t = red[0] + red[1] + red[2] + red[3];
        di[v] = rsqrtf(t);
    }
}

__global__ __launch_bounds__(256) void k_norm(const float* __restrict__ adj,
                                              const float* __restrict__ di,
                                              ushort_t* __restrict__ An,
                                              ushort_t* __restrict__ AnT) {
    int idx = blockIdx.x * 256 + threadIdx.x;  // 0..262143
    int v = idx >> 9, w = idx & 511;
    float a = adj[idx] + (v == w ? 1.f : 0.f);
    ushort_t val = f2bf(di[v] * a * di[w]);
    An[idx] = val;
    AnT[w * 512 + v] = val;
}

// ---------------------------------------------------------------------------
// An2 = An·An (row-major); An2T = (An2)^T.
__global__ __launch_bounds__(256) void k_An2(
    const ushort_t* __restrict__ Anb, const ushort_t* __restrict__ AnTb,
    ushort_t* __restrict__ An2, ushort_t* __restrict__ An2T) {
    int tid = threadIdx.x;
    int w = tid >> 6, lane = tid & 63;
    int l15 = lane & 15, lg = lane >> 4;
    int wbase = blockIdx.x * 256 + w * 64;
    int n0 = blockIdx.y * 64;
    f32x4 acc[4][4] = {};
    const ushort_t* Ap = Anb + (size_t)(wbase + l15) * 512 + lg * 8;
    const ushort_t* Bp = AnTb + (size_t)(n0 + l15) * 512 + lg * 8;
    bf16x8 avC[4], bvC[4], avN[4], bvN[4];
#pragma unroll
    for (int i = 0; i < 4; ++i) {
        avC[i] = *(const bf16x8*)(Ap + (size_t)i * 16 * 512);
        bvC[i] = *(const bf16x8*)(Bp + (size_t)i * 16 * 512);
    }
#pragma unroll 2
    for (int k0 = 0; k0 < 512; k0 += 32) {
        int kn = k0 + 32;
        if (kn < 512) {
#pragma unroll
            for (int i = 0; i < 4; ++i) {
                avN[i] = *(const bf16x8*)(Ap + (size_t)i * 16 * 512 + kn);
                bvN[i] = *(const bf16x8*)(Bp + (size_t)i * 16 * 512 + kn);
            }
        }
#pragma unroll
        for (int mf = 0; mf < 4; ++mf)
#pragma unroll
            for (int nf = 0; nf < 4; ++nf)
                acc[mf][nf] = __builtin_amdgcn_mfma_f32_16x16x32_bf16(
                    avC[mf], bvC[nf], acc[mf][nf], 0, 0, 0);
#pragma unroll
        for (int i = 0; i < 4; ++i) { avC[i] = avN[i]; bvC[i] = bvN[i]; }
    }
#pragma unroll
    for (int mf = 0; mf < 4; ++mf)
#pragma unroll
        for (int nf = 0; nf < 4; ++nf) {
            int col = n0 + 16 * nf + l15;
            int row0 = wbase + 16 * mf + 4 * lg;
            u16x4 q;
#pragma unroll
            for (int r = 0; r < 4; ++r) {
                ushort_t vb = f2bf(acc[mf][nf][r]);
                q[r] = vb;
                An2[(size_t)(row0 + r) * 512 + col] = vb;
            }
            *(u16x4*)(An2T + (size_t)col * 512 + row0) = q;
        }
}

// ---------------------------------------------------------------------------
// Fused per-kb weight prep: blocks 0..111 -> inception Weff; 112,113 ->
// mix matrices (e = bx-112); 114,115 -> head weights (e = bx-114).
__global__ __launch_bounds__(256) void k_prep(
    const float* __restrict__ Wf2, const float* __restrict__ Wf3,
    const float* __restrict__ Wf5, const float* __restrict__ Wf7,
    const float* __restrict__ Wg2, const float* __restrict__ Wg3,
    const float* __restrict__ Wg5, const float* __restrict__ Wg7,
    ushort_t* __restrict__ Wb,
    const float* __restrict__ Wgc1, const float* __restrict__ bgc1,
    const float* __restrict__ Wgc2, const float* __restrict__ bgc2,
    ushort_t* __restrict__ Amix, float* __restrict__ bsum,
    const float* __restrict__ Wb1, const float* __restrict__ Wb2,
    const float* __restrict__ Wfc1, const float* __restrict__ Wfc2,
    ushort_t* __restrict__ Whd, float* __restrict__ rS, int kb) {
    int bx = blockIdx.x;
    if (bx < 112) {
        int idx = bx * 256 + threadIdx.x;  // 28672 total
        if (idx >= 2 * 2 * 7 * 2 * 16 * 32) return;
        int c = idx & 31;
        int t1 = idx >> 5;
        int o16 = t1 & 15;
        int t2 = t1 >> 4;
        int ot = t2 & 1;
        int t3 = t2 >> 1;
        int dt = t3 % 7;
        int t4 = t3 / 7;
        int fg = t4 & 1;
        int e = t4 >> 1;
        int ek = e * NBK + kb;
        int o = ot * 16 + o16;
        int grp = o >> 3, oo = o & 7;
        const int kstab[4] = {2, 3, 5, 7};
        int ks = kstab[grp];
        int lo = 7 - ks;
        float val = 0.f;
        if (dt >= lo) {
            int di = dt - lo;
            const float* W;
            if (grp == 0) W = (fg ? Wg2 : Wf2) + (size_t)ek * 512 + oo * 64 + c * 2 + di;
            else if (grp == 1) W = (fg ? Wg3 : Wf3) + (size_t)ek * 768 + oo * 96 + c * 3 + di;
            else if (grp == 2) W = (fg ? Wg5 : Wf5) + (size_t)ek * 1280 + oo * 160 + c * 5 + di;
            else W = (fg ? Wg7 : Wf7) + (size_t)ek * 1792 + oo * 224 + c * 7 + di;
            val = *W;
        }
        Wb[idx] = f2bf(val);
    } else if (bx < 114) {
        int e = bx - 112;
        int ek = e * NBK + kb;
        const float* W1 = Wgc1 + (size_t)ek * 32 * 96;
        const float* W2 = Wgc2 + (size_t)ek * 32 * 96;
        for (int idx = threadIdx.x; idx < 32 * 160; idx += 256) {
            int co = idx / 160, k = idx % 160;
            int slot = k >> 5, cp = k & 31;
            float val;
            if (slot == 0)
                val = W1[co * 96 + cp] + W1[co * 96 + 32 + cp] + W1[co * 96 + 64 + cp] +
                      W2[co * 96 + cp] + W2[co * 96 + 32 + cp] + W2[co * 96 + 64 + cp];
            else if (slot == 1) val = 0.5f * W1[co * 96 + 32 + cp] + W1[co * 96 + 64 + cp];
            else if (slot == 2) val = 0.25f * W1[co * 96 + 64 + cp];
            else if (slot == 3) val = 0.5f * W2[co * 96 + 32 + cp] + W2[co * 96 + 64 + cp];
            else val = 0.25f * W2[co * 96 + 64 + cp];
            Amix[((size_t)e * 32 + co) * 160 + k] = f2bf(val);
        }
        if (threadIdx.x < 32)
            bsum[e * 32 + threadIdx.x] =
                bgc1[ek * 32 + threadIdx.x] + bgc2[ek * 32 + threadIdx.x];
    } else {
        int e = bx - 114;
        int ek = e * NBK + kb;
        ushort_t* Wh = Whd + (size_t)e * 6144;
        for (int i = threadIdx.x; i < 2048; i += 256)
            Wh[i] = f2bf(Wb1[(size_t)ek * 2048 + i]);
        for (int i = threadIdx.x; i < 1024; i += 256) {
            int r = i >> 6, d = i & 63;
            Wh[2048 + i] = f2bf(r < 12 ? Wb2[(size_t)ek * 768 + r * 64 + d] : 0.f);
        }
        for (int i = threadIdx.x; i < 2048; i += 256)
            Wh[3072 + i] = f2bf(Wfc1[(size_t)ek * 2048 + i]);
        for (int i = threadIdx.x; i < 1024; i += 256) {
            int r = i >> 6, d = i & 63;
            Wh[5120 + i] = f2bf(r < 12 ? Wfc2[(size_t)ek * 768 + r * 64 + d] : 0.f);
        }
        if (threadIdx.x < 64) {
            int d = threadIdx.x;
            float s1 = 0.f, s2 = 0.f;
            for (int c = 0; c < 32; ++c) {
                s1 += Wb1[(size_t)ek * 2048 + d * 32 + c];
                s2 += Wfc1[(size_t)ek * 2048 + d * 32 + c];
            }
            rS[e * 128 + d] = s1;
            rS[e * 128 + 64 + d] = s2;
        }
    }
}

// ---------------------------------------------------------------------------
// start: writes x fp32 [eb][t][c][n] and bf16 mirror xb [eb][t][n][c]
__global__ __launch_bounds__(256) void k_start(const float* __restrict__ bkc,
                                               float* __restrict__ x,
                                               ushort_t* __restrict__ xb,
                                               const float* __restrict__ Wst,
                                               const float* __restrict__ bst,
                                               int kb) {
    int n = blockIdx.x * 256 + threadIdx.x;
    int t = blockIdx.y;
    int eb = blockIdx.z;
    int e = eb >> 3;
    int ek = e * NBK + kb;
    const float* Wp = Wst + (size_t)ek * 32 * 2;
    const float* bp = bst + (size_t)ek * 32;
    float in0 = 0.f, in1 = 0.f;
    if (t >= 14) {
        const float* p = bkc + ((size_t)(eb * 12 + (t - 14)) * 512 + n) * 2;
        in0 = p[0];
        in1 = p[1];
    }
    float* xo = x + ((size_t)(eb * 26 + t) * 32) * 512 + n;
    ushort_t tmp[32];
#pragma unroll
    for (int c = 0; c < 32; ++c) {
        float v = bp[c] + Wp[c * 2] * in0 + Wp[c * 2 + 1] * in1;
        xo[(size_t)c * 512] = v;
        tmp[c] = f2bf(v);
    }
    ushort_t* xbp = xb + ((size_t)(eb * 26 + t) * 512 + n) * 32;
#pragma unroll
    for (int q = 0; q < 4; ++q)
        *(bf16x8*)(xbp + q * 8) = *(bf16x8*)(tmp + q * 8);
}

// ---------------------------------------------------------------------------
// MFMA inception: writes h_old [col][n] (GEMM A operand) + buf5 slot0 (Y)
__global__ __launch_bounds__(256) void k_incept_mfma(
    const ushort_t* __restrict__ xb, ushort_t* __restrict__ h,
    ushort_t* __restrict__ buf5, const ushort_t* __restrict__ Wb,
    const float* __restrict__ bf, const float* __restrict__ bg,
    int kb, int cur_len, int L) {
    int j = blockIdx.y, eb = blockIdx.z, e = eb >> 3, ek = e * NBK + kb;
    int tid = threadIdx.x;
    int w = tid >> 6, lane = tid & 63;
    int l15 = lane & 15, lg = lane >> 4;
    int ot = w >> 1;
    int n0base = blockIdx.x * 128 + (w & 1) * 64;
    int t0 = 26 - cur_len + j;

    const ushort_t* WbE = Wb + (size_t)e * 14336;
    bf16x8 af_[7], ag_[7];
#pragma unroll
    for (int dt = 0; dt < 7; ++dt) {
        af_[dt] = *(const bf16x8*)(WbE + ((size_t)(dt * 2 + ot) * 16 + l15) * 32 + lg * 8);
        ag_[dt] = *(const bf16x8*)(WbE + 7168 + ((size_t)(dt * 2 + ot) * 16 + l15) * 32 + lg * 8);
    }
    float bfv[4], bgv[4];
#pragma unroll
    for (int r = 0; r < 4; ++r) {
        int o = ot * 16 + 4 * lg + r;
        bfv[r] = bf[ek * 32 + o];
        bgv[r] = bg[ek * 32 + o];
    }
    size_t colbase = ((size_t)eb * L + j) * 32;
    size_t rowb = ((size_t)eb * L + j) * 512;
    const ushort_t* xe = xb + ((size_t)eb * 26) * 512 * 32;
#pragma unroll
    for (int nt = 0; nt < 4; ++nt) {
        int n0 = n0base + nt * 16;
        // batch all 7 window loads up-front (ILP), then run the MFMA chain
        bf16x8 bfr[7];
#pragma unroll
        for (int dt = 0; dt < 7; ++dt)
            bfr[dt] = *(const bf16x8*)(xe + ((size_t)(t0 + dt) * 512 + n0 + l15) * 32 + lg * 8);
        f32x4 accf = {}, accg = {};
#pragma unroll
        for (int dt = 0; dt < 7; ++dt) {
            accf = __builtin_amdgcn_mfma_f32_16x16x32_bf16(af_[dt], bfr[dt], accf, 0, 0, 0);
            accg = __builtin_amdgcn_mfma_f32_16x16x32_bf16(ag_[dt], bfr[dt], accg, 0, 0, 0);
        }
        u16x4 q;
#pragma unroll
        for (int r = 0; r < 4; ++r) {
            float a = accf[r] + bfv[r];
            float b = accg[r] + bgv[r];
            float hv = tanhf(a) * (1.f / (1.f + expf(-b)));
            ushort_t hb = f2bf(hv);
            q[r] = hb;
            int o = ot * 16 + 4 * lg + r;
            h[(colbase + o) * 512 + n0 + l15] = hb;
        }
        *(u16x4*)(buf5 + (rowb + n0 + l15) * 160 + ot * 16 + 4 * lg) = q;
    }
}

// ---------------------------------------------------------------------------
// 4-way NT GEMM from h with double-buffered fragment prefetch.
// slot z+1 of buf5 = h @ Bz^T; z: 0->An, 1->An2, 2->AnT, 3->An2T
__global__ __launch_bounds__(256) void k_gemm4(
    const ushort_t* __restrict__ A,
    const ushort_t* __restrict__ B0, const ushort_t* __restrict__ B1,
    const ushort_t* __restrict__ B2, const ushort_t* __restrict__ B3,
    ushort_t* __restrict__ buf5) {
    int z = blockIdx.z;
    const ushort_t* B = (z == 0) ? B0 : (z == 1) ? B1 : (z == 2) ? B2 : B3;
    int slot = z + 1;
    int tid = threadIdx.x;
    int w = tid >> 6, lane = tid & 63;
    int l15 = lane & 15, lg = lane >> 4;
    int wbase = blockIdx.x * 256 + w * 64;
    int n0 = blockIdx.y * 64;
    f32x4 acc[4][4] = {};
    const ushort_t* Ap = A + (size_t)(wbase + l15) * 512 + lg * 8;
    const ushort_t* Bp = B + (size_t)(n0 + l15) * 512 + lg * 8;
    bf16x8 avC[4], bvC[4], avN[4], bvN[4];
#pragma unroll
    for (int i = 0; i < 4; ++i) {
        avC[i] = *(const bf16x8*)(Ap + (size_t)i * 16 * 512);
        bvC[i] = *(const bf16x8*)(Bp + (size_t)i * 16 * 512);
    }
#pragma unroll 2
    for (int k0 = 0; k0 < 512; k0 += 32) {
        int kn = k0 + 32;
        if (kn < 512) {
#pragma unroll
            for (int i = 0; i < 4; ++i) {
                avN[i] = *(const bf16x8*)(Ap + (size_t)i * 16 * 512 + kn);
                bvN[i] = *(const bf16x8*)(Bp + (size_t)i * 16 * 512 + kn);
            }
        }
#pragma unroll
        for (int mf = 0; mf < 4; ++mf)
#pragma unroll
            for (int nf = 0; nf < 4; ++nf)
                acc[mf][nf] = __builtin_amdgcn_mfma_f32_16x16x32_bf16(
                    avC[mf], bvC[nf], acc[mf][nf], 0, 0, 0);
#pragma unroll
        for (int i = 0; i < 4; ++i) { avC[i] = avN[i]; bvC[i] = bvN[i]; }
    }
#pragma unroll
    for (int mf = 0; mf < 4; ++mf) {
        int jeb = (wbase >> 5) + (mf >> 1);
        int c0 = 16 * (mf & 1) + 4 * lg;
#pragma unroll
        for (int nf = 0; nf < 4; ++nf) {
            int col = n0 + 16 * nf + l15;
            u16x4 q;
#pragma unroll
            for (int r = 0; r < 4; ++r) q[r] = f2bf(acc[mf][nf][r]);
            *(u16x4*)(buf5 + ((size_t)jeb * 512 + col) * 160 + slot * 32 + c0) = q;
        }
    }
}

// ---------------------------------------------------------------------------
// MFMA combine: g = Amix @ buf5^T + bsum; x -= 0.25*g; xb = bf16(x)
__global__ __launch_bounds__(256) void k_combine_mfma(
    float* __restrict__ x, ushort_t* __restrict__ xb,
    const ushort_t* __restrict__ buf5, const ushort_t* __restrict__ Amix,
    const float* __restrict__ bsum, int L) {
    int j = blockIdx.x, eb = blockIdx.y, e = eb >> 3;
    int tid = threadIdx.x, wv = tid >> 6, lane = tid & 63;
    int l15 = lane & 15, lg = lane >> 4;
    int t = 26 - L + j;
    const ushort_t* Ae = Amix + (size_t)e * 32 * 160;
    bf16x8 a[2][5];
#pragma unroll
    for (int ct = 0; ct < 2; ++ct)
#pragma unroll
        for (int ks = 0; ks < 5; ++ks)
            a[ct][ks] = *(const bf16x8*)(Ae + (size_t)(ct * 16 + l15) * 160 + ks * 32 + lg * 8);
    float bs[2][4];
#pragma unroll
    for (int ct = 0; ct < 2; ++ct)
#pragma unroll
        for (int r = 0; r < 4; ++r) bs[ct][r] = bsum[e * 32 + ct * 16 + 4 * lg + r];
    size_t rowb = ((size_t)eb * L + j) * 512;
    size_t xtb = ((size_t)(eb * 26 + t) * 32) * 512;
    ushort_t* xbt = xb + ((size_t)(eb * 26 + t) * 512) * 32;
#pragma unroll
    for (int nt = 0; nt < 8; ++nt) {
        int n = wv * 128 + nt * 16 + l15;
        const ushort_t* bp = buf5 + (rowb + n) * 160 + lg * 8;
        bf16x8 b[5];
#pragma unroll
        for (int ks = 0; ks < 5; ++ks) b[ks] = *(const bf16x8*)(bp + ks * 32);
        f32x4 acc[2] = {};
#pragma unroll
        for (int ks = 0; ks < 5; ++ks) {
            acc[0] = __builtin_amdgcn_mfma_f32_16x16x32_bf16(a[0][ks], b[ks], acc[0], 0, 0, 0);
            acc[1] = __builtin_amdgcn_mfma_f32_16x16x32_bf16(a[1][ks], b[ks], acc[1], 0, 0, 0);
        }
#pragma unroll
        for (int ct = 0; ct < 2; ++ct) {
            u16x4 q;
#pragma unroll
            for (int r = 0; r < 4; ++r) {
                int co = ct * 16 + 4 * lg + r;
                float* xp = x + xtb + (size_t)co * 512 + n;
                float nv = *xp - 0.25f * (acc[ct][r] + bs[ct][r]);
                *xp = nv;
                q[r] = f2bf(nv);
            }
            *(u16x4*)(xbt + (size_t)n * 32 + ct * 16 + 4 * lg) = q;
        }
    }
}

// ---------------------------------------------------------------------------
__global__ __launch_bounds__(256) void k_lnstats(const float* __restrict__ x,
                                                 float* __restrict__ stats) {
    int eb = blockIdx.x;
    const float* p = x + ((size_t)(eb * 26 + 24) * 32) * 512;
    float s = 0.f, s2 = 0.f;
    for (int i = threadIdx.x; i < 32768; i += 256) {
        float v = p[i];
        s += v;
        s2 += v * v;
    }
    for (int off = 32; off; off >>= 1) {
        s += __shfl_down(s, off);
        s2 += __shfl_down(s2, off);
    }
    __shared__ float r1[4], r2[4];
    if ((threadIdx.x & 63) == 0) {
        r1[threadIdx.x >> 6] = s;
        r2[threadIdx.x >> 6] = s2;
    }
    __syncthreads();
    if (threadIdx.x == 0) {
        float S = r1[0] + r1[1] + r1[2] + r1[3];
        float S2 = r2[0] + r2[1] + r2[2] + r2[3];
        float mu = S / 32768.f;
        float var = S2 / 32768.f - mu * mu;
        stats[eb * 2] = mu;
        stats[eb * 2 + 1] = rsqrtf(var + 1e-5f);
    }
}

// ---------------------------------------------------------------------------
__global__ __launch_bounds__(256) void k_heads_mfma(
    const ushort_t* __restrict__ xb, const float* __restrict__ stats,
    float* __restrict__ bkc, float* __restrict__ acc,
    const ushort_t* __restrict__ Whd, const float* __restrict__ rS,
    const float* __restrict__ bb1, const float* __restrict__ bb2,
    const float* __restrict__ bfc1, const float* __restrict__ bfc2,
    int kb) {
    __shared__ __align__(16) ushort_t lds[4][64][72];
    int w = blockIdx.y, eb = blockIdx.z;
    int e = eb >> 3, ek = e * NBK + kb;
    int tid = threadIdx.x, wv = tid >> 6, lane = tid & 63;
    int l15 = lane & 15, lg = lane >> 4;
    int n0 = blockIdx.x * 256 + wv * 64;
    float mu = stats[eb * 2], rsv = stats[eb * 2 + 1];
    const ushort_t* Wh = Whd + (size_t)e * 6144;
    const ushort_t* xrow = xb + ((size_t)(eb * 26 + 24 + w) * 512) * 32;

#pragma unroll
    for (int head = 0; head < 2; ++head) {
        if (head == 1 && w == 0) break;  // fc only for w==1
        int woff = head ? 3072 : 0;
        const float* b1 = head ? bfc1 : bb1;
        const float* b2 = head ? bfc2 : bb2;
        const float* rs1 = rS + e * 128 + (head ? 64 : 0);
        bf16x8 a1[4];
#pragma unroll
        for (int rt = 0; rt < 4; ++rt)
            a1[rt] = *(const bf16x8*)(Wh + woff + (size_t)(rt * 16 + l15) * 32 + lg * 8);
        float be[4][4];
#pragma unroll
        for (int rt = 0; rt < 4; ++rt)
#pragma unroll
            for (int r = 0; r < 4; ++r) {
                int d = rt * 16 + 4 * lg + r;
                be[rt][r] = b1[ek * 64 + d] - rsv * mu * rs1[d];
            }
#pragma unroll
        for (int nt = 0; nt < 4; ++nt) {
            bf16x8 bv = *(const bf16x8*)(xrow + (size_t)(n0 + nt * 16 + l15) * 32 + lg * 8);
            f32x4 ac[4] = {};
#pragma unroll
            for (int rt = 0; rt < 4; ++rt)
                ac[rt] = __builtin_amdgcn_mfma_f32_16x16x32_bf16(a1[rt], bv, ac[rt], 0, 0, 0);
#pragma unroll
            for (int rt = 0; rt < 4; ++rt)
#pragma unroll
                for (int r = 0; r < 4; ++r) {
                    float hv = fmaxf(rsv * ac[rt][r] + be[rt][r], 0.f);
                    lds[wv][nt * 16 + l15][rt * 16 + 4 * lg + r] = f2bf(hv);
                }
        }
        bf16x8 a2[2];
        a2[0] = *(const bf16x8*)(Wh + woff + 2048 + (size_t)l15 * 64 + lg * 8);
        a2[1] = *(const bf16x8*)(Wh + woff + 2048 + (size_t)l15 * 64 + 32 + lg * 8);
        float b2v[4];
#pragma unroll
        for (int r = 0; r < 4; ++r) {
            int s = 4 * lg + r;
            b2v[r] = (s < 12) ? b2[ek * 12 + s] : 0.f;
        }
#pragma unroll
        for (int nt = 0; nt < 4; ++nt) {
            bf16x8 b0 = *(const bf16x8*)&lds[wv][nt * 16 + l15][lg * 8];
            bf16x8 b1f = *(const bf16x8*)&lds[wv][nt * 16 + l15][32 + lg * 8];
            f32x4 ac2 = {};
            ac2 = __builtin_amdgcn_mfma_f32_16x16x32_bf16(a2[0], b0, ac2, 0, 0, 0);
            ac2 = __builtin_amdgcn_mfma_f32_16x16x32_bf16(a2[1], b1f, ac2, 0, 0, 0);
#pragma unroll
            for (int r = 0; r < 4; ++r) {
                int s = 4 * lg + r;
                if (s < 12) {
                    int n = n0 + nt * 16 + l15;
                    float val = ac2[r] + b2v[r];
                    if (head == 0)
                        bkc[((size_t)(eb * 12 + s) * 512 + n) * 2 + w] -= val;
                    else
                        acc[(size_t)(eb * 12 + s) * 512 + n] += val;
                }
            }
        }
    }
}

// ---------------------------------------------------------------------------
__global__ __launch_bounds__(256) void k_final(const float* __restrict__ acc,
                                               const float* __restrict__ ew,
                                               float* __restrict__ out) {
    int i = blockIdx.x * 256 + threadIdx.x;  // 49152
    out[i] = ew[0] * acc[i] + ew[1] * acc[49152 + i];
}

// ---------------------------------------------------------------------------
extern "C" void kernel_launch(void* const* d_in, const int* in_sizes, int n_in,
                              void* d_out, int out_size, void* d_ws, size_t ws_size,
                              hipStream_t stream) {
    const float* X    = (const float*)d_in[0];
    const float* adj  = (const float*)d_in[1];
    const float* ew   = (const float*)d_in[2];
    const float* Wst  = (const float*)d_in[3];
    const float* bst  = (const float*)d_in[4];
    const float* Wf2  = (const float*)d_in[5];
    const float* Wf3  = (const float*)d_in[6];
    const float* Wf5  = (const float*)d_in[7];
    const float* Wf7  = (const float*)d_in[8];
    const float* bf   = (const float*)d_in[9];
    const float* Wg2  = (const float*)d_in[10];
    const float* Wg3  = (const float*)d_in[11];
    const float* Wg5  = (const float*)d_in[12];
    const float* Wg7  = (const float*)d_in[13];
    const float* bg   = (const float*)d_in[14];
    const float* Wgc1 = (const float*)d_in[15];
    const float* bgc1 = (const float*)d_in[16];
    const float* Wgc2 = (const float*)d_in[17];
    const float* bgc2 = (const float*)d_in[18];
    const float* Wb1  = (const float*)d_in[19];
    const float* bb1  = (const float*)d_in[20];
    const float* Wb2  = (const float*)d_in[21];
    const float* bb2  = (const float*)d_in[22];
    const float* Wfc1 = (const float*)d_in[23];
    const float* bfc1 = (const float*)d_in[24];
    const float* Wfc2 = (const float*)d_in[25];
    const float* bfc2 = (const float*)d_in[26];

    float* ws = (float*)d_ws;
    size_t off = 0;
    auto alloc = [&](size_t nf) { float* p = ws + off; off += nf; return p; };
    float* di    = alloc(512);
    ushort_t* Anb   = (ushort_t*)alloc(512 * 512 / 2);
    ushort_t* AnTb  = (ushort_t*)alloc(512 * 512 / 2);
    ushort_t* An2b  = (ushort_t*)alloc(512 * 512 / 2);
    ushort_t* An2Tb = (ushort_t*)alloc(512 * 512 / 2);
    float* bkc   = alloc((size_t)EE * BATCH * 12 * 512 * 2);
    float* acc   = alloc((size_t)EE * BATCH * 12 * 512);
    float* stats = alloc(32);
    ushort_t* Amix = (ushort_t*)alloc(2 * 32 * 160 / 2);
    float* bsum  = alloc(64);
    ushort_t* Wb = (ushort_t*)alloc(14336);
    ushort_t* Whd = (ushort_t*)alloc(6144);
    float* rSb   = alloc(256);
    float* x     = alloc((size_t)16 * 26 * 32 * 512);
    ushort_t* xb = (ushort_t*)alloc((size_t)16 * 26 * 512 * 32 / 2);
    size_t hbuf_f = (size_t)16 * 20 * 32 * 512 / 2;  // bf16 old-layout, float units
    ushort_t* h   = (ushort_t*)alloc(hbuf_f);
    ushort_t* buf5 = (ushort_t*)alloc((size_t)16 * 20 * 512 * 160 / 2);
    if (off * sizeof(float) > ws_size) return;  // workspace too small: bail

    // Graph normalization + An^2 precompute
    k_rowsum<<<512, 256, 0, stream>>>(adj, di);
    k_norm<<<1024, 256, 0, stream>>>(adj, di, Anb, AnTb);
    k_An2<<<dim3(2, 8), 256, 0, stream>>>(Anb, AnTb, An2b, An2Tb);

    // Residual init (both experts start from X) + output accumulator zero
    hipMemcpyAsync(bkc, X, (size_t)98304 * 4, hipMemcpyDeviceToDevice, stream);
    hipMemcpyAsync(bkc + 98304, X, (size_t)98304 * 4, hipMemcpyDeviceToDevice, stream);
    hipMemsetAsync(acc, 0, (size_t)EE * BATCH * 12 * 512 * 4, stream);

    for (int kb = 0; kb < NBK; ++kb) {
        k_prep<<<116, 256, 0, stream>>>(Wf2, Wf3, Wf5, Wf7, Wg2, Wg3, Wg5, Wg7, Wb,
                                        Wgc1, bgc1, Wgc2, bgc2, Amix, bsum,
                                        Wb1, Wb2, Wfc1, Wfc2, Whd, rSb, kb);
        k_start<<<dim3(2, 26, 16), 256, 0, stream>>>(bkc, x, xb, Wst, bst, kb);
        int cur = 26;
        for (int it = 0; it < 4; ++it) {
            int L = cur - 6;
            k_incept_mfma<<<dim3(4, L, 16), 256, 0, stream>>>(
                xb, h, buf5, Wb, bf, bg, kb, cur, L);
            k_gemm4<<<dim3(2 * L, 8, 4), 256, 0, stream>>>(
                h, Anb, An2b, AnTb, An2Tb, buf5);
            k_combine_mfma<<<dim3(L, 16), 256, 0, stream>>>(x, xb, buf5, Amix, bsum, L);
            cur -= 6;
        }
        k_lnstats<<<16, 256, 0, stream>>>(x, stats);
        k_heads_mfma<<<dim3(2, 2, 16), 256, 0, stream>>>(xb, stats, bkc, acc, Whd, rSb,
                                                         bb1, bb2, bfc1, bfc2, kb);
    }
    k_final<<<192, 256, 0, stream>>>(acc, ew, (float*)d_out);
}

// Round 12
// 759.322 us; speedup vs baseline: 4.4732x; 1.1819x over previous
//
#include <hip/hip_runtime.h>
#include <stddef.h>

// Problem constants (E=2 experts, NB=2 blocks, B=8 batch, N=512 nodes)
#define EE 2
#define NBK 2
#define BATCH 8

typedef unsigned short ushort_t;
typedef short bf16x8 __attribute__((ext_vector_type(8)));
typedef float f32x4 __attribute__((ext_vector_type(4)));
typedef unsigned short u16x4 __attribute__((ext_vector_type(4)));

__device__ __forceinline__ ushort_t f2bf(float f) {
    unsigned int u = __float_as_uint(f);
    u += 0x7FFF + ((u >> 16) & 1);
    return (ushort_t)(u >> 16);
}
__device__ __forceinline__ float bf2f(ushort_t h) {
    return __uint_as_float(((unsigned int)h) << 16);
}

// ---------------------------------------------------------------------------
__global__ __launch_bounds__(256) void k_rowsum(const float* __restrict__ adj,
                                                float* __restrict__ di) {
    int v = blockIdx.x;
    int tid = threadIdx.x;
    float s = 0.f;
    for (int w = tid; w < 512; w += 256)
        s += adj[v * 512 + w] + (w == v ? 1.f : 0.f);
    for (int off = 32; off; off >>= 1) s += __shfl_down(s, off);
    __shared__ float red[4];
    if ((tid & 63) == 0) red[tid >> 6] = s;
    __syncthreads();
    if (tid == 0) {
        float t = red[0] + red[1] + red[2] + red[3];
        di[v] = rsqrtf(t);
    }
}

__global__ __launch_bounds__(256) void k_norm(const float* __restrict__ adj,
                                              const float* __restrict__ di,
                                              ushort_t* __restrict__ An,
                                              ushort_t* __restrict__ AnT) {
    int idx = blockIdx.x * 256 + threadIdx.x;  // 0..262143
    int v = idx >> 9, w = idx & 511;
    float a = adj[idx] + (v == w ? 1.f : 0.f);
    ushort_t val = f2bf(di[v] * a * di[w]);
    An[idx] = val;
    AnT[w * 512 + v] = val;
}

// ---------------------------------------------------------------------------
// An2 = An·An (row-major); An2T = (An2)^T.
__global__ __launch_bounds__(256) void k_An2(
    const ushort_t* __restrict__ Anb, const ushort_t* __restrict__ AnTb,
    ushort_t* __restrict__ An2, ushort_t* __restrict__ An2T) {
    int tid = threadIdx.x;
    int w = tid >> 6, lane = tid & 63;
    int l15 = lane & 15, lg = lane >> 4;
    int wbase = blockIdx.x * 256 + w * 64;
    int n0 = blockIdx.y * 64;
    f32x4 acc[4][4] = {};
    const ushort_t* Ap = Anb + (size_t)(wbase + l15) * 512 + lg * 8;
    const ushort_t* Bp = AnTb + (size_t)(n0 + l15) * 512 + lg * 8;
    bf16x8 avC[4], bvC[4], avN[4], bvN[4];
#pragma unroll
    for (int i = 0; i < 4; ++i) {
        avC[i] = *(const bf16x8*)(Ap + (size_t)i * 16 * 512);
        bvC[i] = *(const bf16x8*)(Bp + (size_t)i * 16 * 512);
    }
#pragma unroll 2
    for (int k0 = 0; k0 < 512; k0 += 32) {
        int kn = k0 + 32;
        if (kn < 512) {
#pragma unroll
            for (int i = 0; i < 4; ++i) {
                avN[i] = *(const bf16x8*)(Ap + (size_t)i * 16 * 512 + kn);
                bvN[i] = *(const bf16x8*)(Bp + (size_t)i * 16 * 512 + kn);
            }
        }
#pragma unroll
        for (int mf = 0; mf < 4; ++mf)
#pragma unroll
            for (int nf = 0; nf < 4; ++nf)
                acc[mf][nf] = __builtin_amdgcn_mfma_f32_16x16x32_bf16(
                    avC[mf], bvC[nf], acc[mf][nf], 0, 0, 0);
#pragma unroll
        for (int i = 0; i < 4; ++i) { avC[i] = avN[i]; bvC[i] = bvN[i]; }
    }
#pragma unroll
    for (int mf = 0; mf < 4; ++mf)
#pragma unroll
        for (int nf = 0; nf < 4; ++nf) {
            int col = n0 + 16 * nf + l15;
            int row0 = wbase + 16 * mf + 4 * lg;
            u16x4 q;
#pragma unroll
            for (int r = 0; r < 4; ++r) {
                ushort_t vb = f2bf(acc[mf][nf][r]);
                q[r] = vb;
                An2[(size_t)(row0 + r) * 512 + col] = vb;
            }
            *(u16x4*)(An2T + (size_t)col * 512 + row0) = q;
        }
}

// ---------------------------------------------------------------------------
// Fused per-kb weight prep: blocks 0..111 -> inception Weff; 112,113 ->
// mix matrices (e = bx-112); 114,115 -> head weights (e = bx-114).
__global__ __launch_bounds__(256) void k_prep(
    const float* __restrict__ Wf2, const float* __restrict__ Wf3,
    const float* __restrict__ Wf5, const float* __restrict__ Wf7,
    const float* __restrict__ Wg2, const float* __restrict__ Wg3,
    const float* __restrict__ Wg5, const float* __restrict__ Wg7,
    ushort_t* __restrict__ Wb,
    const float* __restrict__ Wgc1, const float* __restrict__ bgc1,
    const float* __restrict__ Wgc2, const float* __restrict__ bgc2,
    ushort_t* __restrict__ Amix, float* __restrict__ bsum,
    const float* __restrict__ Wb1, const float* __restrict__ Wb2,
    const float* __restrict__ Wfc1, const float* __restrict__ Wfc2,
    ushort_t* __restrict__ Whd, float* __restrict__ rS, int kb) {
    int bx = blockIdx.x;
    if (bx < 112) {
        int idx = bx * 256 + threadIdx.x;  // 28672 total
        if (idx >= 2 * 2 * 7 * 2 * 16 * 32) return;
        int c = idx & 31;
        int t1 = idx >> 5;
        int o16 = t1 & 15;
        int t2 = t1 >> 4;
        int ot = t2 & 1;
        int t3 = t2 >> 1;
        int dt = t3 % 7;
        int t4 = t3 / 7;
        int fg = t4 & 1;
        int e = t4 >> 1;
        int ek = e * NBK + kb;
        int o = ot * 16 + o16;
        int grp = o >> 3, oo = o & 7;
        const int kstab[4] = {2, 3, 5, 7};
        int ks = kstab[grp];
        int lo = 7 - ks;
        float val = 0.f;
        if (dt >= lo) {
            int di = dt - lo;
            const float* W;
            if (grp == 0) W = (fg ? Wg2 : Wf2) + (size_t)ek * 512 + oo * 64 + c * 2 + di;
            else if (grp == 1) W = (fg ? Wg3 : Wf3) + (size_t)ek * 768 + oo * 96 + c * 3 + di;
            else if (grp == 2) W = (fg ? Wg5 : Wf5) + (size_t)ek * 1280 + oo * 160 + c * 5 + di;
            else W = (fg ? Wg7 : Wf7) + (size_t)ek * 1792 + oo * 224 + c * 7 + di;
            val = *W;
        }
        Wb[idx] = f2bf(val);
    } else if (bx < 114) {
        int e = bx - 112;
        int ek = e * NBK + kb;
        const float* W1 = Wgc1 + (size_t)ek * 32 * 96;
        const float* W2 = Wgc2 + (size_t)ek * 32 * 96;
        for (int idx = threadIdx.x; idx < 32 * 160; idx += 256) {
            int co = idx / 160, k = idx % 160;
            int slot = k >> 5, cp = k & 31;
            float val;
            if (slot == 0)
                val = W1[co * 96 + cp] + W1[co * 96 + 32 + cp] + W1[co * 96 + 64 + cp] +
                      W2[co * 96 + cp] + W2[co * 96 + 32 + cp] + W2[co * 96 + 64 + cp];
            else if (slot == 1) val = 0.5f * W1[co * 96 + 32 + cp] + W1[co * 96 + 64 + cp];
            else if (slot == 2) val = 0.25f * W1[co * 96 + 64 + cp];
            else if (slot == 3) val = 0.5f * W2[co * 96 + 32 + cp] + W2[co * 96 + 64 + cp];
            else val = 0.25f * W2[co * 96 + 64 + cp];
            Amix[((size_t)e * 32 + co) * 160 + k] = f2bf(val);
        }
        if (threadIdx.x < 32)
            bsum[e * 32 + threadIdx.x] =
                bgc1[ek * 32 + threadIdx.x] + bgc2[ek * 32 + threadIdx.x];
    } else {
        int e = bx - 114;
        int ek = e * NBK + kb;
        ushort_t* Wh = Whd + (size_t)e * 6144;
        for (int i = threadIdx.x; i < 2048; i += 256)
            Wh[i] = f2bf(Wb1[(size_t)ek * 2048 + i]);
        for (int i = threadIdx.x; i < 1024; i += 256) {
            int r = i >> 6, d = i & 63;
            Wh[2048 + i] = f2bf(r < 12 ? Wb2[(size_t)ek * 768 + r * 64 + d] : 0.f);
        }
        for (int i = threadIdx.x; i < 2048; i += 256)
            Wh[3072 + i] = f2bf(Wfc1[(size_t)ek * 2048 + i]);
        for (int i = threadIdx.x; i < 1024; i += 256) {
            int r = i >> 6, d = i & 63;
            Wh[5120 + i] = f2bf(r < 12 ? Wfc2[(size_t)ek * 768 + r * 64 + d] : 0.f);
        }
        if (threadIdx.x < 64) {
            int d = threadIdx.x;
            float s1 = 0.f, s2 = 0.f;
            for (int c = 0; c < 32; ++c) {
                s1 += Wb1[(size_t)ek * 2048 + d * 32 + c];
                s2 += Wfc1[(size_t)ek * 2048 + d * 32 + c];
            }
            rS[e * 128 + d] = s1;
            rS[e * 128 + 64 + d] = s2;
        }
    }
}

// ---------------------------------------------------------------------------
// start: writes x fp32 [eb][t][c][n] and bf16 mirror xb [eb][t][n][c]
__global__ __launch_bounds__(256) void k_start(const float* __restrict__ bkc,
                                               float* __restrict__ x,
                                               ushort_t* __restrict__ xb,
                                               const float* __restrict__ Wst,
                                               const float* __restrict__ bst,
                                               int kb) {
    int n = blockIdx.x * 256 + threadIdx.x;
    int t = blockIdx.y;
    int eb = blockIdx.z;
    int e = eb >> 3;
    int ek = e * NBK + kb;
    const float* Wp = Wst + (size_t)ek * 32 * 2;
    const float* bp = bst + (size_t)ek * 32;
    float in0 = 0.f, in1 = 0.f;
    if (t >= 14) {
        const float* p = bkc + ((size_t)(eb * 12 + (t - 14)) * 512 + n) * 2;
        in0 = p[0];
        in1 = p[1];
    }
    float* xo = x + ((size_t)(eb * 26 + t) * 32) * 512 + n;
    ushort_t tmp[32];
#pragma unroll
    for (int c = 0; c < 32; ++c) {
        float v = bp[c] + Wp[c * 2] * in0 + Wp[c * 2 + 1] * in1;
        xo[(size_t)c * 512] = v;
        tmp[c] = f2bf(v);
    }
    ushort_t* xbp = xb + ((size_t)(eb * 26 + t) * 512 + n) * 32;
#pragma unroll
    for (int q = 0; q < 4; ++q)
        *(bf16x8*)(xbp + q * 8) = *(bf16x8*)(tmp + q * 8);
}

// ---------------------------------------------------------------------------
// MFMA inception: writes h_old [col][n] (GEMM A operand) + buf5 slot0 (Y)
__global__ __launch_bounds__(256) void k_incept_mfma(
    const ushort_t* __restrict__ xb, ushort_t* __restrict__ h,
    ushort_t* __restrict__ buf5, const ushort_t* __restrict__ Wb,
    const float* __restrict__ bf, const float* __restrict__ bg,
    int kb, int cur_len, int L) {
    int j = blockIdx.y, eb = blockIdx.z, e = eb >> 3, ek = e * NBK + kb;
    int tid = threadIdx.x;
    int w = tid >> 6, lane = tid & 63;
    int l15 = lane & 15, lg = lane >> 4;
    int ot = w >> 1;
    int n0base = blockIdx.x * 128 + (w & 1) * 64;
    int t0 = 26 - cur_len + j;

    const ushort_t* WbE = Wb + (size_t)e * 14336;
    bf16x8 af_[7], ag_[7];
#pragma unroll
    for (int dt = 0; dt < 7; ++dt) {
        af_[dt] = *(const bf16x8*)(WbE + ((size_t)(dt * 2 + ot) * 16 + l15) * 32 + lg * 8);
        ag_[dt] = *(const bf16x8*)(WbE + 7168 + ((size_t)(dt * 2 + ot) * 16 + l15) * 32 + lg * 8);
    }
    float bfv[4], bgv[4];
#pragma unroll
    for (int r = 0; r < 4; ++r) {
        int o = ot * 16 + 4 * lg + r;
        bfv[r] = bf[ek * 32 + o];
        bgv[r] = bg[ek * 32 + o];
    }
    size_t colbase = ((size_t)eb * L + j) * 32;
    size_t rowb = ((size_t)eb * L + j) * 512;
    const ushort_t* xe = xb + ((size_t)eb * 26) * 512 * 32;
#pragma unroll
    for (int nt = 0; nt < 4; ++nt) {
        int n0 = n0base + nt * 16;
        // batch all 7 window loads up-front (ILP), then run the MFMA chain
        bf16x8 bfr[7];
#pragma unroll
        for (int dt = 0; dt < 7; ++dt)
            bfr[dt] = *(const bf16x8*)(xe + ((size_t)(t0 + dt) * 512 + n0 + l15) * 32 + lg * 8);
        f32x4 accf = {}, accg = {};
#pragma unroll
        for (int dt = 0; dt < 7; ++dt) {
            accf = __builtin_amdgcn_mfma_f32_16x16x32_bf16(af_[dt], bfr[dt], accf, 0, 0, 0);
            accg = __builtin_amdgcn_mfma_f32_16x16x32_bf16(ag_[dt], bfr[dt], accg, 0, 0, 0);
        }
        u16x4 q;
#pragma unroll
        for (int r = 0; r < 4; ++r) {
            float a = accf[r] + bfv[r];
            float b = accg[r] + bgv[r];
            float hv = tanhf(a) * (1.f / (1.f + expf(-b)));
            ushort_t hb = f2bf(hv);
            q[r] = hb;
            int o = ot * 16 + 4 * lg + r;
            h[(colbase + o) * 512 + n0 + l15] = hb;
        }
        *(u16x4*)(buf5 + (rowb + n0 + l15) * 160 + ot * 16 + 4 * lg) = q;
    }
}

// ---------------------------------------------------------------------------
// 4-way NT GEMM from h with LDS-staged B tile (double-buffered, padded).
// slot z+1 of buf5 = h @ Bz^T; z: 0->An, 1->An2, 2->AnT, 3->An2T
// Block = 4 waves x 64 rows = 256 rows, 64 cols. B chunk (64 cols x 32 K)
// staged cooperatively: thread t loads 16B (col=t>>2, kq=(t&3)*8), writes
// LDS [2][64][36] (pad 32->36 => ~2-way max read conflicts).
__global__ __launch_bounds__(256) void k_gemm4(
    const ushort_t* __restrict__ A,
    const ushort_t* __restrict__ B0, const ushort_t* __restrict__ B1,
    const ushort_t* __restrict__ B2, const ushort_t* __restrict__ B3,
    ushort_t* __restrict__ buf5) {
    __shared__ __align__(16) ushort_t Bs[2][64][36];
    int z = blockIdx.z;
    const ushort_t* B = (z == 0) ? B0 : (z == 1) ? B1 : (z == 2) ? B2 : B3;
    int slot = z + 1;
    int tid = threadIdx.x;
    int w = tid >> 6, lane = tid & 63;
    int l15 = lane & 15, lg = lane >> 4;
    int wbase = blockIdx.x * 256 + w * 64;
    int n0 = blockIdx.y * 64;
    int scol = tid >> 2;          // 0..63
    int skq = (tid & 3) * 8;      // 0,8,16,24
    const ushort_t* Bsrc = B + (size_t)(n0 + scol) * 512 + skq;
    const ushort_t* Ap = A + (size_t)(wbase + l15) * 512 + lg * 8;
    f32x4 acc[4][4] = {};
    bf16x8 bregN;
    {
        bf16x8 b0r = *(const bf16x8*)(Bsrc);
        bregN = *(const bf16x8*)(Bsrc + 32);
        *(bf16x8*)&Bs[0][scol][skq] = b0r;
    }
    __syncthreads();
#pragma unroll 2
    for (int ks = 0; ks < 16; ++ks) {
        int cur = ks & 1;
        int k0 = ks * 32;
        bf16x8 av[4], bv[4];
#pragma unroll
        for (int mf = 0; mf < 4; ++mf)
            av[mf] = *(const bf16x8*)(Ap + (size_t)mf * 16 * 512 + k0);
#pragma unroll
        for (int nf = 0; nf < 4; ++nf)
            bv[nf] = *(const bf16x8*)&Bs[cur][16 * nf + l15][lg * 8];
        if (ks < 15) *(bf16x8*)&Bs[cur ^ 1][scol][skq] = bregN;   // chunk ks+1
        if (ks < 14) bregN = *(const bf16x8*)(Bsrc + (ks + 2) * 32);  // chunk ks+2
#pragma unroll
        for (int mf = 0; mf < 4; ++mf)
#pragma unroll
            for (int nf = 0; nf < 4; ++nf)
                acc[mf][nf] = __builtin_amdgcn_mfma_f32_16x16x32_bf16(
                    av[mf], bv[nf], acc[mf][nf], 0, 0, 0);
        __syncthreads();
    }
#pragma unroll
    for (int mf = 0; mf < 4; ++mf) {
        int jeb = (wbase >> 5) + (mf >> 1);
        int c0 = 16 * (mf & 1) + 4 * lg;
#pragma unroll
        for (int nf = 0; nf < 4; ++nf) {
            int col = n0 + 16 * nf + l15;
            u16x4 q;
#pragma unroll
            for (int r = 0; r < 4; ++r) q[r] = f2bf(acc[mf][nf][r]);
            *(u16x4*)(buf5 + ((size_t)jeb * 512 + col) * 160 + slot * 32 + c0) = q;
        }
    }
}

// ---------------------------------------------------------------------------
// MFMA combine: g = Amix @ buf5^T + bsum; x -= 0.25*g; xb = bf16(x)
__global__ __launch_bounds__(256) void k_combine_mfma(
    float* __restrict__ x, ushort_t* __restrict__ xb,
    const ushort_t* __restrict__ buf5, const ushort_t* __restrict__ Amix,
    const float* __restrict__ bsum, int L) {
    int j = blockIdx.x, eb = blockIdx.y, e = eb >> 3;
    int tid = threadIdx.x, wv = tid >> 6, lane = tid & 63;
    int l15 = lane & 15, lg = lane >> 4;
    int t = 26 - L + j;
    const ushort_t* Ae = Amix + (size_t)e * 32 * 160;
    bf16x8 a[2][5];
#pragma unroll
    for (int ct = 0; ct < 2; ++ct)
#pragma unroll
        for (int ks = 0; ks < 5; ++ks)
            a[ct][ks] = *(const bf16x8*)(Ae + (size_t)(ct * 16 + l15) * 160 + ks * 32 + lg * 8);
    float bs[2][4];
#pragma unroll
    for (int ct = 0; ct < 2; ++ct)
#pragma unroll
        for (int r = 0; r < 4; ++r) bs[ct][r] = bsum[e * 32 + ct * 16 + 4 * lg + r];
    size_t rowb = ((size_t)eb * L + j) * 512;
    size_t xtb = ((size_t)(eb * 26 + t) * 32) * 512;
    ushort_t* xbt = xb + ((size_t)(eb * 26 + t) * 512) * 32;
#pragma unroll
    for (int nt = 0; nt < 8; ++nt) {
        int n = wv * 128 + nt * 16 + l15;
        const ushort_t* bp = buf5 + (rowb + n) * 160 + lg * 8;
        bf16x8 b[5];
#pragma unroll
        for (int ks = 0; ks < 5; ++ks) b[ks] = *(const bf16x8*)(bp + ks * 32);
        f32x4 acc[2] = {};
#pragma unroll
        for (int ks = 0; ks < 5; ++ks) {
            acc[0] = __builtin_amdgcn_mfma_f32_16x16x32_bf16(a[0][ks], b[ks], acc[0], 0, 0, 0);
            acc[1] = __builtin_amdgcn_mfma_f32_16x16x32_bf16(a[1][ks], b[ks], acc[1], 0, 0, 0);
        }
#pragma unroll
        for (int ct = 0; ct < 2; ++ct) {
            u16x4 q;
#pragma unroll
            for (int r = 0; r < 4; ++r) {
                int co = ct * 16 + 4 * lg + r;
                float* xp = x + xtb + (size_t)co * 512 + n;
                float nv = *xp - 0.25f * (acc[ct][r] + bs[ct][r]);
                *xp = nv;
                q[r] = f2bf(nv);
            }
            *(u16x4*)(xbt + (size_t)n * 32 + ct * 16 + 4 * lg) = q;
        }
    }
}

// ---------------------------------------------------------------------------
__global__ __launch_bounds__(256) void k_lnstats(const float* __restrict__ x,
                                                 float* __restrict__ stats) {
    int eb = blockIdx.x;
    const float* p = x + ((size_t)(eb * 26 + 24) * 32) * 512;
    float s = 0.f, s2 = 0.f;
    for (int i = threadIdx.x; i < 32768; i += 256) {
        float v = p[i];
        s += v;
        s2 += v * v;
    }
    for (int off = 32; off; off >>= 1) {
        s += __shfl_down(s, off);
        s2 += __shfl_down(s2, off);
    }
    __shared__ float r1[4], r2[4];
    if ((threadIdx.x & 63) == 0) {
        r1[threadIdx.x >> 6] = s;
        r2[threadIdx.x >> 6] = s2;
    }
    __syncthreads();
    if (threadIdx.x == 0) {
        float S = r1[0] + r1[1] + r1[2] + r1[3];
        float S2 = r2[0] + r2[1] + r2[2] + r2[3];
        float mu = S / 32768.f;
        float var = S2 / 32768.f - mu * mu;
        stats[eb * 2] = mu;
        stats[eb * 2 + 1] = rsqrtf(var + 1e-5f);
    }
}

// ---------------------------------------------------------------------------
__global__ __launch_bounds__(256) void k_heads_mfma(
    const ushort_t* __restrict__ xb, const float* __restrict__ stats,
    float* __restrict__ bkc, float* __restrict__ acc,
    const ushort_t* __restrict__ Whd, const float* __restrict__ rS,
    const float* __restrict__ bb1, const float* __restrict__ bb2,
    const float* __restrict__ bfc1, const float* __restrict__ bfc2,
    int kb) {
    __shared__ __align__(16) ushort_t lds[4][64][72];
    int w = blockIdx.y, eb = blockIdx.z;
    int e = eb >> 3, ek = e * NBK + kb;
    int tid = threadIdx.x, wv = tid >> 6, lane = tid & 63;
    int l15 = lane & 15, lg = lane >> 4;
    int n0 = blockIdx.x * 256 + wv * 64;
    float mu = stats[eb * 2], rsv = stats[eb * 2 + 1];
    const ushort_t* Wh = Whd + (size_t)e * 6144;
    const ushort_t* xrow = xb + ((size_t)(eb * 26 + 24 + w) * 512) * 32;

#pragma unroll
    for (int head = 0; head < 2; ++head) {
        if (head == 1 && w == 0) break;  // fc only for w==1
        int woff = head ? 3072 : 0;
        const float* b1 = head ? bfc1 : bb1;
        const float* b2 = head ? bfc2 : bb2;
        const float* rs1 = rS + e * 128 + (head ? 64 : 0);
        bf16x8 a1[4];
#pragma unroll
        for (int rt = 0; rt < 4; ++rt)
            a1[rt] = *(const bf16x8*)(Wh + woff + (size_t)(rt * 16 + l15) * 32 + lg * 8);
        float be[4][4];
#pragma unroll
        for (int rt = 0; rt < 4; ++rt)
#pragma unroll
            for (int r = 0; r < 4; ++r) {
                int d = rt * 16 + 4 * lg + r;
                be[rt][r] = b1[ek * 64 + d] - rsv * mu * rs1[d];
            }
#pragma unroll
        for (int nt = 0; nt < 4; ++nt) {
            bf16x8 bv = *(const bf16x8*)(xrow + (size_t)(n0 + nt * 16 + l15) * 32 + lg * 8);
            f32x4 ac[4] = {};
#pragma unroll
            for (int rt = 0; rt < 4; ++rt)
                ac[rt] = __builtin_amdgcn_mfma_f32_16x16x32_bf16(a1[rt], bv, ac[rt], 0, 0, 0);
#pragma unroll
            for (int rt = 0; rt < 4; ++rt)
#pragma unroll
                for (int r = 0; r < 4; ++r) {
                    float hv = fmaxf(rsv * ac[rt][r] + be[rt][r], 0.f);
                    lds[wv][nt * 16 + l15][rt * 16 + 4 * lg + r] = f2bf(hv);
                }
        }
        bf16x8 a2[2];
        a2[0] = *(const bf16x8*)(Wh + woff + 2048 + (size_t)l15 * 64 + lg * 8);
        a2[1] = *(const bf16x8*)(Wh + woff + 2048 + (size_t)l15 * 64 + 32 + lg * 8);
        float b2v[4];
#pragma unroll
        for (int r = 0; r < 4; ++r) {
            int s = 4 * lg + r;
            b2v[r] = (s < 12) ? b2[ek * 12 + s] : 0.f;
        }
#pragma unroll
        for (int nt = 0; nt < 4; ++nt) {
            bf16x8 b0 = *(const bf16x8*)&lds[wv][nt * 16 + l15][lg * 8];
            bf16x8 b1f = *(const bf16x8*)&lds[wv][nt * 16 + l15][32 + lg * 8];
            f32x4 ac2 = {};
            ac2 = __builtin_amdgcn_mfma_f32_16x16x32_bf16(a2[0], b0, ac2, 0, 0, 0);
            ac2 = __builtin_amdgcn_mfma_f32_16x16x32_bf16(a2[1], b1f, ac2, 0, 0, 0);
#pragma unroll
            for (int r = 0; r < 4; ++r) {
                int s = 4 * lg + r;
                if (s < 12) {
                    int n = n0 + nt * 16 + l15;
                    float val = ac2[r] + b2v[r];
                    if (head == 0)
                        bkc[((size_t)(eb * 12 + s) * 512 + n) * 2 + w] -= val;
                    else
                        acc[(size_t)(eb * 12 + s) * 512 + n] += val;
                }
            }
        }
    }
}

// ---------------------------------------------------------------------------
__global__ __launch_bounds__(256) void k_final(const float* __restrict__ acc,
                                               const float* __restrict__ ew,
                                               float* __restrict__ out) {
    int i = blockIdx.x * 256 + threadIdx.x;  // 49152
    out[i] = ew[0] * acc[i] + ew[1] * acc[49152 + i];
}

// ---------------------------------------------------------------------------
extern "C" void kernel_launch(void* const* d_in, const int* in_sizes, int n_in,
                              void* d_out, int out_size, void* d_ws, size_t ws_size,
                              hipStream_t stream) {
    const float* X    = (const float*)d_in[0];
    const float* adj  = (const float*)d_in[1];
    const float* ew   = (const float*)d_in[2];
    const float* Wst  = (const float*)d_in[3];
    const float* bst  = (const float*)d_in[4];
    const float* Wf2  = (const float*)d_in[5];
    const float* Wf3  = (const float*)d_in[6];
    const float* Wf5  = (const float*)d_in[7];
    const float* Wf7  = (const float*)d_in[8];
    const float* bf   = (const float*)d_in[9];
    const float* Wg2  = (const float*)d_in[10];
    const float* Wg3  = (const float*)d_in[11];
    const float* Wg5  = (const float*)d_in[12];
    const float* Wg7  = (const float*)d_in[13];
    const float* bg   = (const float*)d_in[14];
    const float* Wgc1 = (const float*)d_in[15];
    const float* bgc1 = (const float*)d_in[16];
    const float* Wgc2 = (const float*)d_in[17];
    const float* bgc2 = (const float*)d_in[18];
    const float* Wb1  = (const float*)d_in[19];
    const float* bb1  = (const float*)d_in[20];
    const float* Wb2  = (const float*)d_in[21];
    const float* bb2  = (const float*)d_in[22];
    const float* Wfc1 = (const float*)d_in[23];
    const float* bfc1 = (const float*)d_in[24];
    const float* Wfc2 = (const float*)d_in[25];
    const float* bfc2 = (const float*)d_in[26];

    float* ws = (float*)d_ws;
    size_t off = 0;
    auto alloc = [&](size_t nf) { float* p = ws + off; off += nf; return p; };
    float* di    = alloc(512);
    ushort_t* Anb   = (ushort_t*)alloc(512 * 512 / 2);
    ushort_t* AnTb  = (ushort_t*)alloc(512 * 512 / 2);
    ushort_t* An2b  = (ushort_t*)alloc(512 * 512 / 2);
    ushort_t* An2Tb = (ushort_t*)alloc(512 * 512 / 2);
    float* bkc   = alloc((size_t)EE * BATCH * 12 * 512 * 2);
    float* acc   = alloc((size_t)EE * BATCH * 12 * 512);
    float* stats = alloc(32);
    ushort_t* Amix = (ushort_t*)alloc(2 * 32 * 160 / 2);
    float* bsum  = alloc(64);
    ushort_t* Wb = (ushort_t*)alloc(14336);
    ushort_t* Whd = (ushort_t*)alloc(6144);
    float* rSb   = alloc(256);
    float* x     = alloc((size_t)16 * 26 * 32 * 512);
    ushort_t* xb = (ushort_t*)alloc((size_t)16 * 26 * 512 * 32 / 2);
    size_t hbuf_f = (size_t)16 * 20 * 32 * 512 / 2;  // bf16 old-layout, float units
    ushort_t* h   = (ushort_t*)alloc(hbuf_f);
    ushort_t* buf5 = (ushort_t*)alloc((size_t)16 * 20 * 512 * 160 / 2);
    if (off * sizeof(float) > ws_size) return;  // workspace too small: bail

    // Graph normalization + An^2 precompute
    k_rowsum<<<512, 256, 0, stream>>>(adj, di);
    k_norm<<<1024, 256, 0, stream>>>(adj, di, Anb, AnTb);
    k_An2<<<dim3(2, 8), 256, 0, stream>>>(Anb, AnTb, An2b, An2Tb);

    // Residual init (both experts start from X) + output accumulator zero
    hipMemcpyAsync(bkc, X, (size_t)98304 * 4, hipMemcpyDeviceToDevice, stream);
    hipMemcpyAsync(bkc + 98304, X, (size_t)98304 * 4, hipMemcpyDeviceToDevice, stream);
    hipMemsetAsync(acc, 0, (size_t)EE * BATCH * 12 * 512 * 4, stream);

    for (int kb = 0; kb < NBK; ++kb) {
        k_prep<<<116, 256, 0, stream>>>(Wf2, Wf3, Wf5, Wf7, Wg2, Wg3, Wg5, Wg7, Wb,
                                        Wgc1, bgc1, Wgc2, bgc2, Amix, bsum,
                                        Wb1, Wb2, Wfc1, Wfc2, Whd, rSb, kb);
        k_start<<<dim3(2, 26, 16), 256, 0, stream>>>(bkc, x, xb, Wst, bst, kb);
        int cur = 26;
        for (int it = 0; it < 4; ++it) {
            int L = cur - 6;
            k_incept_mfma<<<dim3(4, L, 16), 256, 0, stream>>>(
                xb, h, buf5, Wb, bf, bg, kb, cur, L);
            k_gemm4<<<dim3(2 * L, 8, 4), 256, 0, stream>>>(
                h, Anb, An2b, AnTb, An2Tb, buf5);
            k_combine_mfma<<<dim3(L, 16), 256, 0, stream>>>(x, xb, buf5, Amix, bsum, L);
            cur -= 6;
        }
        k_lnstats<<<16, 256, 0, stream>>>(x, stats);
        k_heads_mfma<<<dim3(2, 2, 16), 256, 0, stream>>>(xb, stats, bkc, acc, Whd, rSb,
                                                         bb1, bb2, bfc1, bfc2, kb);
    }
    k_final<<<192, 256, 0, stream>>>(acc, ew, (float*)d_out);
}